// Round 8
// baseline (904.177 us; speedup 1.0000x reference)
//
#include <hip/hip_runtime.h>
#include <hip/hip_bf16.h>

#define B_   16
#define N_   1024
#define KNN  20
#define NP   (B_ * N_)   // 16384

typedef short bf16x8 __attribute__((ext_vector_type(8)));
typedef float f32x4  __attribute__((ext_vector_type(4)));
typedef float f32x16 __attribute__((ext_vector_type(16)));

__device__ __forceinline__ unsigned short f2bf(float f) {
  unsigned u = __float_as_uint(f);
  u += 0x7fffu + ((u >> 16) & 1u);   // RNE
  return (unsigned short)(u >> 16);
}

// ---------------------------------------------------------------------------
// Row squared norms: sq[p] = sum_c X[p][c]^2  (fp32)
// ---------------------------------------------------------------------------
__global__ __launch_bounds__(256) void sqnorm_kernel(
    const float* __restrict__ X, int LD, int coff, int C, float* __restrict__ sq) {
  int p = blockIdx.x * 256 + threadIdx.x;
  const float* row = X + (size_t)p * LD + coff;
  float s = 0.f;
  if ((C & 3) == 0) {
    for (int c = 0; c < C; c += 4) {
      float4 vv = *(const float4*)(row + c);
      s = fmaf(vv.x, vv.x, s); s = fmaf(vv.y, vv.y, s);
      s = fmaf(vv.z, vv.z, s); s = fmaf(vv.w, vv.w, s);
    }
  } else {
    for (int c = 0; c < C; ++c) { float vv = row[c]; s = fmaf(vv, vv, s); }
  }
  sq[p] = s;
}

// ---------------------------------------------------------------------------
// Pairwise squared distances, Gram form, emitted as PACKED u32 SORT KEYS:
//   key[i][j] = (float_bits(max(d,0)) & 0xFFFFFC00) | j
// ---------------------------------------------------------------------------
__global__ __launch_bounds__(256) void pairdist_kernel(
    const float* __restrict__ X, int LD, int coff, int C,
    const float* __restrict__ sq, unsigned* __restrict__ Dk) {
  __shared__ float Xi[16][68];
  __shared__ float Xj[16][68];
  int b  = blockIdx.z;
  int i0 = blockIdx.y * 64, j0 = blockIdx.x * 64;
  int t  = threadIdx.x;
  int tx = t & 15, ty = t >> 4;
  float acc[4][4] = {};
  for (int c0 = 0; c0 < C; c0 += 16) {
    int cc = min(16, C - c0);
    if (tx < cc) {
      for (int r = ty; r < 64; r += 16) {
        Xi[tx][r] = X[(size_t)(b * N_ + i0 + r) * LD + coff + c0 + tx];
        Xj[tx][r] = X[(size_t)(b * N_ + j0 + r) * LD + coff + c0 + tx];
      }
    }
    __syncthreads();
    for (int c = 0; c < cc; ++c) {
      float4 a4 = *(const float4*)&Xi[c][ty * 4];
      float4 b4 = *(const float4*)&Xj[c][tx * 4];
      float a[4] = {a4.x, a4.y, a4.z, a4.w};
      float bb[4] = {b4.x, b4.y, b4.z, b4.w};
#pragma unroll
      for (int p = 0; p < 4; ++p)
#pragma unroll
        for (int q = 0; q < 4; ++q)
          acc[p][q] = fmaf(a[p], bb[q], acc[p][q]);
    }
    __syncthreads();
  }
  float sqi[4], sqj[4];
#pragma unroll
  for (int p = 0; p < 4; ++p) sqi[p] = sq[b * N_ + i0 + ty * 4 + p];
#pragma unroll
  for (int q = 0; q < 4; ++q) sqj[q] = sq[b * N_ + j0 + tx * 4 + q];
#pragma unroll
  for (int p = 0; p < 4; ++p) {
    uint4 st;
    unsigned* kk = (unsigned*)&st;
#pragma unroll
    for (int q = 0; q < 4; ++q) {
      float d = fmaxf((sqi[p] - 2.f * acc[p][q]) + sqj[q], 0.f);
      kk[q] = (__float_as_uint(d) & 0xFFFFFC00u) | (unsigned)(j0 + tx * 4 + q);
    }
    *(uint4*)&Dk[(size_t)(b * N_ + i0 + ty * 4 + p) * N_ + j0 + tx * 4] = st;
  }
}

// ---------------------------------------------------------------------------
// Top-K=20 smallest keys per point. One wave per point, u32 keys.
// ---------------------------------------------------------------------------
__global__ __launch_bounds__(256) void topk_kernel(
    const unsigned* __restrict__ Dk, int* __restrict__ idx) {
  int w = threadIdx.x >> 6, lane = threadIdx.x & 63;
  int p = blockIdx.x * 4 + w;
  const unsigned* row = Dk + (size_t)p * N_;
  unsigned key[16];
#pragma unroll
  for (int s = 0; s < 16; ++s) key[s] = row[lane + 64 * s];
  int base = p & ~(N_ - 1);
  for (int k = 0; k < KNN; ++k) {
    unsigned m = key[0];
#pragma unroll
    for (int s = 1; s < 16; ++s) m = min(m, key[s]);
#pragma unroll
    for (int off = 32; off >= 1; off >>= 1)
      m = min(m, (unsigned)__shfl_xor((int)m, off));
    int j = (int)(m & 1023u);
    if (lane == 0) idx[p * KNN + k] = base + j;
    if ((j & 63) == lane) key[j >> 6] = 0xFFFFFFFFu;
  }
}

// ---------------------------------------------------------------------------
// Per-point transform: u = x@(Wa_top - Wa_bot) + ba ; v = x@Wa_bot
// fp32 accumulate, bf16 out. X rows staged in LDS.
// ---------------------------------------------------------------------------
__global__ __launch_bounds__(256) void transform_kernel(
    const float* __restrict__ X, int LD, int coff, int Cin, int Cmid,
    const float* __restrict__ Wa, const float* __restrict__ ba,
    unsigned short* __restrict__ u, unsigned short* __restrict__ v) {
  __shared__ float xs[16 * 128];
  int w = threadIdx.x >> 6, lane = threadIdx.x & 63;
  int m  = blockIdx.y * 64 + lane;
  int p0 = blockIdx.x * 16;
  if ((Cin & 3) == 0) {
    for (int i = threadIdx.x; i < 16 * (Cin / 4); i += 256) {
      int pt = i / (Cin / 4), q = i - pt * (Cin / 4);
      *(float4*)&xs[pt * Cin + q * 4] =
          *(const float4*)&X[(size_t)(p0 + pt) * LD + coff + q * 4];
    }
  } else {
    for (int i = threadIdx.x; i < 16 * Cin; i += 256) {
      int pt = i / Cin, c = i - pt * Cin;
      xs[pt * Cin + c] = X[(size_t)(p0 + pt) * LD + coff + c];
    }
  }
  __syncthreads();
  const float* xw = xs + (w * 4) * Cin;
  float ua[4] = {0.f, 0.f, 0.f, 0.f}, va[4] = {0.f, 0.f, 0.f, 0.f};
  for (int c = 0; c < Cin; ++c) {
    float wt = Wa[(size_t)c * Cmid + m];
    float wb = Wa[(size_t)(Cin + c) * Cmid + m];
    float wd = wt - wb;
#pragma unroll
    for (int i = 0; i < 4; ++i) {
      float xv = xw[i * Cin + c];
      ua[i] = fmaf(xv, wd, ua[i]);
      va[i] = fmaf(xv, wb, va[i]);
    }
  }
  float bias = ba[m];
#pragma unroll
  for (int i = 0; i < 4; ++i) {
    u[(size_t)(p0 + w * 4 + i) * Cmid + m] = f2bf(ua[i] + bias);
    v[(size_t)(p0 + w * 4 + i) * Cmid + m] = f2bf(va[i]);
  }
}

// ---------------------------------------------------------------------------
// Batched transpose+convert of all four Wb (Cmid x Cout, fp32) -> bf16 WbT.
// ---------------------------------------------------------------------------
__global__ __launch_bounds__(256) void cvtw4_kernel(
    const float* __restrict__ W0, const float* __restrict__ W1,
    const float* __restrict__ W2, const float* __restrict__ W3,
    unsigned short* __restrict__ o0, unsigned short* __restrict__ o1,
    unsigned short* __restrict__ o2, unsigned short* __restrict__ o3) {
  __shared__ unsigned short tile[32][33];
  int z = blockIdx.z;
  const float* W; unsigned short* out; int Cmid, Cout;
  if (z == 0)      { W = W0; out = o0; Cmid = 64;  Cout = 64;  }
  else if (z == 1) { W = W1; out = o1; Cmid = 64;  Cout = 64;  }
  else if (z == 2) { W = W2; out = o2; Cmid = 128; Cout = 128; }
  else             { W = W3; out = o3; Cmid = 256; Cout = 256; }
  int c0 = blockIdx.x * 32, co0 = blockIdx.y * 32;
  if (c0 >= Cmid || co0 >= Cout) return;
  int tx = threadIdx.x & 31, ty = threadIdx.x >> 5;   // 32 x 8
  for (int r = ty; r < 32; r += 8)
    tile[r][tx] = f2bf(W[(size_t)(c0 + r) * Cout + co0 + tx]);
  __syncthreads();
  for (int r = ty; r < 32; r += 8)
    out[(size_t)(co0 + r) * Cmid + c0 + tx] = tile[tx][r];
}

// ---------------------------------------------------------------------------
// Edge MLP second GEMM + max-aggregate. v6: ZERO-barrier K*G loop.
//  - B-fragments read DIRECTLY FROM GLOBAL (wbt is 8..128 KB, L1/L2-hot;
//    per-wave frag load = the exact 1 KB B-tile). No W LDS, no W barriers:
//    the compiler pipelines the independent W loads across the MFMA stream.
//  - Per-group quad-maxes kept in REGISTERS (qm[G][4], <=32 VGPRs); one LDS
//    write phase + SINGLE __syncthreads + one reduce phase at the end.
//  - LDS = qmax only (40 x Cout floats). Block: 5 waves = 160 edges = 8 pts.
// ---------------------------------------------------------------------------
template<int Cmid, int Cout>
__global__ __launch_bounds__(320, 3) void edge_mlp_kernel(
    const unsigned short* __restrict__ u, const unsigned short* __restrict__ v,
    const int* __restrict__ idx,
    const unsigned short* __restrict__ wbt, const float* __restrict__ bb,
    float* __restrict__ xcat, int coff) {
  constexpr int KC = Cmid / 16;    // k chunks of 16
  constexpr int G  = Cout / 32;    // 32-col groups
  __shared__ float qmax[40 * Cout];
  int tid = threadIdx.x, w = tid >> 6, lane = tid & 63;
  int col = lane & 31, half = lane >> 5;

  int rg = blockIdx.x * 160 + w * 32 + col;
  int p  = rg / 20;
  int j  = idx[rg];
  const unsigned short* up = u + (size_t)p * Cmid + half * 8;
  const unsigned short* vp = v + (size_t)j * Cmid + half * 8;

  // A-fragments: relu(u_p + v_j) in bf16, register-resident for all groups.
  bf16x8 afr[KC];
#pragma unroll
  for (int c = 0; c < KC; ++c) {
    union { int4 i; __hip_bfloat162 h[4]; bf16x8 vec; } U, V, R;
    U.i = *(const int4*)(up + c * 16);
    V.i = *(const int4*)(vp + c * 16);
#pragma unroll
    for (int q = 0; q < 4; ++q) {
      float2 a = __bfloat1622float2(U.h[q]);
      float2 b = __bfloat1622float2(V.h[q]);
      R.h[q] = __float22bfloat162_rn({fmaxf(a.x + b.x, 0.f), fmaxf(a.y + b.y, 0.f)});
    }
    afr[c] = R.vec;
  }

  // B-frag base: row (g*32+col) of wbt, 16B chunk at k = c*16 + half*8.
  const unsigned short* wrow = wbt + (size_t)col * Cmid + half * 8;

  float qm[G][4];
#pragma unroll
  for (int g = 0; g < G; ++g) {
    const unsigned short* wg = wrow + (size_t)g * 32 * Cmid;
    f32x16 acc = {};
#pragma unroll
    for (int c = 0; c < KC; ++c) {
      bf16x8 bf = *(const bf16x8*)(wg + c * 16);
      acc = __builtin_amdgcn_mfma_f32_32x32x16_bf16(afr[c], bf, acc, 0, 0, 0);
    }
#pragma unroll
    for (int Q = 0; Q < 4; ++Q)
      qm[g][Q] = fmaxf(fmaxf(acc[4 * Q], acc[4 * Q + 1]),
                       fmaxf(acc[4 * Q + 2], acc[4 * Q + 3]));
  }

  // Single LDS round-trip for the cross-wave point-max.
#pragma unroll
  for (int g = 0; g < G; ++g)
#pragma unroll
    for (int Q = 0; Q < 4; ++Q)
      qmax[(w * 8 + 2 * Q + half) * Cout + g * 32 + col] = qm[g][Q];
  __syncthreads();
  for (int i = tid; i < 8 * Cout; i += 320) {
    int pl = i / Cout, c2 = i - pl * Cout;
    float mm = qmax[(pl * 5 + 0) * Cout + c2];
#pragma unroll
    for (int qq = 1; qq < 5; ++qq) mm = fmaxf(mm, qmax[(pl * 5 + qq) * Cout + c2]);
    int pg = blockIdx.x * 8 + pl;
    xcat[(size_t)pg * 512 + coff + c2] = mm + bb[c2];
  }
}

// ---------------------------------------------------------------------------
// Global max pool, two-stage coalesced.
// ---------------------------------------------------------------------------
__global__ __launch_bounds__(256) void pool1_kernel(const float* __restrict__ xcat,
                                                    float* __restrict__ part) {
  int b = blockIdx.x, g = blockIdx.y, t = threadIdx.x;
  const float* base = xcat + ((size_t)b * N_ + g * 128) * 512 + t * 2;
  float mx = -__builtin_inff(), my = -__builtin_inff();
#pragma unroll 4
  for (int r = 0; r < 128; ++r) {
    float2 vv = *(const float2*)(base + (size_t)r * 512);
    mx = fmaxf(mx, vv.x);
    my = fmaxf(my, vv.y);
  }
  *(float2*)&part[((size_t)b * 8 + g) * 512 + t * 2] = make_float2(mx, my);
}

__global__ __launch_bounds__(256) void pool2_kernel(const float* __restrict__ part,
                                                    float* __restrict__ pooled) {
  int b = blockIdx.x, t = threadIdx.x;
  float2 m = *(const float2*)&part[(size_t)b * 8 * 512 + t * 2];
#pragma unroll
  for (int g = 1; g < 8; ++g) {
    float2 vv = *(const float2*)&part[((size_t)b * 8 + g) * 512 + t * 2];
    m.x = fmaxf(m.x, vv.x);
    m.y = fmaxf(m.y, vv.y);
  }
  *(float2*)&pooled[b * 512 + t * 2] = m;
}

__global__ __launch_bounds__(256) void lin1_kernel(const float* __restrict__ pooled,
                                                   const float* __restrict__ W,
                                                   const float* __restrict__ bias,
                                                   float* __restrict__ h) {
  int flat = blockIdx.x * 256 + threadIdx.x;
  int b = flat >> 10, m = flat & 1023;
  float s = 0.f;
  for (int c = 0; c < 512; ++c) s = fmaf(pooled[b * 512 + c], W[(size_t)c * 1024 + m], s);
  h[flat] = s + bias[m];
}

__global__ __launch_bounds__(256) void bn_kernel(const float* __restrict__ h,
                                                 const float* __restrict__ gamma,
                                                 const float* __restrict__ beta,
                                                 float* __restrict__ h2) {
  int m = blockIdx.x * 256 + threadIdx.x;
  float s = 0.f;
  for (int b = 0; b < 16; ++b) s += h[b * 1024 + m];
  float mu = s * (1.f / 16.f);
  float vv = 0.f;
  for (int b = 0; b < 16; ++b) { float d = h[b * 1024 + m] - mu; vv = fmaf(d, d, vv); }
  vv *= (1.f / 16.f);
  float rstd = rsqrtf(vv + 1e-5f);
  float g = gamma[m] * rstd, be = beta[m];
  for (int b = 0; b < 16; ++b) {
    float val = (h[b * 1024 + m] - mu) * g + be;
    h2[b * 1024 + m] = fmaxf(val, 0.f);
  }
}

__global__ __launch_bounds__(64) void lin2_kernel(const float* __restrict__ h2,
                                                  const float* __restrict__ W,
                                                  const float* __restrict__ bias,
                                                  float* __restrict__ out) {
  int b = blockIdx.x, lane = threadIdx.x;
  float logit = 0.f;
  if (lane < 40) {
    logit = bias[lane];
    for (int c = 0; c < 1024; ++c)
      logit = fmaf(h2[b * 1024 + c], W[(size_t)c * 40 + lane], logit);
  }
  float mv = (lane < 40) ? logit : -__builtin_inff();
#pragma unroll
  for (int off = 32; off >= 1; off >>= 1) mv = fmaxf(mv, __shfl_xor(mv, off));
  float e = (lane < 40) ? expf(logit - mv) : 0.f;
#pragma unroll
  for (int off = 32; off >= 1; off >>= 1) e += __shfl_xor(e, off);
  float lse = mv + logf(e);
  if (lane < 40) out[b * 40 + lane] = logit - lse;
}

// ---------------------------------------------------------------------------
extern "C" void kernel_launch(void* const* d_in, const int* in_sizes, int n_in,
                              void* d_out, int out_size, void* d_ws, size_t ws_size,
                              hipStream_t stream) {
  const float* pos    = (const float*)d_in[0];
  const float* W1a = (const float*)d_in[2];  const float* b1a = (const float*)d_in[3];
  const float* W1b = (const float*)d_in[4];  const float* b1b = (const float*)d_in[5];
  const float* W2a = (const float*)d_in[6];  const float* b2a = (const float*)d_in[7];
  const float* W2b = (const float*)d_in[8];  const float* b2b = (const float*)d_in[9];
  const float* W3a = (const float*)d_in[10]; const float* b3a = (const float*)d_in[11];
  const float* W3b = (const float*)d_in[12]; const float* b3b = (const float*)d_in[13];
  const float* W4a = (const float*)d_in[14]; const float* b4a = (const float*)d_in[15];
  const float* W4b = (const float*)d_in[16]; const float* b4b = (const float*)d_in[17];
  const float* lin1_w = (const float*)d_in[18]; const float* lin1_b = (const float*)d_in[19];
  const float* gamma  = (const float*)d_in[20]; const float* beta   = (const float*)d_in[21];
  const float* lin2_w = (const float*)d_in[22]; const float* lin2_b = (const float*)d_in[23];
  float* out = (float*)d_out;

  char* ws = (char*)d_ws;
  size_t off = 0;
  auto alloc = [&](size_t bytes) {
    void* p = ws + off; off += (bytes + 255) & ~(size_t)255; return p;
  };
  float*    xcat = (float*)alloc((size_t)NP * 512 * 4);   // 32 MB
  unsigned* Dk   = (unsigned*)alloc((size_t)NP * N_ * 4); // 64 MB (u/v alias inside)
  int*      idx  = (int*)alloc((size_t)NP * KNN * 4);
  float*    sq   = (float*)alloc((size_t)NP * 4);
  unsigned short* wbt1 = (unsigned short*)alloc(64 * 64 * 2);
  unsigned short* wbt2 = (unsigned short*)alloc(64 * 64 * 2);
  unsigned short* wbt3 = (unsigned short*)alloc(128 * 128 * 2);
  unsigned short* wbt4 = (unsigned short*)alloc(256 * 256 * 2);
  float* h      = (float*)alloc(16 * 1024 * 4);
  float* h2     = (float*)alloc(16 * 1024 * 4);
  float* pooled = (float*)alloc(16 * 512 * 4);
  float* part   = (float*)alloc(16 * 8 * 512 * 4);
  unsigned short* u = (unsigned short*)Dk;             // bf16, aliases Dk
  unsigned short* v = (unsigned short*)Dk + (size_t)NP * 256;

  cvtw4_kernel<<<dim3(8, 8, 4), 256, 0, stream>>>(W1b, W2b, W3b, W4b,
                                                  wbt1, wbt2, wbt3, wbt4);

  dim3 pd_grid(16, 16, 16);
  // layer 1: in pos (C=3) -> xcat[:,0:64]
  sqnorm_kernel<<<NP / 256, 256, 0, stream>>>(pos, 3, 0, 3, sq);
  pairdist_kernel<<<pd_grid, 256, 0, stream>>>(pos, 3, 0, 3, sq, Dk);
  topk_kernel<<<NP / 4, 256, 0, stream>>>(Dk, idx);
  transform_kernel<<<dim3(NP / 16, 1), 256, 0, stream>>>(pos, 3, 0, 3, 64, W1a, b1a, u, v);
  edge_mlp_kernel<64, 64><<<2048, 320, 0, stream>>>(u, v, idx, wbt1, b1b, xcat, 0);
  // layer 2: in xcat[:,0:64] -> xcat[:,64:128]
  sqnorm_kernel<<<NP / 256, 256, 0, stream>>>(xcat, 512, 0, 64, sq);
  pairdist_kernel<<<pd_grid, 256, 0, stream>>>(xcat, 512, 0, 64, sq, Dk);
  topk_kernel<<<NP / 4, 256, 0, stream>>>(Dk, idx);
  transform_kernel<<<dim3(NP / 16, 1), 256, 0, stream>>>(xcat, 512, 0, 64, 64, W2a, b2a, u, v);
  edge_mlp_kernel<64, 64><<<2048, 320, 0, stream>>>(u, v, idx, wbt2, b2b, xcat, 64);
  // layer 3: in xcat[:,64:128] -> xcat[:,128:256]
  sqnorm_kernel<<<NP / 256, 256, 0, stream>>>(xcat, 512, 64, 64, sq);
  pairdist_kernel<<<pd_grid, 256, 0, stream>>>(xcat, 512, 64, 64, sq, Dk);
  topk_kernel<<<NP / 4, 256, 0, stream>>>(Dk, idx);
  transform_kernel<<<dim3(NP / 16, 2), 256, 0, stream>>>(xcat, 512, 64, 64, 128, W3a, b3a, u, v);
  edge_mlp_kernel<128, 128><<<2048, 320, 0, stream>>>(u, v, idx, wbt3, b3b, xcat, 128);
  // layer 4: in xcat[:,128:256] -> xcat[:,256:512]
  sqnorm_kernel<<<NP / 256, 256, 0, stream>>>(xcat, 512, 128, 128, sq);
  pairdist_kernel<<<pd_grid, 256, 0, stream>>>(xcat, 512, 128, 128, sq, Dk);
  topk_kernel<<<NP / 4, 256, 0, stream>>>(Dk, idx);
  transform_kernel<<<dim3(NP / 16, 4), 256, 0, stream>>>(xcat, 512, 128, 128, 256, W4a, b4a, u, v);
  edge_mlp_kernel<256, 256><<<2048, 320, 0, stream>>>(u, v, idx, wbt4, b4b, xcat, 256);
  // head
  pool1_kernel<<<dim3(16, 8), 256, 0, stream>>>(xcat, part);
  pool2_kernel<<<16, 256, 0, stream>>>(part, pooled);
  lin1_kernel<<<64, 256, 0, stream>>>(pooled, lin1_w, lin1_b, h);
  bn_kernel<<<4, 256, 0, stream>>>(h, gamma, beta, h2);
  lin2_kernel<<<16, 64, 0, stream>>>(h2, lin2_w, lin2_b, out);
}

// Round 9
// 832.974 us; speedup vs baseline: 1.0855x; 1.0855x over previous
//
#include <hip/hip_runtime.h>
#include <hip/hip_bf16.h>

#define B_   16
#define N_   1024
#define KNN  20
#define NP   (B_ * N_)   // 16384

typedef short bf16x8 __attribute__((ext_vector_type(8)));
typedef float f32x4  __attribute__((ext_vector_type(4)));
typedef float f32x16 __attribute__((ext_vector_type(16)));

__device__ __forceinline__ unsigned short f2bf(float f) {
  unsigned u = __float_as_uint(f);
  u += 0x7fffu + ((u >> 16) & 1u);   // RNE
  return (unsigned short)(u >> 16);
}

// ---------------------------------------------------------------------------
// Row squared norms: sq[p] = sum_c X[p][c]^2  (fp32)
// ---------------------------------------------------------------------------
__global__ __launch_bounds__(256) void sqnorm_kernel(
    const float* __restrict__ X, int LD, int coff, int C, float* __restrict__ sq) {
  int p = blockIdx.x * 256 + threadIdx.x;
  const float* row = X + (size_t)p * LD + coff;
  float s = 0.f;
  if ((C & 3) == 0) {
    for (int c = 0; c < C; c += 4) {
      float4 vv = *(const float4*)(row + c);
      s = fmaf(vv.x, vv.x, s); s = fmaf(vv.y, vv.y, s);
      s = fmaf(vv.z, vv.z, s); s = fmaf(vv.w, vv.w, s);
    }
  } else {
    for (int c = 0; c < C; ++c) { float vv = row[c]; s = fmaf(vv, vv, s); }
  }
  sq[p] = s;
}

// ---------------------------------------------------------------------------
// Pairwise squared distances, Gram form, emitted as PACKED u32 SORT KEYS:
//   key[i][j] = (float_bits(max(d,0)) & 0xFFFFFC00) | j
// ---------------------------------------------------------------------------
__global__ __launch_bounds__(256) void pairdist_kernel(
    const float* __restrict__ X, int LD, int coff, int C,
    const float* __restrict__ sq, unsigned* __restrict__ Dk) {
  __shared__ float Xi[16][68];
  __shared__ float Xj[16][68];
  int b  = blockIdx.z;
  int i0 = blockIdx.y * 64, j0 = blockIdx.x * 64;
  int t  = threadIdx.x;
  int tx = t & 15, ty = t >> 4;
  float acc[4][4] = {};
  for (int c0 = 0; c0 < C; c0 += 16) {
    int cc = min(16, C - c0);
    if (tx < cc) {
      for (int r = ty; r < 64; r += 16) {
        Xi[tx][r] = X[(size_t)(b * N_ + i0 + r) * LD + coff + c0 + tx];
        Xj[tx][r] = X[(size_t)(b * N_ + j0 + r) * LD + coff + c0 + tx];
      }
    }
    __syncthreads();
    for (int c = 0; c < cc; ++c) {
      float4 a4 = *(const float4*)&Xi[c][ty * 4];
      float4 b4 = *(const float4*)&Xj[c][tx * 4];
      float a[4] = {a4.x, a4.y, a4.z, a4.w};
      float bb[4] = {b4.x, b4.y, b4.z, b4.w};
#pragma unroll
      for (int p = 0; p < 4; ++p)
#pragma unroll
        for (int q = 0; q < 4; ++q)
          acc[p][q] = fmaf(a[p], bb[q], acc[p][q]);
    }
    __syncthreads();
  }
  float sqi[4], sqj[4];
#pragma unroll
  for (int p = 0; p < 4; ++p) sqi[p] = sq[b * N_ + i0 + ty * 4 + p];
#pragma unroll
  for (int q = 0; q < 4; ++q) sqj[q] = sq[b * N_ + j0 + tx * 4 + q];
#pragma unroll
  for (int p = 0; p < 4; ++p) {
    uint4 st;
    unsigned* kk = (unsigned*)&st;
#pragma unroll
    for (int q = 0; q < 4; ++q) {
      float d = fmaxf((sqi[p] - 2.f * acc[p][q]) + sqj[q], 0.f);
      kk[q] = (__float_as_uint(d) & 0xFFFFFC00u) | (unsigned)(j0 + tx * 4 + q);
    }
    *(uint4*)&Dk[(size_t)(b * N_ + i0 + ty * 4 + p) * N_ + j0 + tx * 4] = st;
  }
}

// ---------------------------------------------------------------------------
// Top-K=20 smallest keys per point. One wave per point, u32 keys.
// ---------------------------------------------------------------------------
__global__ __launch_bounds__(256) void topk_kernel(
    const unsigned* __restrict__ Dk, int* __restrict__ idx) {
  int w = threadIdx.x >> 6, lane = threadIdx.x & 63;
  int p = blockIdx.x * 4 + w;
  const unsigned* row = Dk + (size_t)p * N_;
  unsigned key[16];
#pragma unroll
  for (int s = 0; s < 16; ++s) key[s] = row[lane + 64 * s];
  int base = p & ~(N_ - 1);
  for (int k = 0; k < KNN; ++k) {
    unsigned m = key[0];
#pragma unroll
    for (int s = 1; s < 16; ++s) m = min(m, key[s]);
#pragma unroll
    for (int off = 32; off >= 1; off >>= 1)
      m = min(m, (unsigned)__shfl_xor((int)m, off));
    int j = (int)(m & 1023u);
    if (lane == 0) idx[p * KNN + k] = base + j;
    if ((j & 63) == lane) key[j >> 6] = 0xFFFFFFFFu;
  }
}

// ---------------------------------------------------------------------------
// Per-point transform: u = x@(Wa_top - Wa_bot) + ba ; v = x@Wa_bot
// fp32 accumulate, bf16 out. X rows staged in LDS.
// ---------------------------------------------------------------------------
__global__ __launch_bounds__(256) void transform_kernel(
    const float* __restrict__ X, int LD, int coff, int Cin, int Cmid,
    const float* __restrict__ Wa, const float* __restrict__ ba,
    unsigned short* __restrict__ u, unsigned short* __restrict__ v) {
  __shared__ float xs[16 * 128];
  int w = threadIdx.x >> 6, lane = threadIdx.x & 63;
  int m  = blockIdx.y * 64 + lane;
  int p0 = blockIdx.x * 16;
  if ((Cin & 3) == 0) {
    for (int i = threadIdx.x; i < 16 * (Cin / 4); i += 256) {
      int pt = i / (Cin / 4), q = i - pt * (Cin / 4);
      *(float4*)&xs[pt * Cin + q * 4] =
          *(const float4*)&X[(size_t)(p0 + pt) * LD + coff + q * 4];
    }
  } else {
    for (int i = threadIdx.x; i < 16 * Cin; i += 256) {
      int pt = i / Cin, c = i - pt * Cin;
      xs[pt * Cin + c] = X[(size_t)(p0 + pt) * LD + coff + c];
    }
  }
  __syncthreads();
  const float* xw = xs + (w * 4) * Cin;
  float ua[4] = {0.f, 0.f, 0.f, 0.f}, va[4] = {0.f, 0.f, 0.f, 0.f};
  for (int c = 0; c < Cin; ++c) {
    float wt = Wa[(size_t)c * Cmid + m];
    float wb = Wa[(size_t)(Cin + c) * Cmid + m];
    float wd = wt - wb;
#pragma unroll
    for (int i = 0; i < 4; ++i) {
      float xv = xw[i * Cin + c];
      ua[i] = fmaf(xv, wd, ua[i]);
      va[i] = fmaf(xv, wb, va[i]);
    }
  }
  float bias = ba[m];
#pragma unroll
  for (int i = 0; i < 4; ++i) {
    u[(size_t)(p0 + w * 4 + i) * Cmid + m] = f2bf(ua[i] + bias);
    v[(size_t)(p0 + w * 4 + i) * Cmid + m] = f2bf(va[i]);
  }
}

// ---------------------------------------------------------------------------
// Batched transpose+convert of all four Wb (Cmid x Cout, fp32) -> bf16 WbT.
// ---------------------------------------------------------------------------
__global__ __launch_bounds__(256) void cvtw4_kernel(
    const float* __restrict__ W0, const float* __restrict__ W1,
    const float* __restrict__ W2, const float* __restrict__ W3,
    unsigned short* __restrict__ o0, unsigned short* __restrict__ o1,
    unsigned short* __restrict__ o2, unsigned short* __restrict__ o3) {
  __shared__ unsigned short tile[32][33];
  int z = blockIdx.z;
  const float* W; unsigned short* out; int Cmid, Cout;
  if (z == 0)      { W = W0; out = o0; Cmid = 64;  Cout = 64;  }
  else if (z == 1) { W = W1; out = o1; Cmid = 64;  Cout = 64;  }
  else if (z == 2) { W = W2; out = o2; Cmid = 128; Cout = 128; }
  else             { W = W3; out = o3; Cmid = 256; Cout = 256; }
  int c0 = blockIdx.x * 32, co0 = blockIdx.y * 32;
  if (c0 >= Cmid || co0 >= Cout) return;
  int tx = threadIdx.x & 31, ty = threadIdx.x >> 5;   // 32 x 8
  for (int r = ty; r < 32; r += 8)
    tile[r][tx] = f2bf(W[(size_t)(c0 + r) * Cout + co0 + tx]);
  __syncthreads();
  for (int r = ty; r < 32; r += 8)
    out[(size_t)(co0 + r) * Cmid + c0 + tx] = tile[tx][r];
}

// ---------------------------------------------------------------------------
// Edge MLP second GEMM + max-aggregate. v7 = round-7 two-barrier LDS staging
// + REGISTER PREFETCH of next W group: the global load for group g+1 issues
// right after the barriers and completes during MFMA(g)+reduce(g), so no
// naked global latency sits between barriers. Single W LDS buffer (22KB L4).
// Block: 320 threads (5 waves) = 160 edges = 8 points.
// ---------------------------------------------------------------------------
template<int Cmid, int Cout, int CG>
__global__ __launch_bounds__(320, 4) void edge_mlp_kernel(
    const unsigned short* __restrict__ u, const unsigned short* __restrict__ v,
    const int* __restrict__ idx,
    const unsigned short* __restrict__ wbt, const float* __restrict__ bb,
    float* __restrict__ xcat, int coff) {
  constexpr int AP  = Cmid + 8;
  constexpr int T   = CG / 32;       // 32-col tiles per group
  constexpr int KC  = Cmid / 16;     // k chunks of 16
  constexpr int G   = Cout / CG;     // col groups
  constexpr int NW  = CG * (Cmid / 8);          // int4s per W group
  constexpr int NLD = (NW + 319) / 320;         // int4s per thread
  __shared__ __align__(16) unsigned short W_lds[CG * AP];
  __shared__ float qmax[40 * CG];
  int tid = threadIdx.x, w = tid >> 6, lane = tid & 63;
  int col = lane & 31, half = lane >> 5;

  int rg = blockIdx.x * 160 + w * 32 + col;
  int p  = rg / 20;
  int j  = idx[rg];
  const unsigned short* up = u + (size_t)p * Cmid + half * 8;
  const unsigned short* vp = v + (size_t)j * Cmid + half * 8;

  // A-fragments: relu(u_p + v_j) in bf16, register-resident for all groups.
  bf16x8 afr[KC];
#pragma unroll
  for (int c = 0; c < KC; ++c) {
    union { int4 i; __hip_bfloat162 h[4]; bf16x8 vec; } U, V, R;
    U.i = *(const int4*)(up + c * 16);
    V.i = *(const int4*)(vp + c * 16);
#pragma unroll
    for (int q = 0; q < 4; ++q) {
      float2 a = __bfloat1622float2(U.h[q]);
      float2 b = __bfloat1622float2(V.h[q]);
      R.h[q] = __float22bfloat162_rn({fmaxf(a.x + b.x, 0.f), fmaxf(a.y + b.y, 0.f)});
    }
    afr[c] = R.vec;
  }

  int brow = col * AP + half * 8;

  int4 pre[NLD];
  auto prefetch = [&](int g) {
#pragma unroll
    for (int n = 0; n < NLD; ++n) {
      int i = tid + n * 320;
      if (NW % 320 == 0 || i < NW)
        pre[n] = *(const int4*)&wbt[(size_t)g * CG * Cmid + i * 8];
    }
  };
  auto commit = [&]() {
#pragma unroll
    for (int n = 0; n < NLD; ++n) {
      int i = tid + n * 320;
      if (NW % 320 == 0 || i < NW) {
        int rr = i / (Cmid / 8), q = i - rr * (Cmid / 8);
        *(int4*)&W_lds[rr * AP + q * 8] = pre[n];
      }
    }
  };

  prefetch(0);
  for (int g = 0; g < G; ++g) {
    __syncthreads();                 // prior MFMA/reduce done with LDS
    commit();
    __syncthreads();
    if (g + 1 < G) prefetch(g + 1);  // overlaps MFMA + reduce below
    f32x16 acc[T] = {};
#pragma unroll
    for (int c = 0; c < KC; ++c) {
#pragma unroll
      for (int t = 0; t < T; ++t) {
        bf16x8 bf = *(const bf16x8*)&W_lds[brow + t * 32 * AP + c * 16];
        acc[t] = __builtin_amdgcn_mfma_f32_32x32x16_bf16(afr[c], bf, acc[t], 0, 0, 0);
      }
    }
#pragma unroll
    for (int t = 0; t < T; ++t) {
#pragma unroll
      for (int Q = 0; Q < 4; ++Q) {
        float m0 = fmaxf(fmaxf(acc[t][4 * Q], acc[t][4 * Q + 1]),
                         fmaxf(acc[t][4 * Q + 2], acc[t][4 * Q + 3]));
        qmax[(w * 8 + 2 * Q + half) * CG + t * 32 + col] = m0;
      }
    }
    __syncthreads();
    for (int i = tid; i < 8 * CG; i += 320) {
      int pl = i / CG, c2 = i - pl * CG;
      float mm = qmax[(pl * 5 + 0) * CG + c2];
#pragma unroll
      for (int qq = 1; qq < 5; ++qq) mm = fmaxf(mm, qmax[(pl * 5 + qq) * CG + c2]);
      int pg = blockIdx.x * 8 + pl;
      xcat[(size_t)pg * 512 + coff + g * CG + c2] = mm + bb[g * CG + c2];
    }
  }
}

// ---------------------------------------------------------------------------
// Global max pool, two-stage coalesced.
// ---------------------------------------------------------------------------
__global__ __launch_bounds__(256) void pool1_kernel(const float* __restrict__ xcat,
                                                    float* __restrict__ part) {
  int b = blockIdx.x, g = blockIdx.y, t = threadIdx.x;
  const float* base = xcat + ((size_t)b * N_ + g * 128) * 512 + t * 2;
  float mx = -__builtin_inff(), my = -__builtin_inff();
#pragma unroll 4
  for (int r = 0; r < 128; ++r) {
    float2 vv = *(const float2*)(base + (size_t)r * 512);
    mx = fmaxf(mx, vv.x);
    my = fmaxf(my, vv.y);
  }
  *(float2*)&part[((size_t)b * 8 + g) * 512 + t * 2] = make_float2(mx, my);
}

__global__ __launch_bounds__(256) void pool2_kernel(const float* __restrict__ part,
                                                    float* __restrict__ pooled) {
  int b = blockIdx.x, t = threadIdx.x;
  float2 m = *(const float2*)&part[(size_t)b * 8 * 512 + t * 2];
#pragma unroll
  for (int g = 1; g < 8; ++g) {
    float2 vv = *(const float2*)&part[((size_t)b * 8 + g) * 512 + t * 2];
    m.x = fmaxf(m.x, vv.x);
    m.y = fmaxf(m.y, vv.y);
  }
  *(float2*)&pooled[b * 512 + t * 2] = m;
}

__global__ __launch_bounds__(256) void lin1_kernel(const float* __restrict__ pooled,
                                                   const float* __restrict__ W,
                                                   const float* __restrict__ bias,
                                                   float* __restrict__ h) {
  int flat = blockIdx.x * 256 + threadIdx.x;
  int b = flat >> 10, m = flat & 1023;
  float s = 0.f;
  for (int c = 0; c < 512; ++c) s = fmaf(pooled[b * 512 + c], W[(size_t)c * 1024 + m], s);
  h[flat] = s + bias[m];
}

__global__ __launch_bounds__(256) void bn_kernel(const float* __restrict__ h,
                                                 const float* __restrict__ gamma,
                                                 const float* __restrict__ beta,
                                                 float* __restrict__ h2) {
  int m = blockIdx.x * 256 + threadIdx.x;
  float s = 0.f;
  for (int b = 0; b < 16; ++b) s += h[b * 1024 + m];
  float mu = s * (1.f / 16.f);
  float vv = 0.f;
  for (int b = 0; b < 16; ++b) { float d = h[b * 1024 + m] - mu; vv = fmaf(d, d, vv); }
  vv *= (1.f / 16.f);
  float rstd = rsqrtf(vv + 1e-5f);
  float g = gamma[m] * rstd, be = beta[m];
  for (int b = 0; b < 16; ++b) {
    float val = (h[b * 1024 + m] - mu) * g + be;
    h2[b * 1024 + m] = fmaxf(val, 0.f);
  }
}

__global__ __launch_bounds__(64) void lin2_kernel(const float* __restrict__ h2,
                                                  const float* __restrict__ W,
                                                  const float* __restrict__ bias,
                                                  float* __restrict__ out) {
  int b = blockIdx.x, lane = threadIdx.x;
  float logit = 0.f;
  if (lane < 40) {
    logit = bias[lane];
    for (int c = 0; c < 1024; ++c)
      logit = fmaf(h2[b * 1024 + c], W[(size_t)c * 40 + lane], logit);
  }
  float mv = (lane < 40) ? logit : -__builtin_inff();
#pragma unroll
  for (int off = 32; off >= 1; off >>= 1) mv = fmaxf(mv, __shfl_xor(mv, off));
  float e = (lane < 40) ? expf(logit - mv) : 0.f;
#pragma unroll
  for (int off = 32; off >= 1; off >>= 1) e += __shfl_xor(e, off);
  float lse = mv + logf(e);
  if (lane < 40) out[b * 40 + lane] = logit - lse;
}

// ---------------------------------------------------------------------------
extern "C" void kernel_launch(void* const* d_in, const int* in_sizes, int n_in,
                              void* d_out, int out_size, void* d_ws, size_t ws_size,
                              hipStream_t stream) {
  const float* pos    = (const float*)d_in[0];
  const float* W1a = (const float*)d_in[2];  const float* b1a = (const float*)d_in[3];
  const float* W1b = (const float*)d_in[4];  const float* b1b = (const float*)d_in[5];
  const float* W2a = (const float*)d_in[6];  const float* b2a = (const float*)d_in[7];
  const float* W2b = (const float*)d_in[8];  const float* b2b = (const float*)d_in[9];
  const float* W3a = (const float*)d_in[10]; const float* b3a = (const float*)d_in[11];
  const float* W3b = (const float*)d_in[12]; const float* b3b = (const float*)d_in[13];
  const float* W4a = (const float*)d_in[14]; const float* b4a = (const float*)d_in[15];
  const float* W4b = (const float*)d_in[16]; const float* b4b = (const float*)d_in[17];
  const float* lin1_w = (const float*)d_in[18]; const float* lin1_b = (const float*)d_in[19];
  const float* gamma  = (const float*)d_in[20]; const float* beta   = (const float*)d_in[21];
  const float* lin2_w = (const float*)d_in[22]; const float* lin2_b = (const float*)d_in[23];
  float* out = (float*)d_out;

  char* ws = (char*)d_ws;
  size_t off = 0;
  auto alloc = [&](size_t bytes) {
    void* p = ws + off; off += (bytes + 255) & ~(size_t)255; return p;
  };
  float*    xcat = (float*)alloc((size_t)NP * 512 * 4);   // 32 MB
  unsigned* Dk   = (unsigned*)alloc((size_t)NP * N_ * 4); // 64 MB (u/v alias inside)
  int*      idx  = (int*)alloc((size_t)NP * KNN * 4);
  float*    sq   = (float*)alloc((size_t)NP * 4);
  unsigned short* wbt1 = (unsigned short*)alloc(64 * 64 * 2);
  unsigned short* wbt2 = (unsigned short*)alloc(64 * 64 * 2);
  unsigned short* wbt3 = (unsigned short*)alloc(128 * 128 * 2);
  unsigned short* wbt4 = (unsigned short*)alloc(256 * 256 * 2);
  float* h      = (float*)alloc(16 * 1024 * 4);
  float* h2     = (float*)alloc(16 * 1024 * 4);
  float* pooled = (float*)alloc(16 * 512 * 4);
  float* part   = (float*)alloc(16 * 8 * 512 * 4);
  unsigned short* u = (unsigned short*)Dk;             // bf16, aliases Dk
  unsigned short* v = (unsigned short*)Dk + (size_t)NP * 256;

  cvtw4_kernel<<<dim3(8, 8, 4), 256, 0, stream>>>(W1b, W2b, W3b, W4b,
                                                  wbt1, wbt2, wbt3, wbt4);

  dim3 pd_grid(16, 16, 16);
  // layer 1: in pos (C=3) -> xcat[:,0:64]
  sqnorm_kernel<<<NP / 256, 256, 0, stream>>>(pos, 3, 0, 3, sq);
  pairdist_kernel<<<pd_grid, 256, 0, stream>>>(pos, 3, 0, 3, sq, Dk);
  topk_kernel<<<NP / 4, 256, 0, stream>>>(Dk, idx);
  transform_kernel<<<dim3(NP / 16, 1), 256, 0, stream>>>(pos, 3, 0, 3, 64, W1a, b1a, u, v);
  edge_mlp_kernel<64, 64, 64><<<2048, 320, 0, stream>>>(u, v, idx, wbt1, b1b, xcat, 0);
  // layer 2: in xcat[:,0:64] -> xcat[:,64:128]
  sqnorm_kernel<<<NP / 256, 256, 0, stream>>>(xcat, 512, 0, 64, sq);
  pairdist_kernel<<<pd_grid, 256, 0, stream>>>(xcat, 512, 0, 64, sq, Dk);
  topk_kernel<<<NP / 4, 256, 0, stream>>>(Dk, idx);
  transform_kernel<<<dim3(NP / 16, 1), 256, 0, stream>>>(xcat, 512, 0, 64, 64, W2a, b2a, u, v);
  edge_mlp_kernel<64, 64, 64><<<2048, 320, 0, stream>>>(u, v, idx, wbt2, b2b, xcat, 64);
  // layer 3: in xcat[:,64:128] -> xcat[:,128:256]
  sqnorm_kernel<<<NP / 256, 256, 0, stream>>>(xcat, 512, 64, 64, sq);
  pairdist_kernel<<<pd_grid, 256, 0, stream>>>(xcat, 512, 64, 64, sq, Dk);
  topk_kernel<<<NP / 4, 256, 0, stream>>>(Dk, idx);
  transform_kernel<<<dim3(NP / 16, 2), 256, 0, stream>>>(xcat, 512, 64, 64, 128, W3a, b3a, u, v);
  edge_mlp_kernel<128, 128, 64><<<2048, 320, 0, stream>>>(u, v, idx, wbt3, b3b, xcat, 128);
  // layer 4: in xcat[:,128:256] -> xcat[:,256:512]
  sqnorm_kernel<<<NP / 256, 256, 0, stream>>>(xcat, 512, 128, 128, sq);
  pairdist_kernel<<<pd_grid, 256, 0, stream>>>(xcat, 512, 128, 128, sq, Dk);
  topk_kernel<<<NP / 4, 256, 0, stream>>>(Dk, idx);
  transform_kernel<<<dim3(NP / 16, 4), 256, 0, stream>>>(xcat, 512, 128, 128, 256, W4a, b4a, u, v);
  edge_mlp_kernel<256, 256, 32><<<2048, 320, 0, stream>>>(u, v, idx, wbt4, b4b, xcat, 256);
  // head
  pool1_kernel<<<dim3(16, 8), 256, 0, stream>>>(xcat, part);
  pool2_kernel<<<16, 256, 0, stream>>>(part, pooled);
  lin1_kernel<<<64, 256, 0, stream>>>(pooled, lin1_w, lin1_b, h);
  bn_kernel<<<4, 256, 0, stream>>>(h, gamma, beta, h2);
  lin2_kernel<<<16, 64, 0, stream>>>(h2, lin2_w, lin2_b, out);
}

// Round 10
// 788.421 us; speedup vs baseline: 1.1468x; 1.0565x over previous
//
#include <hip/hip_runtime.h>
#include <hip/hip_bf16.h>

#define B_   16
#define N_   1024
#define KNN  20
#define NP   (B_ * N_)   // 16384

typedef short bf16x8 __attribute__((ext_vector_type(8)));
typedef float f32x4  __attribute__((ext_vector_type(4)));
typedef float f32x16 __attribute__((ext_vector_type(16)));

__device__ __forceinline__ unsigned short f2bf(float f) {
  unsigned u = __float_as_uint(f);
  u += 0x7fffu + ((u >> 16) & 1u);   // RNE
  return (unsigned short)(u >> 16);
}

// ---------------------------------------------------------------------------
// Row squared norms: sq[p] = sum_c X[p][c]^2  (fp32)
// ---------------------------------------------------------------------------
__global__ __launch_bounds__(256) void sqnorm_kernel(
    const float* __restrict__ X, int LD, int coff, int C, float* __restrict__ sq) {
  int p = blockIdx.x * 256 + threadIdx.x;
  const float* row = X + (size_t)p * LD + coff;
  float s = 0.f;
  if ((C & 3) == 0) {
    for (int c = 0; c < C; c += 4) {
      float4 vv = *(const float4*)(row + c);
      s = fmaf(vv.x, vv.x, s); s = fmaf(vv.y, vv.y, s);
      s = fmaf(vv.z, vv.z, s); s = fmaf(vv.w, vv.w, s);
    }
  } else {
    for (int c = 0; c < C; ++c) { float vv = row[c]; s = fmaf(vv, vv, s); }
  }
  sq[p] = s;
}

// ---------------------------------------------------------------------------
// Pairwise squared distances, Gram form, emitted as PACKED u32 SORT KEYS:
//   key[i][j] = (float_bits(max(d,0)) & 0xFFFFFC00) | j
// ---------------------------------------------------------------------------
__global__ __launch_bounds__(256) void pairdist_kernel(
    const float* __restrict__ X, int LD, int coff, int C,
    const float* __restrict__ sq, unsigned* __restrict__ Dk) {
  __shared__ float Xi[16][68];
  __shared__ float Xj[16][68];
  int b  = blockIdx.z;
  int i0 = blockIdx.y * 64, j0 = blockIdx.x * 64;
  int t  = threadIdx.x;
  int tx = t & 15, ty = t >> 4;
  float acc[4][4] = {};
  for (int c0 = 0; c0 < C; c0 += 16) {
    int cc = min(16, C - c0);
    if (tx < cc) {
      for (int r = ty; r < 64; r += 16) {
        Xi[tx][r] = X[(size_t)(b * N_ + i0 + r) * LD + coff + c0 + tx];
        Xj[tx][r] = X[(size_t)(b * N_ + j0 + r) * LD + coff + c0 + tx];
      }
    }
    __syncthreads();
    for (int c = 0; c < cc; ++c) {
      float4 a4 = *(const float4*)&Xi[c][ty * 4];
      float4 b4 = *(const float4*)&Xj[c][tx * 4];
      float a[4] = {a4.x, a4.y, a4.z, a4.w};
      float bb[4] = {b4.x, b4.y, b4.z, b4.w};
#pragma unroll
      for (int p = 0; p < 4; ++p)
#pragma unroll
        for (int q = 0; q < 4; ++q)
          acc[p][q] = fmaf(a[p], bb[q], acc[p][q]);
    }
    __syncthreads();
  }
  float sqi[4], sqj[4];
#pragma unroll
  for (int p = 0; p < 4; ++p) sqi[p] = sq[b * N_ + i0 + ty * 4 + p];
#pragma unroll
  for (int q = 0; q < 4; ++q) sqj[q] = sq[b * N_ + j0 + tx * 4 + q];
#pragma unroll
  for (int p = 0; p < 4; ++p) {
    uint4 st;
    unsigned* kk = (unsigned*)&st;
#pragma unroll
    for (int q = 0; q < 4; ++q) {
      float d = fmaxf((sqi[p] - 2.f * acc[p][q]) + sqj[q], 0.f);
      kk[q] = (__float_as_uint(d) & 0xFFFFFC00u) | (unsigned)(j0 + tx * 4 + q);
    }
    *(uint4*)&Dk[(size_t)(b * N_ + i0 + ty * 4 + p) * N_ + j0 + tx * 4] = st;
  }
}

// ---------------------------------------------------------------------------
// Top-K=20 smallest keys per point. One wave per point, u32 keys.
// ---------------------------------------------------------------------------
__global__ __launch_bounds__(256) void topk_kernel(
    const unsigned* __restrict__ Dk, int* __restrict__ idx) {
  int w = threadIdx.x >> 6, lane = threadIdx.x & 63;
  int p = blockIdx.x * 4 + w;
  const unsigned* row = Dk + (size_t)p * N_;
  unsigned key[16];
#pragma unroll
  for (int s = 0; s < 16; ++s) key[s] = row[lane + 64 * s];
  int base = p & ~(N_ - 1);
  for (int k = 0; k < KNN; ++k) {
    unsigned m = key[0];
#pragma unroll
    for (int s = 1; s < 16; ++s) m = min(m, key[s]);
#pragma unroll
    for (int off = 32; off >= 1; off >>= 1)
      m = min(m, (unsigned)__shfl_xor((int)m, off));
    int j = (int)(m & 1023u);
    if (lane == 0) idx[p * KNN + k] = base + j;
    if ((j & 63) == lane) key[j >> 6] = 0xFFFFFFFFu;
  }
}

// ---------------------------------------------------------------------------
// Per-point transform: u = x@(Wa_top - Wa_bot) + ba ; v = x@Wa_bot
// fp32 accumulate, bf16 out. X rows staged in LDS.
// ---------------------------------------------------------------------------
__global__ __launch_bounds__(256) void transform_kernel(
    const float* __restrict__ X, int LD, int coff, int Cin, int Cmid,
    const float* __restrict__ Wa, const float* __restrict__ ba,
    unsigned short* __restrict__ u, unsigned short* __restrict__ v) {
  __shared__ float xs[16 * 128];
  int w = threadIdx.x >> 6, lane = threadIdx.x & 63;
  int m  = blockIdx.y * 64 + lane;
  int p0 = blockIdx.x * 16;
  if ((Cin & 3) == 0) {
    for (int i = threadIdx.x; i < 16 * (Cin / 4); i += 256) {
      int pt = i / (Cin / 4), q = i - pt * (Cin / 4);
      *(float4*)&xs[pt * Cin + q * 4] =
          *(const float4*)&X[(size_t)(p0 + pt) * LD + coff + q * 4];
    }
  } else {
    for (int i = threadIdx.x; i < 16 * Cin; i += 256) {
      int pt = i / Cin, c = i - pt * Cin;
      xs[pt * Cin + c] = X[(size_t)(p0 + pt) * LD + coff + c];
    }
  }
  __syncthreads();
  const float* xw = xs + (w * 4) * Cin;
  float ua[4] = {0.f, 0.f, 0.f, 0.f}, va[4] = {0.f, 0.f, 0.f, 0.f};
  for (int c = 0; c < Cin; ++c) {
    float wt = Wa[(size_t)c * Cmid + m];
    float wb = Wa[(size_t)(Cin + c) * Cmid + m];
    float wd = wt - wb;
#pragma unroll
    for (int i = 0; i < 4; ++i) {
      float xv = xw[i * Cin + c];
      ua[i] = fmaf(xv, wd, ua[i]);
      va[i] = fmaf(xv, wb, va[i]);
    }
  }
  float bias = ba[m];
#pragma unroll
  for (int i = 0; i < 4; ++i) {
    u[(size_t)(p0 + w * 4 + i) * Cmid + m] = f2bf(ua[i] + bias);
    v[(size_t)(p0 + w * 4 + i) * Cmid + m] = f2bf(va[i]);
  }
}

// ---------------------------------------------------------------------------
// Convert all four Wb (Cmid x Cout, fp32) into FRAGMENT-MAJOR bf16 layout:
//   out[((g*KC + c)*64 + lane)*8 + j] = Wb[k][co]
//   with co = g*32 + (lane&31), k = c*16 + (lane>>5)*8 + j, KC = Cmid/16.
// A wave's MFMA B-fragment load for (g,c) is then ONE coalesced 1KB read.
// ---------------------------------------------------------------------------
__global__ __launch_bounds__(256) void cvtw_swz_kernel(
    const float* __restrict__ W0, const float* __restrict__ W1,
    const float* __restrict__ W2, const float* __restrict__ W3,
    unsigned short* __restrict__ o0, unsigned short* __restrict__ o1,
    unsigned short* __restrict__ o2, unsigned short* __restrict__ o3) {
  int z = blockIdx.z;
  const float* W; unsigned short* out; int Cmid, Cout;
  if (z == 0)      { W = W0; out = o0; Cmid = 64;  Cout = 64;  }
  else if (z == 1) { W = W1; out = o1; Cmid = 64;  Cout = 64;  }
  else if (z == 2) { W = W2; out = o2; Cmid = 128; Cout = 128; }
  else             { W = W3; out = o3; Cmid = 256; Cout = 256; }
  int NC = Cout * Cmid / 8;          // 16B fragments
  int ci = blockIdx.x * 256 + threadIdx.x;
  if (ci >= NC) return;
  int KC = Cmid / 16;
  int gKc = ci >> 6, lane = ci & 63;
  int g = gKc / KC, c = gKc - g * KC;
  int n = lane & 31, half = lane >> 5;
  int co = g * 32 + n;
  int kb = c * 16 + half * 8;
  unsigned short* dst = out + (size_t)ci * 8;
#pragma unroll
  for (int j = 0; j < 8; ++j)
    dst[j] = f2bf(W[(size_t)(kb + j) * Cout + co]);
}

// ---------------------------------------------------------------------------
// Edge MLP second GEMM + max-aggregate. v8: ZERO-barrier K*G loop with
// fragment-major W (see cvtw_swz): every B-load is one coalesced 1KB read
// from L1/L2 (weights are L2-resident), no LDS W staging, no K-loop barriers.
// Per-group quad-maxes in regs; one LDS write + SINGLE barrier + reduce.
// Block: 320 threads (5 waves) = 160 edges = 8 points.
// __launch_bounds__(320,3): <=170 regs (afr 64 + qm 32 + acc 16 + pipeline)
// -- r9 showed (320,4) spills to scratch (WRITE_SIZE 162MB); do not tighten.
// ---------------------------------------------------------------------------
template<int Cmid, int Cout>
__global__ __launch_bounds__(320, 3) void edge_mlp_kernel(
    const unsigned short* __restrict__ u, const unsigned short* __restrict__ v,
    const int* __restrict__ idx,
    const unsigned short* __restrict__ wbt, const float* __restrict__ bb,
    float* __restrict__ xcat, int coff) {
  constexpr int KC = Cmid / 16;    // k chunks of 16
  constexpr int G  = Cout / 32;    // 32-col groups
  __shared__ float qmax[40 * Cout];
  int tid = threadIdx.x, w = tid >> 6, lane = tid & 63;
  int col = lane & 31, half = lane >> 5;

  int rg = blockIdx.x * 160 + w * 32 + col;
  int p  = rg / 20;
  int j  = idx[rg];
  const unsigned short* up = u + (size_t)p * Cmid + half * 8;
  const unsigned short* vp = v + (size_t)j * Cmid + half * 8;

  // A-fragments: relu(u_p + v_j) in bf16, register-resident for all groups.
  bf16x8 afr[KC];
#pragma unroll
  for (int c = 0; c < KC; ++c) {
    union { int4 i; __hip_bfloat162 h[4]; bf16x8 vec; } U, V, R;
    U.i = *(const int4*)(up + c * 16);
    V.i = *(const int4*)(vp + c * 16);
#pragma unroll
    for (int q = 0; q < 4; ++q) {
      float2 a = __bfloat1622float2(U.h[q]);
      float2 b = __bfloat1622float2(V.h[q]);
      R.h[q] = __float22bfloat162_rn({fmaxf(a.x + b.x, 0.f), fmaxf(a.y + b.y, 0.f)});
    }
    afr[c] = R.vec;
  }

  // Fragment-major W: lane's 16B chunk for (g,c) at ((g*KC+c)*64 + lane)*8.
  const unsigned short* wl = wbt + (size_t)lane * 8;

  float qm[G][4];
#pragma unroll
  for (int g = 0; g < G; ++g) {
    f32x16 acc = {};
#pragma unroll
    for (int c = 0; c < KC; ++c) {
      bf16x8 bf = *(const bf16x8*)(wl + (size_t)(g * KC + c) * 512);
      acc = __builtin_amdgcn_mfma_f32_32x32x16_bf16(afr[c], bf, acc, 0, 0, 0);
    }
#pragma unroll
    for (int Q = 0; Q < 4; ++Q)
      qm[g][Q] = fmaxf(fmaxf(acc[4 * Q], acc[4 * Q + 1]),
                       fmaxf(acc[4 * Q + 2], acc[4 * Q + 3]));
  }

  // Single LDS round-trip for the cross-wave point-max.
#pragma unroll
  for (int g = 0; g < G; ++g)
#pragma unroll
    for (int Q = 0; Q < 4; ++Q)
      qmax[(w * 8 + 2 * Q + half) * Cout + g * 32 + col] = qm[g][Q];
  __syncthreads();
  for (int i = tid; i < 8 * Cout; i += 320) {
    int pl = i / Cout, c2 = i - pl * Cout;
    float mm = qmax[(pl * 5 + 0) * Cout + c2];
#pragma unroll
    for (int qq = 1; qq < 5; ++qq) mm = fmaxf(mm, qmax[(pl * 5 + qq) * Cout + c2]);
    int pg = blockIdx.x * 8 + pl;
    xcat[(size_t)pg * 512 + coff + c2] = mm + bb[c2];
  }
}

// ---------------------------------------------------------------------------
// Global max pool, two-stage coalesced.
// ---------------------------------------------------------------------------
__global__ __launch_bounds__(256) void pool1_kernel(const float* __restrict__ xcat,
                                                    float* __restrict__ part) {
  int b = blockIdx.x, g = blockIdx.y, t = threadIdx.x;
  const float* base = xcat + ((size_t)b * N_ + g * 128) * 512 + t * 2;
  float mx = -__builtin_inff(), my = -__builtin_inff();
#pragma unroll 4
  for (int r = 0; r < 128; ++r) {
    float2 vv = *(const float2*)(base + (size_t)r * 512);
    mx = fmaxf(mx, vv.x);
    my = fmaxf(my, vv.y);
  }
  *(float2*)&part[((size_t)b * 8 + g) * 512 + t * 2] = make_float2(mx, my);
}

__global__ __launch_bounds__(256) void pool2_kernel(const float* __restrict__ part,
                                                    float* __restrict__ pooled) {
  int b = blockIdx.x, t = threadIdx.x;
  float2 m = *(const float2*)&part[(size_t)b * 8 * 512 + t * 2];
#pragma unroll
  for (int g = 1; g < 8; ++g) {
    float2 vv = *(const float2*)&part[((size_t)b * 8 + g) * 512 + t * 2];
    m.x = fmaxf(m.x, vv.x);
    m.y = fmaxf(m.y, vv.y);
  }
  *(float2*)&pooled[b * 512 + t * 2] = m;
}

__global__ __launch_bounds__(256) void lin1_kernel(const float* __restrict__ pooled,
                                                   const float* __restrict__ W,
                                                   const float* __restrict__ bias,
                                                   float* __restrict__ h) {
  int flat = blockIdx.x * 256 + threadIdx.x;
  int b = flat >> 10, m = flat & 1023;
  float s = 0.f;
  for (int c = 0; c < 512; ++c) s = fmaf(pooled[b * 512 + c], W[(size_t)c * 1024 + m], s);
  h[flat] = s + bias[m];
}

__global__ __launch_bounds__(256) void bn_kernel(const float* __restrict__ h,
                                                 const float* __restrict__ gamma,
                                                 const float* __restrict__ beta,
                                                 float* __restrict__ h2) {
  int m = blockIdx.x * 256 + threadIdx.x;
  float s = 0.f;
  for (int b = 0; b < 16; ++b) s += h[b * 1024 + m];
  float mu = s * (1.f / 16.f);
  float vv = 0.f;
  for (int b = 0; b < 16; ++b) { float d = h[b * 1024 + m] - mu; vv = fmaf(d, d, vv); }
  vv *= (1.f / 16.f);
  float rstd = rsqrtf(vv + 1e-5f);
  float g = gamma[m] * rstd, be = beta[m];
  for (int b = 0; b < 16; ++b) {
    float val = (h[b * 1024 + m] - mu) * g + be;
    h2[b * 1024 + m] = fmaxf(val, 0.f);
  }
}

__global__ __launch_bounds__(64) void lin2_kernel(const float* __restrict__ h2,
                                                  const float* __restrict__ W,
                                                  const float* __restrict__ bias,
                                                  float* __restrict__ out) {
  int b = blockIdx.x, lane = threadIdx.x;
  float logit = 0.f;
  if (lane < 40) {
    logit = bias[lane];
    for (int c = 0; c < 1024; ++c)
      logit = fmaf(h2[b * 1024 + c], W[(size_t)c * 40 + lane], logit);
  }
  float mv = (lane < 40) ? logit : -__builtin_inff();
#pragma unroll
  for (int off = 32; off >= 1; off >>= 1) mv = fmaxf(mv, __shfl_xor(mv, off));
  float e = (lane < 40) ? expf(logit - mv) : 0.f;
#pragma unroll
  for (int off = 32; off >= 1; off >>= 1) e += __shfl_xor(e, off);
  float lse = mv + logf(e);
  if (lane < 40) out[b * 40 + lane] = logit - lse;
}

// ---------------------------------------------------------------------------
extern "C" void kernel_launch(void* const* d_in, const int* in_sizes, int n_in,
                              void* d_out, int out_size, void* d_ws, size_t ws_size,
                              hipStream_t stream) {
  const float* pos    = (const float*)d_in[0];
  const float* W1a = (const float*)d_in[2];  const float* b1a = (const float*)d_in[3];
  const float* W1b = (const float*)d_in[4];  const float* b1b = (const float*)d_in[5];
  const float* W2a = (const float*)d_in[6];  const float* b2a = (const float*)d_in[7];
  const float* W2b = (const float*)d_in[8];  const float* b2b = (const float*)d_in[9];
  const float* W3a = (const float*)d_in[10]; const float* b3a = (const float*)d_in[11];
  const float* W3b = (const float*)d_in[12]; const float* b3b = (const float*)d_in[13];
  const float* W4a = (const float*)d_in[14]; const float* b4a = (const float*)d_in[15];
  const float* W4b = (const float*)d_in[16]; const float* b4b = (const float*)d_in[17];
  const float* lin1_w = (const float*)d_in[18]; const float* lin1_b = (const float*)d_in[19];
  const float* gamma  = (const float*)d_in[20]; const float* beta   = (const float*)d_in[21];
  const float* lin2_w = (const float*)d_in[22]; const float* lin2_b = (const float*)d_in[23];
  float* out = (float*)d_out;

  char* ws = (char*)d_ws;
  size_t off = 0;
  auto alloc = [&](size_t bytes) {
    void* p = ws + off; off += (bytes + 255) & ~(size_t)255; return p;
  };
  float*    xcat = (float*)alloc((size_t)NP * 512 * 4);   // 32 MB
  unsigned* Dk   = (unsigned*)alloc((size_t)NP * N_ * 4); // 64 MB (u/v alias inside)
  int*      idx  = (int*)alloc((size_t)NP * KNN * 4);
  float*    sq   = (float*)alloc((size_t)NP * 4);
  unsigned short* wbt1 = (unsigned short*)alloc(64 * 64 * 2);
  unsigned short* wbt2 = (unsigned short*)alloc(64 * 64 * 2);
  unsigned short* wbt3 = (unsigned short*)alloc(128 * 128 * 2);
  unsigned short* wbt4 = (unsigned short*)alloc(256 * 256 * 2);
  float* h      = (float*)alloc(16 * 1024 * 4);
  float* h2     = (float*)alloc(16 * 1024 * 4);
  float* pooled = (float*)alloc(16 * 512 * 4);
  float* part   = (float*)alloc(16 * 8 * 512 * 4);
  unsigned short* u = (unsigned short*)Dk;             // bf16, aliases Dk
  unsigned short* v = (unsigned short*)Dk + (size_t)NP * 256;

  cvtw_swz_kernel<<<dim3(32, 1, 4), 256, 0, stream>>>(W1b, W2b, W3b, W4b,
                                                      wbt1, wbt2, wbt3, wbt4);

  dim3 pd_grid(16, 16, 16);
  // layer 1: in pos (C=3) -> xcat[:,0:64]
  sqnorm_kernel<<<NP / 256, 256, 0, stream>>>(pos, 3, 0, 3, sq);
  pairdist_kernel<<<pd_grid, 256, 0, stream>>>(pos, 3, 0, 3, sq, Dk);
  topk_kernel<<<NP / 4, 256, 0, stream>>>(Dk, idx);
  transform_kernel<<<dim3(NP / 16, 1), 256, 0, stream>>>(pos, 3, 0, 3, 64, W1a, b1a, u, v);
  edge_mlp_kernel<64, 64><<<2048, 320, 0, stream>>>(u, v, idx, wbt1, b1b, xcat, 0);
  // layer 2: in xcat[:,0:64] -> xcat[:,64:128]
  sqnorm_kernel<<<NP / 256, 256, 0, stream>>>(xcat, 512, 0, 64, sq);
  pairdist_kernel<<<pd_grid, 256, 0, stream>>>(xcat, 512, 0, 64, sq, Dk);
  topk_kernel<<<NP / 4, 256, 0, stream>>>(Dk, idx);
  transform_kernel<<<dim3(NP / 16, 1), 256, 0, stream>>>(xcat, 512, 0, 64, 64, W2a, b2a, u, v);
  edge_mlp_kernel<64, 64><<<2048, 320, 0, stream>>>(u, v, idx, wbt2, b2b, xcat, 64);
  // layer 3: in xcat[:,64:128] -> xcat[:,128:256]
  sqnorm_kernel<<<NP / 256, 256, 0, stream>>>(xcat, 512, 64, 64, sq);
  pairdist_kernel<<<pd_grid, 256, 0, stream>>>(xcat, 512, 64, 64, sq, Dk);
  topk_kernel<<<NP / 4, 256, 0, stream>>>(Dk, idx);
  transform_kernel<<<dim3(NP / 16, 2), 256, 0, stream>>>(xcat, 512, 64, 64, 128, W3a, b3a, u, v);
  edge_mlp_kernel<128, 128><<<2048, 320, 0, stream>>>(u, v, idx, wbt3, b3b, xcat, 128);
  // layer 4: in xcat[:,128:256] -> xcat[:,256:512]
  sqnorm_kernel<<<NP / 256, 256, 0, stream>>>(xcat, 512, 128, 128, sq);
  pairdist_kernel<<<pd_grid, 256, 0, stream>>>(xcat, 512, 128, 128, sq, Dk);
  topk_kernel<<<NP / 4, 256, 0, stream>>>(Dk, idx);
  transform_kernel<<<dim3(NP / 16, 4), 256, 0, stream>>>(xcat, 512, 128, 128, 256, W4a, b4a, u, v);
  edge_mlp_kernel<256, 256><<<2048, 320, 0, stream>>>(u, v, idx, wbt4, b4b, xcat, 256);
  // head
  pool1_kernel<<<dim3(16, 8), 256, 0, stream>>>(xcat, part);
  pool2_kernel<<<16, 256, 0, stream>>>(part, pooled);
  lin1_kernel<<<64, 256, 0, stream>>>(pooled, lin1_w, lin1_b, h);
  bn_kernel<<<4, 256, 0, stream>>>(h, gamma, beta, h2);
  lin2_kernel<<<16, 64, 0, stream>>>(h2, lin2_w, lin2_b, out);
}

// Round 11
// 776.908 us; speedup vs baseline: 1.1638x; 1.0148x over previous
//
#include <hip/hip_runtime.h>
#include <hip/hip_bf16.h>

#define B_   16
#define N_   1024
#define KNN  20
#define NP   (B_ * N_)   // 16384

typedef short bf16x8 __attribute__((ext_vector_type(8)));
typedef float f32x4  __attribute__((ext_vector_type(4)));
typedef float f32x16 __attribute__((ext_vector_type(16)));

__device__ __forceinline__ unsigned short f2bf(float f) {
  unsigned u = __float_as_uint(f);
  u += 0x7fffu + ((u >> 16) & 1u);   // RNE
  return (unsigned short)(u >> 16);
}

// ---------------------------------------------------------------------------
// Row squared norms: sq[p] = sum_c X[p][c]^2  (fp32)
// ---------------------------------------------------------------------------
__global__ __launch_bounds__(256) void sqnorm_kernel(
    const float* __restrict__ X, int LD, int coff, int C, float* __restrict__ sq) {
  int p = blockIdx.x * 256 + threadIdx.x;
  const float* row = X + (size_t)p * LD + coff;
  float s = 0.f;
  if ((C & 3) == 0) {
    for (int c = 0; c < C; c += 4) {
      float4 vv = *(const float4*)(row + c);
      s = fmaf(vv.x, vv.x, s); s = fmaf(vv.y, vv.y, s);
      s = fmaf(vv.z, vv.z, s); s = fmaf(vv.w, vv.w, s);
    }
  } else {
    for (int c = 0; c < C; ++c) { float vv = row[c]; s = fmaf(vv, vv, s); }
  }
  sq[p] = s;
}

// ---------------------------------------------------------------------------
// Pairwise squared distances, Gram form, emitted as PACKED u32 SORT KEYS:
//   key[i][j] = (float_bits(max(d,0)) & 0xFFFFFC00) | j
// ---------------------------------------------------------------------------
__global__ __launch_bounds__(256) void pairdist_kernel(
    const float* __restrict__ X, int LD, int coff, int C,
    const float* __restrict__ sq, unsigned* __restrict__ Dk) {
  __shared__ float Xi[16][68];
  __shared__ float Xj[16][68];
  int b  = blockIdx.z;
  int i0 = blockIdx.y * 64, j0 = blockIdx.x * 64;
  int t  = threadIdx.x;
  int tx = t & 15, ty = t >> 4;
  float acc[4][4] = {};
  for (int c0 = 0; c0 < C; c0 += 16) {
    int cc = min(16, C - c0);
    if (tx < cc) {
      for (int r = ty; r < 64; r += 16) {
        Xi[tx][r] = X[(size_t)(b * N_ + i0 + r) * LD + coff + c0 + tx];
        Xj[tx][r] = X[(size_t)(b * N_ + j0 + r) * LD + coff + c0 + tx];
      }
    }
    __syncthreads();
    for (int c = 0; c < cc; ++c) {
      float4 a4 = *(const float4*)&Xi[c][ty * 4];
      float4 b4 = *(const float4*)&Xj[c][tx * 4];
      float a[4] = {a4.x, a4.y, a4.z, a4.w};
      float bb[4] = {b4.x, b4.y, b4.z, b4.w};
#pragma unroll
      for (int p = 0; p < 4; ++p)
#pragma unroll
        for (int q = 0; q < 4; ++q)
          acc[p][q] = fmaf(a[p], bb[q], acc[p][q]);
    }
    __syncthreads();
  }
  float sqi[4], sqj[4];
#pragma unroll
  for (int p = 0; p < 4; ++p) sqi[p] = sq[b * N_ + i0 + ty * 4 + p];
#pragma unroll
  for (int q = 0; q < 4; ++q) sqj[q] = sq[b * N_ + j0 + tx * 4 + q];
#pragma unroll
  for (int p = 0; p < 4; ++p) {
    uint4 st;
    unsigned* kk = (unsigned*)&st;
#pragma unroll
    for (int q = 0; q < 4; ++q) {
      float d = fmaxf((sqi[p] - 2.f * acc[p][q]) + sqj[q], 0.f);
      kk[q] = (__float_as_uint(d) & 0xFFFFFC00u) | (unsigned)(j0 + tx * 4 + q);
    }
    *(uint4*)&Dk[(size_t)(b * N_ + i0 + ty * 4 + p) * N_ + j0 + tx * 4] = st;
  }
}

// ---------------------------------------------------------------------------
// Top-K=20 smallest keys per point. One wave per point, u32 keys.
// ---------------------------------------------------------------------------
__global__ __launch_bounds__(256) void topk_kernel(
    const unsigned* __restrict__ Dk, int* __restrict__ idx) {
  int w = threadIdx.x >> 6, lane = threadIdx.x & 63;
  int p = blockIdx.x * 4 + w;
  const unsigned* row = Dk + (size_t)p * N_;
  unsigned key[16];
#pragma unroll
  for (int s = 0; s < 16; ++s) key[s] = row[lane + 64 * s];
  int base = p & ~(N_ - 1);
  for (int k = 0; k < KNN; ++k) {
    unsigned m = key[0];
#pragma unroll
    for (int s = 1; s < 16; ++s) m = min(m, key[s]);
#pragma unroll
    for (int off = 32; off >= 1; off >>= 1)
      m = min(m, (unsigned)__shfl_xor((int)m, off));
    int j = (int)(m & 1023u);
    if (lane == 0) idx[p * KNN + k] = base + j;
    if ((j & 63) == lane) key[j >> 6] = 0xFFFFFFFFu;
  }
}

// ---------------------------------------------------------------------------
// Per-point transform: u = x@(Wa_top - Wa_bot) + ba ; v = x@Wa_bot
// fp32 accumulate, bf16 out. X rows staged in LDS.
// ---------------------------------------------------------------------------
__global__ __launch_bounds__(256) void transform_kernel(
    const float* __restrict__ X, int LD, int coff, int Cin, int Cmid,
    const float* __restrict__ Wa, const float* __restrict__ ba,
    unsigned short* __restrict__ u, unsigned short* __restrict__ v) {
  __shared__ float xs[16 * 128];
  int w = threadIdx.x >> 6, lane = threadIdx.x & 63;
  int m  = blockIdx.y * 64 + lane;
  int p0 = blockIdx.x * 16;
  if ((Cin & 3) == 0) {
    for (int i = threadIdx.x; i < 16 * (Cin / 4); i += 256) {
      int pt = i / (Cin / 4), q = i - pt * (Cin / 4);
      *(float4*)&xs[pt * Cin + q * 4] =
          *(const float4*)&X[(size_t)(p0 + pt) * LD + coff + q * 4];
    }
  } else {
    for (int i = threadIdx.x; i < 16 * Cin; i += 256) {
      int pt = i / Cin, c = i - pt * Cin;
      xs[pt * Cin + c] = X[(size_t)(p0 + pt) * LD + coff + c];
    }
  }
  __syncthreads();
  const float* xw = xs + (w * 4) * Cin;
  float ua[4] = {0.f, 0.f, 0.f, 0.f}, va[4] = {0.f, 0.f, 0.f, 0.f};
  for (int c = 0; c < Cin; ++c) {
    float wt = Wa[(size_t)c * Cmid + m];
    float wb = Wa[(size_t)(Cin + c) * Cmid + m];
    float wd = wt - wb;
#pragma unroll
    for (int i = 0; i < 4; ++i) {
      float xv = xw[i * Cin + c];
      ua[i] = fmaf(xv, wd, ua[i]);
      va[i] = fmaf(xv, wb, va[i]);
    }
  }
  float bias = ba[m];
#pragma unroll
  for (int i = 0; i < 4; ++i) {
    u[(size_t)(p0 + w * 4 + i) * Cmid + m] = f2bf(ua[i] + bias);
    v[(size_t)(p0 + w * 4 + i) * Cmid + m] = f2bf(va[i]);
  }
}

// ---------------------------------------------------------------------------
// Convert all four Wb (Cmid x Cout, fp32) into FRAGMENT-MAJOR bf16 layout:
//   out[((g*KC + c)*64 + lane)*8 + j] = Wb[k][co]
//   with co = g*32 + (lane&31), k = c*16 + (lane>>5)*8 + j, KC = Cmid/16.
// Wave B-fragment load for (g,c) = ONE contiguous 1KB read; LDS staging of a
// col-group range is a plain linear memcpy.
// ---------------------------------------------------------------------------
__global__ __launch_bounds__(256) void cvtw_swz_kernel(
    const float* __restrict__ W0, const float* __restrict__ W1,
    const float* __restrict__ W2, const float* __restrict__ W3,
    unsigned short* __restrict__ o0, unsigned short* __restrict__ o1,
    unsigned short* __restrict__ o2, unsigned short* __restrict__ o3) {
  int z = blockIdx.z;
  const float* W; unsigned short* out; int Cmid, Cout;
  if (z == 0)      { W = W0; out = o0; Cmid = 64;  Cout = 64;  }
  else if (z == 1) { W = W1; out = o1; Cmid = 64;  Cout = 64;  }
  else if (z == 2) { W = W2; out = o2; Cmid = 128; Cout = 128; }
  else             { W = W3; out = o3; Cmid = 256; Cout = 256; }
  int NC = Cout * Cmid / 8;          // 16B fragments
  int ci = blockIdx.x * 256 + threadIdx.x;
  if (ci >= NC) return;
  int KC = Cmid / 16;
  int gKc = ci >> 6, lane = ci & 63;
  int g = gKc / KC, c = gKc - g * KC;
  int n = lane & 31, half = lane >> 5;
  int co = g * 32 + n;
  int kb = c * 16 + half * 8;
  unsigned short* dst = out + (size_t)ci * 8;
#pragma unroll
  for (int j = 0; j < 8; ++j)
    dst[j] = f2bf(W[(size_t)(kb + j) * Cout + co]);
}

// ---------------------------------------------------------------------------
// Edge MLP second GEMM + max-aggregate. v9: LDS-staged fragment-major W in
// the LARGEST chunks that fit 32KB (L1/2/3: whole W -> 3 barriers total;
// L4: 4 stages of 64 cols -> 10 barriers vs r7's 24). MFMA B-reads are
// contiguous conflict-free ds_read_b128; per-group quad-maxes live in regs;
// qmax LDS buffer ALIASES the W region (barrier-protected) -> L4 = 40KB LDS.
// Block: 320 threads (5 waves) = 160 edges = 8 points.
// (320,3) for L4 (afr 64 + qm 32 + acc 16 regs; (320,4)=128 cap spills, r9).
// ---------------------------------------------------------------------------
template<int Cmid, int Cout>
__global__ __launch_bounds__(320, (Cmid >= 256) ? 3 : 4) void edge_mlp_kernel(
    const unsigned short* __restrict__ u, const unsigned short* __restrict__ v,
    const int* __restrict__ idx,
    const unsigned short* __restrict__ wbt, const float* __restrict__ bb,
    float* __restrict__ xcat, int coff) {
  constexpr int KC = Cmid / 16;                       // k chunks of 16
  constexpr int CW = (16384 / Cmid < Cout) ? (16384 / Cmid) : Cout;  // stage cols
  constexpr int NS = Cout / CW;                       // stages
  constexpr int T  = CW / 32;                         // 32-col tiles per stage
  constexpr int WBYTES = CW * Cmid * 2;               // <= 32768
  constexpr int QBYTES = 40 * Cout * 4;
  constexpr int SBYTES = (WBYTES > QBYTES) ? WBYTES : QBYTES;
  __shared__ __align__(16) char smem[SBYTES];
  int tid = threadIdx.x, w = tid >> 6, lane = tid & 63;
  int col = lane & 31, half = lane >> 5;

  int rg = blockIdx.x * 160 + w * 32 + col;
  int p  = rg / 20;
  int j  = idx[rg];
  const unsigned short* up = u + (size_t)p * Cmid + half * 8;
  const unsigned short* vp = v + (size_t)j * Cmid + half * 8;

  // A-fragments: relu(u_p + v_j) in bf16, register-resident for all stages.
  bf16x8 afr[KC];
#pragma unroll
  for (int c = 0; c < KC; ++c) {
    union { int4 i; __hip_bfloat162 h[4]; bf16x8 vec; } U, V, R;
    U.i = *(const int4*)(up + c * 16);
    V.i = *(const int4*)(vp + c * 16);
#pragma unroll
    for (int q = 0; q < 4; ++q) {
      float2 a = __bfloat1622float2(U.h[q]);
      float2 b = __bfloat1622float2(V.h[q]);
      R.h[q] = __float22bfloat162_rn({fmaxf(a.x + b.x, 0.f), fmaxf(a.y + b.y, 0.f)});
    }
    afr[c] = R.vec;
  }

  float qm[NS][T][4];
  for (int s = 0; s < NS; ++s) {
    __syncthreads();                 // protect W region from prior-stage reads
    {  // stage W (linear coalesced memcpy, fragment-major)
      const int4* src = (const int4*)(wbt + (size_t)s * CW * Cmid);
      int4* dst = (int4*)smem;
      for (int i = tid; i < WBYTES / 16; i += 320) dst[i] = src[i];
    }
    __syncthreads();
#pragma unroll
    for (int t = 0; t < T; ++t) {
      f32x16 acc = {};
#pragma unroll
      for (int c = 0; c < KC; ++c) {
        bf16x8 bf = *(const bf16x8*)(smem + ((t * KC + c) * 64 + lane) * 16);
        acc = __builtin_amdgcn_mfma_f32_32x32x16_bf16(afr[c], bf, acc, 0, 0, 0);
      }
#pragma unroll
      for (int Q = 0; Q < 4; ++Q)
        qm[s][t][Q] = fmaxf(fmaxf(acc[4 * Q], acc[4 * Q + 1]),
                            fmaxf(acc[4 * Q + 2], acc[4 * Q + 3]));
    }
  }

  __syncthreads();                   // all MFMAs done; reuse smem as qmax
  float* qmax = (float*)smem;
#pragma unroll
  for (int s = 0; s < NS; ++s)
#pragma unroll
    for (int t = 0; t < T; ++t)
#pragma unroll
      for (int Q = 0; Q < 4; ++Q)
        qmax[(w * 8 + 2 * Q + half) * Cout + s * CW + t * 32 + col] = qm[s][t][Q];
  __syncthreads();
  for (int i = tid; i < 8 * Cout; i += 320) {
    int pl = i / Cout, c2 = i - pl * Cout;
    float mm = qmax[(pl * 5 + 0) * Cout + c2];
#pragma unroll
    for (int qq = 1; qq < 5; ++qq) mm = fmaxf(mm, qmax[(pl * 5 + qq) * Cout + c2]);
    int pg = blockIdx.x * 8 + pl;
    xcat[(size_t)pg * 512 + coff + c2] = mm + bb[c2];
  }
}

// ---------------------------------------------------------------------------
// Global max pool, two-stage coalesced.
// ---------------------------------------------------------------------------
__global__ __launch_bounds__(256) void pool1_kernel(const float* __restrict__ xcat,
                                                    float* __restrict__ part) {
  int b = blockIdx.x, g = blockIdx.y, t = threadIdx.x;
  const float* base = xcat + ((size_t)b * N_ + g * 128) * 512 + t * 2;
  float mx = -__builtin_inff(), my = -__builtin_inff();
#pragma unroll 4
  for (int r = 0; r < 128; ++r) {
    float2 vv = *(const float2*)(base + (size_t)r * 512);
    mx = fmaxf(mx, vv.x);
    my = fmaxf(my, vv.y);
  }
  *(float2*)&part[((size_t)b * 8 + g) * 512 + t * 2] = make_float2(mx, my);
}

__global__ __launch_bounds__(256) void pool2_kernel(const float* __restrict__ part,
                                                    float* __restrict__ pooled) {
  int b = blockIdx.x, t = threadIdx.x;
  float2 m = *(const float2*)&part[(size_t)b * 8 * 512 + t * 2];
#pragma unroll
  for (int g = 1; g < 8; ++g) {
    float2 vv = *(const float2*)&part[((size_t)b * 8 + g) * 512 + t * 2];
    m.x = fmaxf(m.x, vv.x);
    m.y = fmaxf(m.y, vv.y);
  }
  *(float2*)&pooled[b * 512 + t * 2] = m;
}

__global__ __launch_bounds__(256) void lin1_kernel(const float* __restrict__ pooled,
                                                   const float* __restrict__ W,
                                                   const float* __restrict__ bias,
                                                   float* __restrict__ h) {
  int flat = blockIdx.x * 256 + threadIdx.x;
  int b = flat >> 10, m = flat & 1023;
  float s = 0.f;
  for (int c = 0; c < 512; ++c) s = fmaf(pooled[b * 512 + c], W[(size_t)c * 1024 + m], s);
  h[flat] = s + bias[m];
}

__global__ __launch_bounds__(256) void bn_kernel(const float* __restrict__ h,
                                                 const float* __restrict__ gamma,
                                                 const float* __restrict__ beta,
                                                 float* __restrict__ h2) {
  int m = blockIdx.x * 256 + threadIdx.x;
  float s = 0.f;
  for (int b = 0; b < 16; ++b) s += h[b * 1024 + m];
  float mu = s * (1.f / 16.f);
  float vv = 0.f;
  for (int b = 0; b < 16; ++b) { float d = h[b * 1024 + m] - mu; vv = fmaf(d, d, vv); }
  vv *= (1.f / 16.f);
  float rstd = rsqrtf(vv + 1e-5f);
  float g = gamma[m] * rstd, be = beta[m];
  for (int b = 0; b < 16; ++b) {
    float val = (h[b * 1024 + m] - mu) * g + be;
    h2[b * 1024 + m] = fmaxf(val, 0.f);
  }
}

__global__ __launch_bounds__(64) void lin2_kernel(const float* __restrict__ h2,
                                                  const float* __restrict__ W,
                                                  const float* __restrict__ bias,
                                                  float* __restrict__ out) {
  int b = blockIdx.x, lane = threadIdx.x;
  float logit = 0.f;
  if (lane < 40) {
    logit = bias[lane];
    for (int c = 0; c < 1024; ++c)
      logit = fmaf(h2[b * 1024 + c], W[(size_t)c * 40 + lane], logit);
  }
  float mv = (lane < 40) ? logit : -__builtin_inff();
#pragma unroll
  for (int off = 32; off >= 1; off >>= 1) mv = fmaxf(mv, __shfl_xor(mv, off));
  float e = (lane < 40) ? expf(logit - mv) : 0.f;
#pragma unroll
  for (int off = 32; off >= 1; off >>= 1) e += __shfl_xor(e, off);
  float lse = mv + logf(e);
  if (lane < 40) out[b * 40 + lane] = logit - lse;
}

// ---------------------------------------------------------------------------
extern "C" void kernel_launch(void* const* d_in, const int* in_sizes, int n_in,
                              void* d_out, int out_size, void* d_ws, size_t ws_size,
                              hipStream_t stream) {
  const float* pos    = (const float*)d_in[0];
  const float* W1a = (const float*)d_in[2];  const float* b1a = (const float*)d_in[3];
  const float* W1b = (const float*)d_in[4];  const float* b1b = (const float*)d_in[5];
  const float* W2a = (const float*)d_in[6];  const float* b2a = (const float*)d_in[7];
  const float* W2b = (const float*)d_in[8];  const float* b2b = (const float*)d_in[9];
  const float* W3a = (const float*)d_in[10]; const float* b3a = (const float*)d_in[11];
  const float* W3b = (const float*)d_in[12]; const float* b3b = (const float*)d_in[13];
  const float* W4a = (const float*)d_in[14]; const float* b4a = (const float*)d_in[15];
  const float* W4b = (const float*)d_in[16]; const float* b4b = (const float*)d_in[17];
  const float* lin1_w = (const float*)d_in[18]; const float* lin1_b = (const float*)d_in[19];
  const float* gamma  = (const float*)d_in[20]; const float* beta   = (const float*)d_in[21];
  const float* lin2_w = (const float*)d_in[22]; const float* lin2_b = (const float*)d_in[23];
  float* out = (float*)d_out;

  char* ws = (char*)d_ws;
  size_t off = 0;
  auto alloc = [&](size_t bytes) {
    void* p = ws + off; off += (bytes + 255) & ~(size_t)255; return p;
  };
  float*    xcat = (float*)alloc((size_t)NP * 512 * 4);   // 32 MB
  unsigned* Dk   = (unsigned*)alloc((size_t)NP * N_ * 4); // 64 MB (u/v alias inside)
  int*      idx  = (int*)alloc((size_t)NP * KNN * 4);
  float*    sq   = (float*)alloc((size_t)NP * 4);
  unsigned short* wbt1 = (unsigned short*)alloc(64 * 64 * 2);
  unsigned short* wbt2 = (unsigned short*)alloc(64 * 64 * 2);
  unsigned short* wbt3 = (unsigned short*)alloc(128 * 128 * 2);
  unsigned short* wbt4 = (unsigned short*)alloc(256 * 256 * 2);
  float* h      = (float*)alloc(16 * 1024 * 4);
  float* h2     = (float*)alloc(16 * 1024 * 4);
  float* pooled = (float*)alloc(16 * 512 * 4);
  float* part   = (float*)alloc(16 * 8 * 512 * 4);
  unsigned short* u = (unsigned short*)Dk;             // bf16, aliases Dk
  unsigned short* v = (unsigned short*)Dk + (size_t)NP * 256;

  cvtw_swz_kernel<<<dim3(32, 1, 4), 256, 0, stream>>>(W1b, W2b, W3b, W4b,
                                                      wbt1, wbt2, wbt3, wbt4);

  dim3 pd_grid(16, 16, 16);
  // layer 1: in pos (C=3) -> xcat[:,0:64]
  sqnorm_kernel<<<NP / 256, 256, 0, stream>>>(pos, 3, 0, 3, sq);
  pairdist_kernel<<<pd_grid, 256, 0, stream>>>(pos, 3, 0, 3, sq, Dk);
  topk_kernel<<<NP / 4, 256, 0, stream>>>(Dk, idx);
  transform_kernel<<<dim3(NP / 16, 1), 256, 0, stream>>>(pos, 3, 0, 3, 64, W1a, b1a, u, v);
  edge_mlp_kernel<64, 64><<<2048, 320, 0, stream>>>(u, v, idx, wbt1, b1b, xcat, 0);
  // layer 2: in xcat[:,0:64] -> xcat[:,64:128]
  sqnorm_kernel<<<NP / 256, 256, 0, stream>>>(xcat, 512, 0, 64, sq);
  pairdist_kernel<<<pd_grid, 256, 0, stream>>>(xcat, 512, 0, 64, sq, Dk);
  topk_kernel<<<NP / 4, 256, 0, stream>>>(Dk, idx);
  transform_kernel<<<dim3(NP / 16, 1), 256, 0, stream>>>(xcat, 512, 0, 64, 64, W2a, b2a, u, v);
  edge_mlp_kernel<64, 64><<<2048, 320, 0, stream>>>(u, v, idx, wbt2, b2b, xcat, 64);
  // layer 3: in xcat[:,64:128] -> xcat[:,128:256]
  sqnorm_kernel<<<NP / 256, 256, 0, stream>>>(xcat, 512, 64, 64, sq);
  pairdist_kernel<<<pd_grid, 256, 0, stream>>>(xcat, 512, 64, 64, sq, Dk);
  topk_kernel<<<NP / 4, 256, 0, stream>>>(Dk, idx);
  transform_kernel<<<dim3(NP / 16, 2), 256, 0, stream>>>(xcat, 512, 64, 64, 128, W3a, b3a, u, v);
  edge_mlp_kernel<128, 128><<<2048, 320, 0, stream>>>(u, v, idx, wbt3, b3b, xcat, 128);
  // layer 4: in xcat[:,128:256] -> xcat[:,256:512]
  sqnorm_kernel<<<NP / 256, 256, 0, stream>>>(xcat, 512, 128, 128, sq);
  pairdist_kernel<<<pd_grid, 256, 0, stream>>>(xcat, 512, 128, 128, sq, Dk);
  topk_kernel<<<NP / 4, 256, 0, stream>>>(Dk, idx);
  transform_kernel<<<dim3(NP / 16, 4), 256, 0, stream>>>(xcat, 512, 128, 128, 256, W4a, b4a, u, v);
  edge_mlp_kernel<256, 256><<<2048, 320, 0, stream>>>(u, v, idx, wbt4, b4b, xcat, 256);
  // head
  pool1_kernel<<<dim3(16, 8), 256, 0, stream>>>(xcat, part);
  pool2_kernel<<<16, 256, 0, stream>>>(part, pooled);
  lin1_kernel<<<64, 256, 0, stream>>>(pooled, lin1_w, lin1_b, h);
  bn_kernel<<<4, 256, 0, stream>>>(h, gamma, beta, h2);
  lin2_kernel<<<16, 64, 0, stream>>>(h2, lin2_w, lin2_b, out);
}

// Round 12
// 737.696 us; speedup vs baseline: 1.2257x; 1.0532x over previous
//
#include <hip/hip_runtime.h>
#include <hip/hip_bf16.h>

#define B_   16
#define N_   1024
#define KNN  20
#define NP   (B_ * N_)   // 16384

typedef short bf16x8 __attribute__((ext_vector_type(8)));
typedef float f32x4  __attribute__((ext_vector_type(4)));
typedef float f32x16 __attribute__((ext_vector_type(16)));

__device__ __forceinline__ unsigned short f2bf(float f) {
  unsigned u = __float_as_uint(f);
  u += 0x7fffu + ((u >> 16) & 1u);   // RNE
  return (unsigned short)(u >> 16);
}

// ---------------------------------------------------------------------------
// Pairwise squared distances, Gram form, emitted as PACKED u32 SORT KEYS:
//   key[i][j] = (float_bits(max(d,0)) & 0xFFFFFC00) | j
// v2: squared norms FUSED — waves 0/1 accumulate sqi/sqj in registers during
// the c-tile loop (ascending c, bit-identical to the old sqnorm kernel),
// written to a small LDS stub at the end. Kills the sqnorm dispatch + array.
// ---------------------------------------------------------------------------
__global__ __launch_bounds__(256) void pairdist_kernel(
    const float* __restrict__ X, int LD, int coff, int C,
    unsigned* __restrict__ Dk) {
  __shared__ float Xi[16][68];
  __shared__ float Xj[16][68];
  __shared__ float sqi_s[64], sqj_s[64];
  int b  = blockIdx.z;
  int i0 = blockIdx.y * 64, j0 = blockIdx.x * 64;
  int t  = threadIdx.x;
  int tx = t & 15, ty = t >> 4;
  float acc[4][4] = {};
  float sqacc = 0.f;     // t<64: ||x_i||^2 row t ; t in [64,128): ||x_j||^2
  for (int c0 = 0; c0 < C; c0 += 16) {
    int cc = min(16, C - c0);
    if (tx < cc) {
      for (int r = ty; r < 64; r += 16) {
        Xi[tx][r] = X[(size_t)(b * N_ + i0 + r) * LD + coff + c0 + tx];
        Xj[tx][r] = X[(size_t)(b * N_ + j0 + r) * LD + coff + c0 + tx];
      }
    }
    __syncthreads();
    if (t < 64) {
      for (int c = 0; c < cc; ++c) sqacc = fmaf(Xi[c][t], Xi[c][t], sqacc);
    } else if (t < 128) {
      int r = t - 64;
      for (int c = 0; c < cc; ++c) sqacc = fmaf(Xj[c][r], Xj[c][r], sqacc);
    }
    for (int c = 0; c < cc; ++c) {
      float4 a4 = *(const float4*)&Xi[c][ty * 4];
      float4 b4 = *(const float4*)&Xj[c][tx * 4];
      float a[4] = {a4.x, a4.y, a4.z, a4.w};
      float bb[4] = {b4.x, b4.y, b4.z, b4.w};
#pragma unroll
      for (int p = 0; p < 4; ++p)
#pragma unroll
        for (int q = 0; q < 4; ++q)
          acc[p][q] = fmaf(a[p], bb[q], acc[p][q]);
    }
    __syncthreads();
  }
  if (t < 64) sqi_s[t] = sqacc;
  else if (t < 128) sqj_s[t - 64] = sqacc;
  __syncthreads();
  float sqi[4], sqj[4];
#pragma unroll
  for (int p = 0; p < 4; ++p) sqi[p] = sqi_s[ty * 4 + p];
#pragma unroll
  for (int q = 0; q < 4; ++q) sqj[q] = sqj_s[tx * 4 + q];
#pragma unroll
  for (int p = 0; p < 4; ++p) {
    uint4 st;
    unsigned* kk = (unsigned*)&st;
#pragma unroll
    for (int q = 0; q < 4; ++q) {
      float d = fmaxf((sqi[p] - 2.f * acc[p][q]) + sqj[q], 0.f);
      kk[q] = (__float_as_uint(d) & 0xFFFFFC00u) | (unsigned)(j0 + tx * 4 + q);
    }
    *(uint4*)&Dk[(size_t)(b * N_ + i0 + ty * 4 + p) * N_ + j0 + tx * 4] = st;
  }
}

// ---------------------------------------------------------------------------
// Top-K=20 smallest keys per point. One wave per point, u32 keys.
// ---------------------------------------------------------------------------
__global__ __launch_bounds__(256) void topk_kernel(
    const unsigned* __restrict__ Dk, int* __restrict__ idx) {
  int w = threadIdx.x >> 6, lane = threadIdx.x & 63;
  int p = blockIdx.x * 4 + w;
  const unsigned* row = Dk + (size_t)p * N_;
  unsigned key[16];
#pragma unroll
  for (int s = 0; s < 16; ++s) key[s] = row[lane + 64 * s];
  int base = p & ~(N_ - 1);
  for (int k = 0; k < KNN; ++k) {
    unsigned m = key[0];
#pragma unroll
    for (int s = 1; s < 16; ++s) m = min(m, key[s]);
#pragma unroll
    for (int off = 32; off >= 1; off >>= 1)
      m = min(m, (unsigned)__shfl_xor((int)m, off));
    int j = (int)(m & 1023u);
    if (lane == 0) idx[p * KNN + k] = base + j;
    if ((j & 63) == lane) key[j >> 6] = 0xFFFFFFFFu;
  }
}

// ---------------------------------------------------------------------------
// Per-point transform: u = x@(Wa_top - Wa_bot) + ba ; v = x@Wa_bot
// fp32 accumulate, bf16 out. X rows staged in LDS.
// ---------------------------------------------------------------------------
__global__ __launch_bounds__(256) void transform_kernel(
    const float* __restrict__ X, int LD, int coff, int Cin, int Cmid,
    const float* __restrict__ Wa, const float* __restrict__ ba,
    unsigned short* __restrict__ u, unsigned short* __restrict__ v) {
  __shared__ float xs[16 * 128];
  int w = threadIdx.x >> 6, lane = threadIdx.x & 63;
  int m  = blockIdx.y * 64 + lane;
  int p0 = blockIdx.x * 16;
  if ((Cin & 3) == 0) {
    for (int i = threadIdx.x; i < 16 * (Cin / 4); i += 256) {
      int pt = i / (Cin / 4), q = i - pt * (Cin / 4);
      *(float4*)&xs[pt * Cin + q * 4] =
          *(const float4*)&X[(size_t)(p0 + pt) * LD + coff + q * 4];
    }
  } else {
    for (int i = threadIdx.x; i < 16 * Cin; i += 256) {
      int pt = i / Cin, c = i - pt * Cin;
      xs[pt * Cin + c] = X[(size_t)(p0 + pt) * LD + coff + c];
    }
  }
  __syncthreads();
  const float* xw = xs + (w * 4) * Cin;
  float ua[4] = {0.f, 0.f, 0.f, 0.f}, va[4] = {0.f, 0.f, 0.f, 0.f};
  for (int c = 0; c < Cin; ++c) {
    float wt = Wa[(size_t)c * Cmid + m];
    float wb = Wa[(size_t)(Cin + c) * Cmid + m];
    float wd = wt - wb;
#pragma unroll
    for (int i = 0; i < 4; ++i) {
      float xv = xw[i * Cin + c];
      ua[i] = fmaf(xv, wd, ua[i]);
      va[i] = fmaf(xv, wb, va[i]);
    }
  }
  float bias = ba[m];
#pragma unroll
  for (int i = 0; i < 4; ++i) {
    u[(size_t)(p0 + w * 4 + i) * Cmid + m] = f2bf(ua[i] + bias);
    v[(size_t)(p0 + w * 4 + i) * Cmid + m] = f2bf(va[i]);
  }
}

// ---------------------------------------------------------------------------
// Batched transpose+convert of all four Wb (Cmid x Cout, fp32) -> bf16 WbT
// (row-major Cout x Cmid). grid.z selects layer.
// ---------------------------------------------------------------------------
__global__ __launch_bounds__(256) void cvtw4_kernel(
    const float* __restrict__ W0, const float* __restrict__ W1,
    const float* __restrict__ W2, const float* __restrict__ W3,
    unsigned short* __restrict__ o0, unsigned short* __restrict__ o1,
    unsigned short* __restrict__ o2, unsigned short* __restrict__ o3) {
  __shared__ unsigned short tile[32][33];
  int z = blockIdx.z;
  const float* W; unsigned short* out; int Cmid, Cout;
  if (z == 0)      { W = W0; out = o0; Cmid = 64;  Cout = 64;  }
  else if (z == 1) { W = W1; out = o1; Cmid = 64;  Cout = 64;  }
  else if (z == 2) { W = W2; out = o2; Cmid = 128; Cout = 128; }
  else             { W = W3; out = o3; Cmid = 256; Cout = 256; }
  int c0 = blockIdx.x * 32, co0 = blockIdx.y * 32;
  if (c0 >= Cmid || co0 >= Cout) return;
  int tx = threadIdx.x & 31, ty = threadIdx.x >> 5;   // 32 x 8
  for (int r = ty; r < 32; r += 8)
    tile[r][tx] = f2bf(W[(size_t)(c0 + r) * Cout + co0 + tx]);
  __syncthreads();
  for (int r = ty; r < 32; r += 8)
    out[(size_t)(co0 + r) * Cmid + c0 + tx] = tile[tx][r];
}

// ---------------------------------------------------------------------------
// Edge MLP second GEMM + max-aggregate (round-7 proven optimum: two-barrier
// LDS W staging, VGPR 52, occupancy ~20%, L4 = 99us; r6/r8/r9/r10/r11
// variants all regressed — see session journal).
// mfma_f32_32x32x16_bf16; block: 320 threads (5 waves) = 160 edges = 8 points.
// A-frags (relu(u_p+v_j) bf16) built in regs from global, cached across groups.
// ---------------------------------------------------------------------------
template<int Cmid, int Cout, int CG>
__global__ __launch_bounds__(320, 4) void edge_mlp_kernel(
    const unsigned short* __restrict__ u, const unsigned short* __restrict__ v,
    const int* __restrict__ idx,
    const unsigned short* __restrict__ wbt, const float* __restrict__ bb,
    float* __restrict__ xcat, int coff) {
  constexpr int AP = Cmid + 8;
  constexpr int T  = CG / 32;      // 32-col tiles per group
  constexpr int KC = Cmid / 16;    // k chunks of 16
  constexpr int G  = Cout / CG;    // col groups
  __shared__ __align__(16) unsigned short W_lds[CG * AP];
  __shared__ float qmax[40 * CG];
  int tid = threadIdx.x, w = tid >> 6, lane = tid & 63;
  int col = lane & 31, half = lane >> 5;

  int rg = blockIdx.x * 160 + w * 32 + col;
  int p  = rg / 20;
  int j  = idx[rg];
  const unsigned short* up = u + (size_t)p * Cmid + half * 8;
  const unsigned short* vp = v + (size_t)j * Cmid + half * 8;

  bf16x8 afr[KC];
#pragma unroll
  for (int c = 0; c < KC; ++c) {
    union { int4 i; __hip_bfloat162 h[4]; bf16x8 vec; } U, V, R;
    U.i = *(const int4*)(up + c * 16);
    V.i = *(const int4*)(vp + c * 16);
#pragma unroll
    for (int q = 0; q < 4; ++q) {
      float2 a = __bfloat1622float2(U.h[q]);
      float2 b = __bfloat1622float2(V.h[q]);
      R.h[q] = __float22bfloat162_rn({fmaxf(a.x + b.x, 0.f), fmaxf(a.y + b.y, 0.f)});
    }
    afr[c] = R.vec;
  }

  int brow = col * AP + half * 8;

  for (int g = 0; g < G; ++g) {
    __syncthreads();
    for (int i = tid; i < CG * (Cmid / 8); i += 320) {
      int rr = i / (Cmid / 8), q = i - rr * (Cmid / 8);
      *(int4*)&W_lds[rr * AP + q * 8] =
          *(const int4*)&wbt[(size_t)(g * CG + rr) * Cmid + q * 8];
    }
    __syncthreads();
    f32x16 acc[T] = {};
#pragma unroll
    for (int c = 0; c < KC; ++c) {
#pragma unroll
      for (int t = 0; t < T; ++t) {
        bf16x8 bf = *(const bf16x8*)&W_lds[brow + t * 32 * AP + c * 16];
        acc[t] = __builtin_amdgcn_mfma_f32_32x32x16_bf16(afr[c], bf, acc[t], 0, 0, 0);
      }
    }
#pragma unroll
    for (int t = 0; t < T; ++t) {
#pragma unroll
      for (int Q = 0; Q < 4; ++Q) {
        float m0 = fmaxf(fmaxf(acc[t][4 * Q], acc[t][4 * Q + 1]),
                         fmaxf(acc[t][4 * Q + 2], acc[t][4 * Q + 3]));
        qmax[(w * 8 + 2 * Q + half) * CG + t * 32 + col] = m0;
      }
    }
    __syncthreads();
    for (int i = tid; i < 8 * CG; i += 320) {
      int pl = i / CG, c2 = i - pl * CG;
      float mm = qmax[(pl * 5 + 0) * CG + c2];
#pragma unroll
      for (int qq = 1; qq < 5; ++qq) mm = fmaxf(mm, qmax[(pl * 5 + qq) * CG + c2]);
      int pg = blockIdx.x * 8 + pl;
      xcat[(size_t)pg * 512 + coff + g * CG + c2] = mm + bb[g * CG + c2];
    }
  }
}

// ---------------------------------------------------------------------------
// Global max pool, two-stage coalesced.
// ---------------------------------------------------------------------------
__global__ __launch_bounds__(256) void pool1_kernel(const float* __restrict__ xcat,
                                                    float* __restrict__ part) {
  int b = blockIdx.x, g = blockIdx.y, t = threadIdx.x;
  const float* base = xcat + ((size_t)b * N_ + g * 128) * 512 + t * 2;
  float mx = -__builtin_inff(), my = -__builtin_inff();
#pragma unroll 4
  for (int r = 0; r < 128; ++r) {
    float2 vv = *(const float2*)(base + (size_t)r * 512);
    mx = fmaxf(mx, vv.x);
    my = fmaxf(my, vv.y);
  }
  *(float2*)&part[((size_t)b * 8 + g) * 512 + t * 2] = make_float2(mx, my);
}

__global__ __launch_bounds__(256) void pool2_kernel(const float* __restrict__ part,
                                                    float* __restrict__ pooled) {
  int b = blockIdx.x, t = threadIdx.x;
  float2 m = *(const float2*)&part[(size_t)b * 8 * 512 + t * 2];
#pragma unroll
  for (int g = 1; g < 8; ++g) {
    float2 vv = *(const float2*)&part[((size_t)b * 8 + g) * 512 + t * 2];
    m.x = fmaxf(m.x, vv.x);
    m.y = fmaxf(m.y, vv.y);
  }
  *(float2*)&pooled[b * 512 + t * 2] = m;
}

__global__ __launch_bounds__(256) void lin1_kernel(const float* __restrict__ pooled,
                                                   const float* __restrict__ W,
                                                   const float* __restrict__ bias,
                                                   float* __restrict__ h) {
  int flat = blockIdx.x * 256 + threadIdx.x;
  int b = flat >> 10, m = flat & 1023;
  float s = 0.f;
  for (int c = 0; c < 512; ++c) s = fmaf(pooled[b * 512 + c], W[(size_t)c * 1024 + m], s);
  h[flat] = s + bias[m];
}

__global__ __launch_bounds__(256) void bn_kernel(const float* __restrict__ h,
                                                 const float* __restrict__ gamma,
                                                 const float* __restrict__ beta,
                                                 float* __restrict__ h2) {
  int m = blockIdx.x * 256 + threadIdx.x;
  float s = 0.f;
  for (int b = 0; b < 16; ++b) s += h[b * 1024 + m];
  float mu = s * (1.f / 16.f);
  float vv = 0.f;
  for (int b = 0; b < 16; ++b) { float d = h[b * 1024 + m] - mu; vv = fmaf(d, d, vv); }
  vv *= (1.f / 16.f);
  float rstd = rsqrtf(vv + 1e-5f);
  float g = gamma[m] * rstd, be = beta[m];
  for (int b = 0; b < 16; ++b) {
    float val = (h[b * 1024 + m] - mu) * g + be;
    h2[b * 1024 + m] = fmaxf(val, 0.f);
  }
}

__global__ __launch_bounds__(64) void lin2_kernel(const float* __restrict__ h2,
                                                  const float* __restrict__ W,
                                                  const float* __restrict__ bias,
                                                  float* __restrict__ out) {
  int b = blockIdx.x, lane = threadIdx.x;
  float logit = 0.f;
  if (lane < 40) {
    logit = bias[lane];
    for (int c = 0; c < 1024; ++c)
      logit = fmaf(h2[b * 1024 + c], W[(size_t)c * 40 + lane], logit);
  }
  float mv = (lane < 40) ? logit : -__builtin_inff();
#pragma unroll
  for (int off = 32; off >= 1; off >>= 1) mv = fmaxf(mv, __shfl_xor(mv, off));
  float e = (lane < 40) ? expf(logit - mv) : 0.f;
#pragma unroll
  for (int off = 32; off >= 1; off >>= 1) e += __shfl_xor(e, off);
  float lse = mv + logf(e);
  if (lane < 40) out[b * 40 + lane] = logit - lse;
}

// ---------------------------------------------------------------------------
extern "C" void kernel_launch(void* const* d_in, const int* in_sizes, int n_in,
                              void* d_out, int out_size, void* d_ws, size_t ws_size,
                              hipStream_t stream) {
  const float* pos    = (const float*)d_in[0];
  const float* W1a = (const float*)d_in[2];  const float* b1a = (const float*)d_in[3];
  const float* W1b = (const float*)d_in[4];  const float* b1b = (const float*)d_in[5];
  const float* W2a = (const float*)d_in[6];  const float* b2a = (const float*)d_in[7];
  const float* W2b = (const float*)d_in[8];  const float* b2b = (const float*)d_in[9];
  const float* W3a = (const float*)d_in[10]; const float* b3a = (const float*)d_in[11];
  const float* W3b = (const float*)d_in[12]; const float* b3b = (const float*)d_in[13];
  const float* W4a = (const float*)d_in[14]; const float* b4a = (const float*)d_in[15];
  const float* W4b = (const float*)d_in[16]; const float* b4b = (const float*)d_in[17];
  const float* lin1_w = (const float*)d_in[18]; const float* lin1_b = (const float*)d_in[19];
  const float* gamma  = (const float*)d_in[20]; const float* beta   = (const float*)d_in[21];
  const float* lin2_w = (const float*)d_in[22]; const float* lin2_b = (const float*)d_in[23];
  float* out = (float*)d_out;

  char* ws = (char*)d_ws;
  size_t off = 0;
  auto alloc = [&](size_t bytes) {
    void* p = ws + off; off += (bytes + 255) & ~(size_t)255; return p;
  };
  float*    xcat = (float*)alloc((size_t)NP * 512 * 4);   // 32 MB
  unsigned* Dk   = (unsigned*)alloc((size_t)NP * N_ * 4); // 64 MB (u/v alias inside)
  int*      idx  = (int*)alloc((size_t)NP * KNN * 4);
  unsigned short* wbt1 = (unsigned short*)alloc(64 * 64 * 2);
  unsigned short* wbt2 = (unsigned short*)alloc(64 * 64 * 2);
  unsigned short* wbt3 = (unsigned short*)alloc(128 * 128 * 2);
  unsigned short* wbt4 = (unsigned short*)alloc(256 * 256 * 2);
  float* h      = (float*)alloc(16 * 1024 * 4);
  float* h2     = (float*)alloc(16 * 1024 * 4);
  float* pooled = (float*)alloc(16 * 512 * 4);
  float* part   = (float*)alloc(16 * 8 * 512 * 4);
  unsigned short* u = (unsigned short*)Dk;             // bf16, aliases Dk
  unsigned short* v = (unsigned short*)Dk + (size_t)NP * 256;

  cvtw4_kernel<<<dim3(8, 8, 4), 256, 0, stream>>>(W1b, W2b, W3b, W4b,
                                                  wbt1, wbt2, wbt3, wbt4);

  dim3 pd_grid(16, 16, 16);
  // layer 1: in pos (C=3) -> xcat[:,0:64]
  pairdist_kernel<<<pd_grid, 256, 0, stream>>>(pos, 3, 0, 3, Dk);
  topk_kernel<<<NP / 4, 256, 0, stream>>>(Dk, idx);
  transform_kernel<<<dim3(NP / 16, 1), 256, 0, stream>>>(pos, 3, 0, 3, 64, W1a, b1a, u, v);
  edge_mlp_kernel<64, 64, 64><<<2048, 320, 0, stream>>>(u, v, idx, wbt1, b1b, xcat, 0);
  // layer 2: in xcat[:,0:64] -> xcat[:,64:128]
  pairdist_kernel<<<pd_grid, 256, 0, stream>>>(xcat, 512, 0, 64, Dk);
  topk_kernel<<<NP / 4, 256, 0, stream>>>(Dk, idx);
  transform_kernel<<<dim3(NP / 16, 1), 256, 0, stream>>>(xcat, 512, 0, 64, 64, W2a, b2a, u, v);
  edge_mlp_kernel<64, 64, 64><<<2048, 320, 0, stream>>>(u, v, idx, wbt2, b2b, xcat, 64);
  // layer 3: in xcat[:,64:128] -> xcat[:,128:256]
  pairdist_kernel<<<pd_grid, 256, 0, stream>>>(xcat, 512, 64, 64, Dk);
  topk_kernel<<<NP / 4, 256, 0, stream>>>(Dk, idx);
  transform_kernel<<<dim3(NP / 16, 2), 256, 0, stream>>>(xcat, 512, 64, 64, 128, W3a, b3a, u, v);
  edge_mlp_kernel<128, 128, 64><<<2048, 320, 0, stream>>>(u, v, idx, wbt3, b3b, xcat, 128);
  // layer 4: in xcat[:,128:256] -> xcat[:,256:512]
  pairdist_kernel<<<pd_grid, 256, 0, stream>>>(xcat, 512, 128, 128, Dk);
  topk_kernel<<<NP / 4, 256, 0, stream>>>(Dk, idx);
  transform_kernel<<<dim3(NP / 16, 4), 256, 0, stream>>>(xcat, 512, 128, 128, 256, W4a, b4a, u, v);
  edge_mlp_kernel<256, 256, 32><<<2048, 320, 0, stream>>>(u, v, idx, wbt4, b4b, xcat, 256);
  // head
  pool1_kernel<<<dim3(16, 8), 256, 0, stream>>>(xcat, part);
  pool2_kernel<<<16, 256, 0, stream>>>(part, pooled);
  lin1_kernel<<<64, 256, 0, stream>>>(pooled, lin1_w, lin1_b, h);
  bn_kernel<<<4, 256, 0, stream>>>(h, gamma, beta, h2);
  lin2_kernel<<<16, 64, 0, stream>>>(h2, lin2_w, lin2_b, out);
}

// Round 13
// 729.073 us; speedup vs baseline: 1.2402x; 1.0118x over previous
//
#include <hip/hip_runtime.h>
#include <hip/hip_bf16.h>

#define B_   16
#define N_   1024
#define KNN  20
#define NP   (B_ * N_)   // 16384

typedef short bf16x8 __attribute__((ext_vector_type(8)));
typedef float f32x4  __attribute__((ext_vector_type(4)));
typedef float f32x16 __attribute__((ext_vector_type(16)));

__device__ __forceinline__ unsigned short f2bf(float f) {
  unsigned u = __float_as_uint(f);
  u += 0x7fffu + ((u >> 16) & 1u);   // RNE
  return (unsigned short)(u >> 16);
}

// ---------------------------------------------------------------------------
// Pairwise squared distances, Gram form, emitted as PACKED u32 SORT KEYS:
//   key[i][j] = (float_bits(max(d,0)) & 0xFFFFFC00) | j
// Squared norms fused (waves 0/1, ascending-c, bit-identical to a separate
// sqnorm pass).
// ---------------------------------------------------------------------------
__global__ __launch_bounds__(256) void pairdist_kernel(
    const float* __restrict__ X, int LD, int coff, int C,
    unsigned* __restrict__ Dk) {
  __shared__ float Xi[16][68];
  __shared__ float Xj[16][68];
  __shared__ float sqi_s[64], sqj_s[64];
  int b  = blockIdx.z;
  int i0 = blockIdx.y * 64, j0 = blockIdx.x * 64;
  int t  = threadIdx.x;
  int tx = t & 15, ty = t >> 4;
  float acc[4][4] = {};
  float sqacc = 0.f;     // t<64: ||x_i||^2 row t ; t in [64,128): ||x_j||^2
  for (int c0 = 0; c0 < C; c0 += 16) {
    int cc = min(16, C - c0);
    if (tx < cc) {
      for (int r = ty; r < 64; r += 16) {
        Xi[tx][r] = X[(size_t)(b * N_ + i0 + r) * LD + coff + c0 + tx];
        Xj[tx][r] = X[(size_t)(b * N_ + j0 + r) * LD + coff + c0 + tx];
      }
    }
    __syncthreads();
    if (t < 64) {
      for (int c = 0; c < cc; ++c) sqacc = fmaf(Xi[c][t], Xi[c][t], sqacc);
    } else if (t < 128) {
      int r = t - 64;
      for (int c = 0; c < cc; ++c) sqacc = fmaf(Xj[c][r], Xj[c][r], sqacc);
    }
    for (int c = 0; c < cc; ++c) {
      float4 a4 = *(const float4*)&Xi[c][ty * 4];
      float4 b4 = *(const float4*)&Xj[c][tx * 4];
      float a[4] = {a4.x, a4.y, a4.z, a4.w};
      float bb[4] = {b4.x, b4.y, b4.z, b4.w};
#pragma unroll
      for (int p = 0; p < 4; ++p)
#pragma unroll
        for (int q = 0; q < 4; ++q)
          acc[p][q] = fmaf(a[p], bb[q], acc[p][q]);
    }
    __syncthreads();
  }
  if (t < 64) sqi_s[t] = sqacc;
  else if (t < 128) sqj_s[t - 64] = sqacc;
  __syncthreads();
  float sqi[4], sqj[4];
#pragma unroll
  for (int p = 0; p < 4; ++p) sqi[p] = sqi_s[ty * 4 + p];
#pragma unroll
  for (int q = 0; q < 4; ++q) sqj[q] = sqj_s[tx * 4 + q];
#pragma unroll
  for (int p = 0; p < 4; ++p) {
    uint4 st;
    unsigned* kk = (unsigned*)&st;
#pragma unroll
    for (int q = 0; q < 4; ++q) {
      float d = fmaxf((sqi[p] - 2.f * acc[p][q]) + sqj[q], 0.f);
      kk[q] = (__float_as_uint(d) & 0xFFFFFC00u) | (unsigned)(j0 + tx * 4 + q);
    }
    *(uint4*)&Dk[(size_t)(b * N_ + i0 + ty * 4 + p) * N_ + j0 + tx * 4] = st;
  }
}

// ---------------------------------------------------------------------------
// Top-K=20 smallest keys per point. One wave per point, u32 keys.
// ---------------------------------------------------------------------------
__global__ __launch_bounds__(256) void topk_kernel(
    const unsigned* __restrict__ Dk, int* __restrict__ idx) {
  int w = threadIdx.x >> 6, lane = threadIdx.x & 63;
  int p = blockIdx.x * 4 + w;
  const unsigned* row = Dk + (size_t)p * N_;
  unsigned key[16];
#pragma unroll
  for (int s = 0; s < 16; ++s) key[s] = row[lane + 64 * s];
  int base = p & ~(N_ - 1);
  for (int k = 0; k < KNN; ++k) {
    unsigned m = key[0];
#pragma unroll
    for (int s = 1; s < 16; ++s) m = min(m, key[s]);
#pragma unroll
    for (int off = 32; off >= 1; off >>= 1)
      m = min(m, (unsigned)__shfl_xor((int)m, off));
    int j = (int)(m & 1023u);
    if (lane == 0) idx[p * KNN + k] = base + j;
    if ((j & 63) == lane) key[j >> 6] = 0xFFFFFFFFu;
  }
}

// ---------------------------------------------------------------------------
// Per-point transform: u = x@(Wa_top - Wa_bot) + ba ; v = x@Wa_bot
// fp32 accumulate, bf16 out. X rows staged in LDS.
// ---------------------------------------------------------------------------
__global__ __launch_bounds__(256) void transform_kernel(
    const float* __restrict__ X, int LD, int coff, int Cin, int Cmid,
    const float* __restrict__ Wa, const float* __restrict__ ba,
    unsigned short* __restrict__ u, unsigned short* __restrict__ v) {
  __shared__ float xs[16 * 128];
  int w = threadIdx.x >> 6, lane = threadIdx.x & 63;
  int m  = blockIdx.y * 64 + lane;
  int p0 = blockIdx.x * 16;
  if ((Cin & 3) == 0) {
    for (int i = threadIdx.x; i < 16 * (Cin / 4); i += 256) {
      int pt = i / (Cin / 4), q = i - pt * (Cin / 4);
      *(float4*)&xs[pt * Cin + q * 4] =
          *(const float4*)&X[(size_t)(p0 + pt) * LD + coff + q * 4];
    }
  } else {
    for (int i = threadIdx.x; i < 16 * Cin; i += 256) {
      int pt = i / Cin, c = i - pt * Cin;
      xs[pt * Cin + c] = X[(size_t)(p0 + pt) * LD + coff + c];
    }
  }
  __syncthreads();
  const float* xw = xs + (w * 4) * Cin;
  float ua[4] = {0.f, 0.f, 0.f, 0.f}, va[4] = {0.f, 0.f, 0.f, 0.f};
  for (int c = 0; c < Cin; ++c) {
    float wt = Wa[(size_t)c * Cmid + m];
    float wb = Wa[(size_t)(Cin + c) * Cmid + m];
    float wd = wt - wb;
#pragma unroll
    for (int i = 0; i < 4; ++i) {
      float xv = xw[i * Cin + c];
      ua[i] = fmaf(xv, wd, ua[i]);
      va[i] = fmaf(xv, wb, va[i]);
    }
  }
  float bias = ba[m];
#pragma unroll
  for (int i = 0; i < 4; ++i) {
    u[(size_t)(p0 + w * 4 + i) * Cmid + m] = f2bf(ua[i] + bias);
    v[(size_t)(p0 + w * 4 + i) * Cmid + m] = f2bf(va[i]);
  }
}

// ---------------------------------------------------------------------------
// Batched transpose+convert of all four Wb (Cmid x Cout, fp32) -> bf16 WbT
// (row-major Cout x Cmid). grid.z selects layer.
// ---------------------------------------------------------------------------
__global__ __launch_bounds__(256) void cvtw4_kernel(
    const float* __restrict__ W0, const float* __restrict__ W1,
    const float* __restrict__ W2, const float* __restrict__ W3,
    unsigned short* __restrict__ o0, unsigned short* __restrict__ o1,
    unsigned short* __restrict__ o2, unsigned short* __restrict__ o3) {
  __shared__ unsigned short tile[32][33];
  int z = blockIdx.z;
  const float* W; unsigned short* out; int Cmid, Cout;
  if (z == 0)      { W = W0; out = o0; Cmid = 64;  Cout = 64;  }
  else if (z == 1) { W = W1; out = o1; Cmid = 64;  Cout = 64;  }
  else if (z == 2) { W = W2; out = o2; Cmid = 128; Cout = 128; }
  else             { W = W3; out = o3; Cmid = 256; Cout = 256; }
  int c0 = blockIdx.x * 32, co0 = blockIdx.y * 32;
  if (c0 >= Cmid || co0 >= Cout) return;
  int tx = threadIdx.x & 31, ty = threadIdx.x >> 5;   // 32 x 8
  for (int r = ty; r < 32; r += 8)
    tile[r][tx] = f2bf(W[(size_t)(c0 + r) * Cout + co0 + tx]);
  __syncthreads();
  for (int r = ty; r < 32; r += 8)
    out[(size_t)(co0 + r) * Cmid + c0 + tx] = tile[tx][r];
}

// ---------------------------------------------------------------------------
// Edge MLP second GEMM + max-aggregate. v10 = r7 two-barrier structure with
// 640-THREAD BLOCKS (10 waves = 320 edges = 16 points, 1024 blocks):
// W-staging bytes per block unchanged but serve 2x the MFMA; per-thread
// registers identical (VGPR ~52), LDS 27-38KB -> ~3 blocks/CU = 30 waves
// (vs 6.4 at 320 threads) to hide the stage latency between barriers.
// ---------------------------------------------------------------------------
template<int Cmid, int Cout, int CG>
__global__ __launch_bounds__(640, 4) void edge_mlp_kernel(
    const unsigned short* __restrict__ u, const unsigned short* __restrict__ v,
    const int* __restrict__ idx,
    const unsigned short* __restrict__ wbt, const float* __restrict__ bb,
    float* __restrict__ xcat, int coff) {
  constexpr int AP = Cmid + 8;
  constexpr int T  = CG / 32;      // 32-col tiles per group
  constexpr int KC = Cmid / 16;    // k chunks of 16
  constexpr int G  = Cout / CG;    // col groups
  __shared__ __align__(16) unsigned short W_lds[CG * AP];
  __shared__ float qmax[80 * CG];
  int tid = threadIdx.x, w = tid >> 6, lane = tid & 63;
  int col = lane & 31, half = lane >> 5;

  int rg = blockIdx.x * 320 + w * 32 + col;
  int p  = rg / 20;
  int j  = idx[rg];
  const unsigned short* up = u + (size_t)p * Cmid + half * 8;
  const unsigned short* vp = v + (size_t)j * Cmid + half * 8;

  bf16x8 afr[KC];
#pragma unroll
  for (int c = 0; c < KC; ++c) {
    union { int4 i; __hip_bfloat162 h[4]; bf16x8 vec; } U, V, R;
    U.i = *(const int4*)(up + c * 16);
    V.i = *(const int4*)(vp + c * 16);
#pragma unroll
    for (int q = 0; q < 4; ++q) {
      float2 a = __bfloat1622float2(U.h[q]);
      float2 b = __bfloat1622float2(V.h[q]);
      R.h[q] = __float22bfloat162_rn({fmaxf(a.x + b.x, 0.f), fmaxf(a.y + b.y, 0.f)});
    }
    afr[c] = R.vec;
  }

  int brow = col * AP + half * 8;

  for (int g = 0; g < G; ++g) {
    __syncthreads();
    for (int i = tid; i < CG * (Cmid / 8); i += 640) {
      int rr = i / (Cmid / 8), q = i - rr * (Cmid / 8);
      *(int4*)&W_lds[rr * AP + q * 8] =
          *(const int4*)&wbt[(size_t)(g * CG + rr) * Cmid + q * 8];
    }
    __syncthreads();
    f32x16 acc[T] = {};
#pragma unroll
    for (int c = 0; c < KC; ++c) {
#pragma unroll
      for (int t = 0; t < T; ++t) {
        bf16x8 bf = *(const bf16x8*)&W_lds[brow + t * 32 * AP + c * 16];
        acc[t] = __builtin_amdgcn_mfma_f32_32x32x16_bf16(afr[c], bf, acc[t], 0, 0, 0);
      }
    }
#pragma unroll
    for (int t = 0; t < T; ++t) {
#pragma unroll
      for (int Q = 0; Q < 4; ++Q) {
        float m0 = fmaxf(fmaxf(acc[t][4 * Q], acc[t][4 * Q + 1]),
                         fmaxf(acc[t][4 * Q + 2], acc[t][4 * Q + 3]));
        qmax[(w * 8 + 2 * Q + half) * CG + t * 32 + col] = m0;
      }
    }
    __syncthreads();
    for (int i = tid; i < 16 * CG; i += 640) {
      int pl = i / CG, c2 = i - pl * CG;
      float mm = qmax[(pl * 5 + 0) * CG + c2];
#pragma unroll
      for (int qq = 1; qq < 5; ++qq) mm = fmaxf(mm, qmax[(pl * 5 + qq) * CG + c2]);
      int pg = blockIdx.x * 16 + pl;
      xcat[(size_t)pg * 512 + coff + g * CG + c2] = mm + bb[g * CG + c2];
    }
  }
}

// ---------------------------------------------------------------------------
// Global max pool, two-stage coalesced.
// ---------------------------------------------------------------------------
__global__ __launch_bounds__(256) void pool1_kernel(const float* __restrict__ xcat,
                                                    float* __restrict__ part) {
  int b = blockIdx.x, g = blockIdx.y, t = threadIdx.x;
  const float* base = xcat + ((size_t)b * N_ + g * 128) * 512 + t * 2;
  float mx = -__builtin_inff(), my = -__builtin_inff();
#pragma unroll 4
  for (int r = 0; r < 128; ++r) {
    float2 vv = *(const float2*)(base + (size_t)r * 512);
    mx = fmaxf(mx, vv.x);
    my = fmaxf(my, vv.y);
  }
  *(float2*)&part[((size_t)b * 8 + g) * 512 + t * 2] = make_float2(mx, my);
}

__global__ __launch_bounds__(256) void pool2_kernel(const float* __restrict__ part,
                                                    float* __restrict__ pooled) {
  int b = blockIdx.x, t = threadIdx.x;
  float2 m = *(const float2*)&part[(size_t)b * 8 * 512 + t * 2];
#pragma unroll
  for (int g = 1; g < 8; ++g) {
    float2 vv = *(const float2*)&part[((size_t)b * 8 + g) * 512 + t * 2];
    m.x = fmaxf(m.x, vv.x);
    m.y = fmaxf(m.y, vv.y);
  }
  *(float2*)&pooled[b * 512 + t * 2] = m;
}

__global__ __launch_bounds__(256) void lin1_kernel(const float* __restrict__ pooled,
                                                   const float* __restrict__ W,
                                                   const float* __restrict__ bias,
                                                   float* __restrict__ h) {
  int flat = blockIdx.x * 256 + threadIdx.x;
  int b = flat >> 10, m = flat & 1023;
  float s = 0.f;
  for (int c = 0; c < 512; ++c) s = fmaf(pooled[b * 512 + c], W[(size_t)c * 1024 + m], s);
  h[flat] = s + bias[m];
}

__global__ __launch_bounds__(256) void bn_kernel(const float* __restrict__ h,
                                                 const float* __restrict__ gamma,
                                                 const float* __restrict__ beta,
                                                 float* __restrict__ h2) {
  int m = blockIdx.x * 256 + threadIdx.x;
  float s = 0.f;
  for (int b = 0; b < 16; ++b) s += h[b * 1024 + m];
  float mu = s * (1.f / 16.f);
  float vv = 0.f;
  for (int b = 0; b < 16; ++b) { float d = h[b * 1024 + m] - mu; vv = fmaf(d, d, vv); }
  vv *= (1.f / 16.f);
  float rstd = rsqrtf(vv + 1e-5f);
  float g = gamma[m] * rstd, be = beta[m];
  for (int b = 0; b < 16; ++b) {
    float val = (h[b * 1024 + m] - mu) * g + be;
    h2[b * 1024 + m] = fmaxf(val, 0.f);
  }
}

__global__ __launch_bounds__(64) void lin2_kernel(const float* __restrict__ h2,
                                                  const float* __restrict__ W,
                                                  const float* __restrict__ bias,
                                                  float* __restrict__ out) {
  int b = blockIdx.x, lane = threadIdx.x;
  float logit = 0.f;
  if (lane < 40) {
    logit = bias[lane];
    for (int c = 0; c < 1024; ++c)
      logit = fmaf(h2[b * 1024 + c], W[(size_t)c * 40 + lane], logit);
  }
  float mv = (lane < 40) ? logit : -__builtin_inff();
#pragma unroll
  for (int off = 32; off >= 1; off >>= 1) mv = fmaxf(mv, __shfl_xor(mv, off));
  float e = (lane < 40) ? expf(logit - mv) : 0.f;
#pragma unroll
  for (int off = 32; off >= 1; off >>= 1) e += __shfl_xor(e, off);
  float lse = mv + logf(e);
  if (lane < 40) out[b * 40 + lane] = logit - lse;
}

// ---------------------------------------------------------------------------
extern "C" void kernel_launch(void* const* d_in, const int* in_sizes, int n_in,
                              void* d_out, int out_size, void* d_ws, size_t ws_size,
                              hipStream_t stream) {
  const float* pos    = (const float*)d_in[0];
  const float* W1a = (const float*)d_in[2];  const float* b1a = (const float*)d_in[3];
  const float* W1b = (const float*)d_in[4];  const float* b1b = (const float*)d_in[5];
  const float* W2a = (const float*)d_in[6];  const float* b2a = (const float*)d_in[7];
  const float* W2b = (const float*)d_in[8];  const float* b2b = (const float*)d_in[9];
  const float* W3a = (const float*)d_in[10]; const float* b3a = (const float*)d_in[11];
  const float* W3b = (const float*)d_in[12]; const float* b3b = (const float*)d_in[13];
  const float* W4a = (const float*)d_in[14]; const float* b4a = (const float*)d_in[15];
  const float* W4b = (const float*)d_in[16]; const float* b4b = (const float*)d_in[17];
  const float* lin1_w = (const float*)d_in[18]; const float* lin1_b = (const float*)d_in[19];
  const float* gamma  = (const float*)d_in[20]; const float* beta   = (const float*)d_in[21];
  const float* lin2_w = (const float*)d_in[22]; const float* lin2_b = (const float*)d_in[23];
  float* out = (float*)d_out;

  char* ws = (char*)d_ws;
  size_t off = 0;
  auto alloc = [&](size_t bytes) {
    void* p = ws + off; off += (bytes + 255) & ~(size_t)255; return p;
  };
  float*    xcat = (float*)alloc((size_t)NP * 512 * 4);   // 32 MB
  unsigned* Dk   = (unsigned*)alloc((size_t)NP * N_ * 4); // 64 MB (u/v alias inside)
  int*      idx  = (int*)alloc((size_t)NP * KNN * 4);
  unsigned short* wbt1 = (unsigned short*)alloc(64 * 64 * 2);
  unsigned short* wbt2 = (unsigned short*)alloc(64 * 64 * 2);
  unsigned short* wbt3 = (unsigned short*)alloc(128 * 128 * 2);
  unsigned short* wbt4 = (unsigned short*)alloc(256 * 256 * 2);
  float* h      = (float*)alloc(16 * 1024 * 4);
  float* h2     = (float*)alloc(16 * 1024 * 4);
  float* pooled = (float*)alloc(16 * 512 * 4);
  float* part   = (float*)alloc(16 * 8 * 512 * 4);
  unsigned short* u = (unsigned short*)Dk;             // bf16, aliases Dk
  unsigned short* v = (unsigned short*)Dk + (size_t)NP * 256;

  cvtw4_kernel<<<dim3(8, 8, 4), 256, 0, stream>>>(W1b, W2b, W3b, W4b,
                                                  wbt1, wbt2, wbt3, wbt4);

  dim3 pd_grid(16, 16, 16);
  // layer 1: in pos (C=3) -> xcat[:,0:64]
  pairdist_kernel<<<pd_grid, 256, 0, stream>>>(pos, 3, 0, 3, Dk);
  topk_kernel<<<NP / 4, 256, 0, stream>>>(Dk, idx);
  transform_kernel<<<dim3(NP / 16, 1), 256, 0, stream>>>(pos, 3, 0, 3, 64, W1a, b1a, u, v);
  edge_mlp_kernel<64, 64, 64><<<1024, 640, 0, stream>>>(u, v, idx, wbt1, b1b, xcat, 0);
  // layer 2: in xcat[:,0:64] -> xcat[:,64:128]
  pairdist_kernel<<<pd_grid, 256, 0, stream>>>(xcat, 512, 0, 64, Dk);
  topk_kernel<<<NP / 4, 256, 0, stream>>>(Dk, idx);
  transform_kernel<<<dim3(NP / 16, 1), 256, 0, stream>>>(xcat, 512, 0, 64, 64, W2a, b2a, u, v);
  edge_mlp_kernel<64, 64, 64><<<1024, 640, 0, stream>>>(u, v, idx, wbt2, b2b, xcat, 64);
  // layer 3: in xcat[:,64:128] -> xcat[:,128:256]
  pairdist_kernel<<<pd_grid, 256, 0, stream>>>(xcat, 512, 64, 64, Dk);
  topk_kernel<<<NP / 4, 256, 0, stream>>>(Dk, idx);
  transform_kernel<<<dim3(NP / 16, 2), 256, 0, stream>>>(xcat, 512, 64, 64, 128, W3a, b3a, u, v);
  edge_mlp_kernel<128, 128, 64><<<1024, 640, 0, stream>>>(u, v, idx, wbt3, b3b, xcat, 128);
  // layer 4: in xcat[:,128:256] -> xcat[:,256:512]
  pairdist_kernel<<<pd_grid, 256, 0, stream>>>(xcat, 512, 128, 128, Dk);
  topk_kernel<<<NP / 4, 256, 0, stream>>>(Dk, idx);
  transform_kernel<<<dim3(NP / 16, 4), 256, 0, stream>>>(xcat, 512, 128, 128, 256, W4a, b4a, u, v);
  edge_mlp_kernel<256, 256, 32><<<1024, 640, 0, stream>>>(u, v, idx, wbt4, b4b, xcat, 256);
  // head
  pool1_kernel<<<dim3(16, 8), 256, 0, stream>>>(xcat, part);
  pool2_kernel<<<16, 256, 0, stream>>>(part, pooled);
  lin1_kernel<<<64, 256, 0, stream>>>(pooled, lin1_w, lin1_b, h);
  bn_kernel<<<4, 256, 0, stream>>>(h, gamma, beta, h2);
  lin2_kernel<<<16, 64, 0, stream>>>(h2, lin2_w, lin2_b, out);
}

// Round 14
// 719.853 us; speedup vs baseline: 1.2561x; 1.0128x over previous
//
#include <hip/hip_runtime.h>
#include <hip/hip_bf16.h>

#define B_   16
#define N_   1024
#define KNN  20
#define NP   (B_ * N_)   // 16384

typedef short bf16x8 __attribute__((ext_vector_type(8)));
typedef float f32x4  __attribute__((ext_vector_type(4)));
typedef float f32x16 __attribute__((ext_vector_type(16)));

__device__ __forceinline__ unsigned short f2bf(float f) {
  unsigned u = __float_as_uint(f);
  u += 0x7fffu + ((u >> 16) & 1u);   // RNE
  return (unsigned short)(u >> 16);
}

// ---------------------------------------------------------------------------
// Pairwise squared distances, Gram form, emitted as PACKED u32 SORT KEYS:
//   key[i][j] = (float_bits(max(d,0)) & 0xFFFFFC00) | j
// Squared norms fused (waves 0/1, ascending-c, bit-identical to a separate
// sqnorm pass).
// ---------------------------------------------------------------------------
__global__ __launch_bounds__(256) void pairdist_kernel(
    const float* __restrict__ X, int LD, int coff, int C,
    unsigned* __restrict__ Dk) {
  __shared__ float Xi[16][68];
  __shared__ float Xj[16][68];
  __shared__ float sqi_s[64], sqj_s[64];
  int b  = blockIdx.z;
  int i0 = blockIdx.y * 64, j0 = blockIdx.x * 64;
  int t  = threadIdx.x;
  int tx = t & 15, ty = t >> 4;
  float acc[4][4] = {};
  float sqacc = 0.f;     // t<64: ||x_i||^2 row t ; t in [64,128): ||x_j||^2
  for (int c0 = 0; c0 < C; c0 += 16) {
    int cc = min(16, C - c0);
    if (tx < cc) {
      for (int r = ty; r < 64; r += 16) {
        Xi[tx][r] = X[(size_t)(b * N_ + i0 + r) * LD + coff + c0 + tx];
        Xj[tx][r] = X[(size_t)(b * N_ + j0 + r) * LD + coff + c0 + tx];
      }
    }
    __syncthreads();
    if (t < 64) {
      for (int c = 0; c < cc; ++c) sqacc = fmaf(Xi[c][t], Xi[c][t], sqacc);
    } else if (t < 128) {
      int r = t - 64;
      for (int c = 0; c < cc; ++c) sqacc = fmaf(Xj[c][r], Xj[c][r], sqacc);
    }
    for (int c = 0; c < cc; ++c) {
      float4 a4 = *(const float4*)&Xi[c][ty * 4];
      float4 b4 = *(const float4*)&Xj[c][tx * 4];
      float a[4] = {a4.x, a4.y, a4.z, a4.w};
      float bb[4] = {b4.x, b4.y, b4.z, b4.w};
#pragma unroll
      for (int p = 0; p < 4; ++p)
#pragma unroll
        for (int q = 0; q < 4; ++q)
          acc[p][q] = fmaf(a[p], bb[q], acc[p][q]);
    }
    __syncthreads();
  }
  if (t < 64) sqi_s[t] = sqacc;
  else if (t < 128) sqj_s[t - 64] = sqacc;
  __syncthreads();
  float sqi[4], sqj[4];
#pragma unroll
  for (int p = 0; p < 4; ++p) sqi[p] = sqi_s[ty * 4 + p];
#pragma unroll
  for (int q = 0; q < 4; ++q) sqj[q] = sqj_s[tx * 4 + q];
#pragma unroll
  for (int p = 0; p < 4; ++p) {
    uint4 st;
    unsigned* kk = (unsigned*)&st;
#pragma unroll
    for (int q = 0; q < 4; ++q) {
      float d = fmaxf((sqi[p] - 2.f * acc[p][q]) + sqj[q], 0.f);
      kk[q] = (__float_as_uint(d) & 0xFFFFFC00u) | (unsigned)(j0 + tx * 4 + q);
    }
    *(uint4*)&Dk[(size_t)(b * N_ + i0 + ty * 4 + p) * N_ + j0 + tx * 4] = st;
  }
}

// ---------------------------------------------------------------------------
// Top-K=20 smallest keys per point. One wave per point, u32 keys.
// ---------------------------------------------------------------------------
__global__ __launch_bounds__(256) void topk_kernel(
    const unsigned* __restrict__ Dk, int* __restrict__ idx) {
  int w = threadIdx.x >> 6, lane = threadIdx.x & 63;
  int p = blockIdx.x * 4 + w;
  const unsigned* row = Dk + (size_t)p * N_;
  unsigned key[16];
#pragma unroll
  for (int s = 0; s < 16; ++s) key[s] = row[lane + 64 * s];
  int base = p & ~(N_ - 1);
  for (int k = 0; k < KNN; ++k) {
    unsigned m = key[0];
#pragma unroll
    for (int s = 1; s < 16; ++s) m = min(m, key[s]);
#pragma unroll
    for (int off = 32; off >= 1; off >>= 1)
      m = min(m, (unsigned)__shfl_xor((int)m, off));
    int j = (int)(m & 1023u);
    if (lane == 0) idx[p * KNN + k] = base + j;
    if ((j & 63) == lane) key[j >> 6] = 0xFFFFFFFFu;
  }
}

// ---------------------------------------------------------------------------
// Per-point transform: u = x@(Wa_top - Wa_bot) + ba ; v = x@Wa_bot
// fp32 accumulate, bf16 out. X rows staged in LDS.
// ---------------------------------------------------------------------------
__global__ __launch_bounds__(256) void transform_kernel(
    const float* __restrict__ X, int LD, int coff, int Cin, int Cmid,
    const float* __restrict__ Wa, const float* __restrict__ ba,
    unsigned short* __restrict__ u, unsigned short* __restrict__ v) {
  __shared__ float xs[16 * 128];
  int w = threadIdx.x >> 6, lane = threadIdx.x & 63;
  int m  = blockIdx.y * 64 + lane;
  int p0 = blockIdx.x * 16;
  if ((Cin & 3) == 0) {
    for (int i = threadIdx.x; i < 16 * (Cin / 4); i += 256) {
      int pt = i / (Cin / 4), q = i - pt * (Cin / 4);
      *(float4*)&xs[pt * Cin + q * 4] =
          *(const float4*)&X[(size_t)(p0 + pt) * LD + coff + q * 4];
    }
  } else {
    for (int i = threadIdx.x; i < 16 * Cin; i += 256) {
      int pt = i / Cin, c = i - pt * Cin;
      xs[pt * Cin + c] = X[(size_t)(p0 + pt) * LD + coff + c];
    }
  }
  __syncthreads();
  const float* xw = xs + (w * 4) * Cin;
  float ua[4] = {0.f, 0.f, 0.f, 0.f}, va[4] = {0.f, 0.f, 0.f, 0.f};
  for (int c = 0; c < Cin; ++c) {
    float wt = Wa[(size_t)c * Cmid + m];
    float wb = Wa[(size_t)(Cin + c) * Cmid + m];
    float wd = wt - wb;
#pragma unroll
    for (int i = 0; i < 4; ++i) {
      float xv = xw[i * Cin + c];
      ua[i] = fmaf(xv, wd, ua[i]);
      va[i] = fmaf(xv, wb, va[i]);
    }
  }
  float bias = ba[m];
#pragma unroll
  for (int i = 0; i < 4; ++i) {
    u[(size_t)(p0 + w * 4 + i) * Cmid + m] = f2bf(ua[i] + bias);
    v[(size_t)(p0 + w * 4 + i) * Cmid + m] = f2bf(va[i]);
  }
}

// ---------------------------------------------------------------------------
// Batched transpose+convert of all four Wb (Cmid x Cout, fp32) -> bf16 WbT
// (row-major Cout x Cmid). grid.z selects layer.
// ---------------------------------------------------------------------------
__global__ __launch_bounds__(256) void cvtw4_kernel(
    const float* __restrict__ W0, const float* __restrict__ W1,
    const float* __restrict__ W2, const float* __restrict__ W3,
    unsigned short* __restrict__ o0, unsigned short* __restrict__ o1,
    unsigned short* __restrict__ o2, unsigned short* __restrict__ o3) {
  __shared__ unsigned short tile[32][33];
  int z = blockIdx.z;
  const float* W; unsigned short* out; int Cmid, Cout;
  if (z == 0)      { W = W0; out = o0; Cmid = 64;  Cout = 64;  }
  else if (z == 1) { W = W1; out = o1; Cmid = 64;  Cout = 64;  }
  else if (z == 2) { W = W2; out = o2; Cmid = 128; Cout = 128; }
  else             { W = W3; out = o3; Cmid = 256; Cout = 256; }
  int c0 = blockIdx.x * 32, co0 = blockIdx.y * 32;
  if (c0 >= Cmid || co0 >= Cout) return;
  int tx = threadIdx.x & 31, ty = threadIdx.x >> 5;   // 32 x 8
  for (int r = ty; r < 32; r += 8)
    tile[r][tx] = f2bf(W[(size_t)(c0 + r) * Cout + co0 + tx]);
  __syncthreads();
  for (int r = ty; r < 32; r += 8)
    out[(size_t)(co0 + r) * Cmid + c0 + tx] = tile[tx][r];
}

// ---------------------------------------------------------------------------
// Edge MLP second GEMM + max-aggregate. v11 = r7 two-barrier structure with
// 960-THREAD BLOCKS (15 waves = 480 edges = 24 points, 683 blocks, tail
// block guarded): W-staging bytes per block unchanged but serve 3x the MFMA
// of the 320-thread original; per-thread registers identical (VGPR ~52),
// LDS 32-48KB -> 2 blocks/CU = 30 waves to hide stage latency.
// ---------------------------------------------------------------------------
template<int Cmid, int Cout, int CG>
__global__ __launch_bounds__(960, 3) void edge_mlp_kernel(
    const unsigned short* __restrict__ u, const unsigned short* __restrict__ v,
    const int* __restrict__ idx,
    const unsigned short* __restrict__ wbt, const float* __restrict__ bb,
    float* __restrict__ xcat, int coff) {
  constexpr int AP = Cmid + 8;
  constexpr int T  = CG / 32;      // 32-col tiles per group
  constexpr int KC = Cmid / 16;    // k chunks of 16
  constexpr int G  = Cout / CG;    // col groups
  __shared__ __align__(16) unsigned short W_lds[CG * AP];
  __shared__ float qmax[120 * CG];
  int tid = threadIdx.x, w = tid >> 6, lane = tid & 63;
  int col = lane & 31, half = lane >> 5;

  int rg = blockIdx.x * 480 + w * 32 + col;
  int rgc = min(rg, NP * KNN - 1);           // tail-block clamp (stores guarded)
  int p  = rgc / 20;
  int j  = idx[rgc];
  const unsigned short* up = u + (size_t)p * Cmid + half * 8;
  const unsigned short* vp = v + (size_t)j * Cmid + half * 8;

  bf16x8 afr[KC];
#pragma unroll
  for (int c = 0; c < KC; ++c) {
    union { int4 i; __hip_bfloat162 h[4]; bf16x8 vec; } U, V, R;
    U.i = *(const int4*)(up + c * 16);
    V.i = *(const int4*)(vp + c * 16);
#pragma unroll
    for (int q = 0; q < 4; ++q) {
      float2 a = __bfloat1622float2(U.h[q]);
      float2 b = __bfloat1622float2(V.h[q]);
      R.h[q] = __float22bfloat162_rn({fmaxf(a.x + b.x, 0.f), fmaxf(a.y + b.y, 0.f)});
    }
    afr[c] = R.vec;
  }

  int brow = col * AP + half * 8;

  for (int g = 0; g < G; ++g) {
    __syncthreads();
    for (int i = tid; i < CG * (Cmid / 8); i += 960) {
      int rr = i / (Cmid / 8), q = i - rr * (Cmid / 8);
      *(int4*)&W_lds[rr * AP + q * 8] =
          *(const int4*)&wbt[(size_t)(g * CG + rr) * Cmid + q * 8];
    }
    __syncthreads();
    f32x16 acc[T] = {};
#pragma unroll
    for (int c = 0; c < KC; ++c) {
#pragma unroll
      for (int t = 0; t < T; ++t) {
        bf16x8 bf = *(const bf16x8*)&W_lds[brow + t * 32 * AP + c * 16];
        acc[t] = __builtin_amdgcn_mfma_f32_32x32x16_bf16(afr[c], bf, acc[t], 0, 0, 0);
      }
    }
#pragma unroll
    for (int t = 0; t < T; ++t) {
#pragma unroll
      for (int Q = 0; Q < 4; ++Q) {
        float m0 = fmaxf(fmaxf(acc[t][4 * Q], acc[t][4 * Q + 1]),
                         fmaxf(acc[t][4 * Q + 2], acc[t][4 * Q + 3]));
        qmax[(w * 8 + 2 * Q + half) * CG + t * 32 + col] = m0;
      }
    }
    __syncthreads();
    for (int i = tid; i < 24 * CG; i += 960) {
      int pl = i / CG, c2 = i - pl * CG;
      int pg = blockIdx.x * 24 + pl;
      if (pg < NP) {
        float mm = qmax[(pl * 5 + 0) * CG + c2];
#pragma unroll
        for (int qq = 1; qq < 5; ++qq) mm = fmaxf(mm, qmax[(pl * 5 + qq) * CG + c2]);
        xcat[(size_t)pg * 512 + coff + g * CG + c2] = mm + bb[g * CG + c2];
      }
    }
  }
}

// ---------------------------------------------------------------------------
// Global max pool, two-stage coalesced.
// ---------------------------------------------------------------------------
__global__ __launch_bounds__(256) void pool1_kernel(const float* __restrict__ xcat,
                                                    float* __restrict__ part) {
  int b = blockIdx.x, g = blockIdx.y, t = threadIdx.x;
  const float* base = xcat + ((size_t)b * N_ + g * 128) * 512 + t * 2;
  float mx = -__builtin_inff(), my = -__builtin_inff();
#pragma unroll 4
  for (int r = 0; r < 128; ++r) {
    float2 vv = *(const float2*)(base + (size_t)r * 512);
    mx = fmaxf(mx, vv.x);
    my = fmaxf(my, vv.y);
  }
  *(float2*)&part[((size_t)b * 8 + g) * 512 + t * 2] = make_float2(mx, my);
}

__global__ __launch_bounds__(256) void pool2_kernel(const float* __restrict__ part,
                                                    float* __restrict__ pooled) {
  int b = blockIdx.x, t = threadIdx.x;
  float2 m = *(const float2*)&part[(size_t)b * 8 * 512 + t * 2];
#pragma unroll
  for (int g = 1; g < 8; ++g) {
    float2 vv = *(const float2*)&part[((size_t)b * 8 + g) * 512 + t * 2];
    m.x = fmaxf(m.x, vv.x);
    m.y = fmaxf(m.y, vv.y);
  }
  *(float2*)&pooled[b * 512 + t * 2] = m;
}

__global__ __launch_bounds__(256) void lin1_kernel(const float* __restrict__ pooled,
                                                   const float* __restrict__ W,
                                                   const float* __restrict__ bias,
                                                   float* __restrict__ h) {
  int flat = blockIdx.x * 256 + threadIdx.x;
  int b = flat >> 10, m = flat & 1023;
  float s = 0.f;
  for (int c = 0; c < 512; ++c) s = fmaf(pooled[b * 512 + c], W[(size_t)c * 1024 + m], s);
  h[flat] = s + bias[m];
}

__global__ __launch_bounds__(256) void bn_kernel(const float* __restrict__ h,
                                                 const float* __restrict__ gamma,
                                                 const float* __restrict__ beta,
                                                 float* __restrict__ h2) {
  int m = blockIdx.x * 256 + threadIdx.x;
  float s = 0.f;
  for (int b = 0; b < 16; ++b) s += h[b * 1024 + m];
  float mu = s * (1.f / 16.f);
  float vv = 0.f;
  for (int b = 0; b < 16; ++b) { float d = h[b * 1024 + m] - mu; vv = fmaf(d, d, vv); }
  vv *= (1.f / 16.f);
  float rstd = rsqrtf(vv + 1e-5f);
  float g = gamma[m] * rstd, be = beta[m];
  for (int b = 0; b < 16; ++b) {
    float val = (h[b * 1024 + m] - mu) * g + be;
    h2[b * 1024 + m] = fmaxf(val, 0.f);
  }
}

__global__ __launch_bounds__(64) void lin2_kernel(const float* __restrict__ h2,
                                                  const float* __restrict__ W,
                                                  const float* __restrict__ bias,
                                                  float* __restrict__ out) {
  int b = blockIdx.x, lane = threadIdx.x;
  float logit = 0.f;
  if (lane < 40) {
    logit = bias[lane];
    for (int c = 0; c < 1024; ++c)
      logit = fmaf(h2[b * 1024 + c], W[(size_t)c * 40 + lane], logit);
  }
  float mv = (lane < 40) ? logit : -__builtin_inff();
#pragma unroll
  for (int off = 32; off >= 1; off >>= 1) mv = fmaxf(mv, __shfl_xor(mv, off));
  float e = (lane < 40) ? expf(logit - mv) : 0.f;
#pragma unroll
  for (int off = 32; off >= 1; off >>= 1) e += __shfl_xor(e, off);
  float lse = mv + logf(e);
  if (lane < 40) out[b * 40 + lane] = logit - lse;
}

// ---------------------------------------------------------------------------
extern "C" void kernel_launch(void* const* d_in, const int* in_sizes, int n_in,
                              void* d_out, int out_size, void* d_ws, size_t ws_size,
                              hipStream_t stream) {
  const float* pos    = (const float*)d_in[0];
  const float* W1a = (const float*)d_in[2];  const float* b1a = (const float*)d_in[3];
  const float* W1b = (const float*)d_in[4];  const float* b1b = (const float*)d_in[5];
  const float* W2a = (const float*)d_in[6];  const float* b2a = (const float*)d_in[7];
  const float* W2b = (const float*)d_in[8];  const float* b2b = (const float*)d_in[9];
  const float* W3a = (const float*)d_in[10]; const float* b3a = (const float*)d_in[11];
  const float* W3b = (const float*)d_in[12]; const float* b3b = (const float*)d_in[13];
  const float* W4a = (const float*)d_in[14]; const float* b4a = (const float*)d_in[15];
  const float* W4b = (const float*)d_in[16]; const float* b4b = (const float*)d_in[17];
  const float* lin1_w = (const float*)d_in[18]; const float* lin1_b = (const float*)d_in[19];
  const float* gamma  = (const float*)d_in[20]; const float* beta   = (const float*)d_in[21];
  const float* lin2_w = (const float*)d_in[22]; const float* lin2_b = (const float*)d_in[23];
  float* out = (float*)d_out;

  char* ws = (char*)d_ws;
  size_t off = 0;
  auto alloc = [&](size_t bytes) {
    void* p = ws + off; off += (bytes + 255) & ~(size_t)255; return p;
  };
  float*    xcat = (float*)alloc((size_t)NP * 512 * 4);   // 32 MB
  unsigned* Dk   = (unsigned*)alloc((size_t)NP * N_ * 4); // 64 MB (u/v alias inside)
  int*      idx  = (int*)alloc((size_t)NP * KNN * 4);
  unsigned short* wbt1 = (unsigned short*)alloc(64 * 64 * 2);
  unsigned short* wbt2 = (unsigned short*)alloc(64 * 64 * 2);
  unsigned short* wbt3 = (unsigned short*)alloc(128 * 128 * 2);
  unsigned short* wbt4 = (unsigned short*)alloc(256 * 256 * 2);
  float* h      = (float*)alloc(16 * 1024 * 4);
  float* h2     = (float*)alloc(16 * 1024 * 4);
  float* pooled = (float*)alloc(16 * 512 * 4);
  float* part   = (float*)alloc(16 * 8 * 512 * 4);
  unsigned short* u = (unsigned short*)Dk;             // bf16, aliases Dk
  unsigned short* v = (unsigned short*)Dk + (size_t)NP * 256;

  cvtw4_kernel<<<dim3(8, 8, 4), 256, 0, stream>>>(W1b, W2b, W3b, W4b,
                                                  wbt1, wbt2, wbt3, wbt4);

  dim3 pd_grid(16, 16, 16);
  const int EB = (NP * KNN + 479) / 480;   // 683 edge blocks
  // layer 1: in pos (C=3) -> xcat[:,0:64]
  pairdist_kernel<<<pd_grid, 256, 0, stream>>>(pos, 3, 0, 3, Dk);
  topk_kernel<<<NP / 4, 256, 0, stream>>>(Dk, idx);
  transform_kernel<<<dim3(NP / 16, 1), 256, 0, stream>>>(pos, 3, 0, 3, 64, W1a, b1a, u, v);
  edge_mlp_kernel<64, 64, 64><<<EB, 960, 0, stream>>>(u, v, idx, wbt1, b1b, xcat, 0);
  // layer 2: in xcat[:,0:64] -> xcat[:,64:128]
  pairdist_kernel<<<pd_grid, 256, 0, stream>>>(xcat, 512, 0, 64, Dk);
  topk_kernel<<<NP / 4, 256, 0, stream>>>(Dk, idx);
  transform_kernel<<<dim3(NP / 16, 1), 256, 0, stream>>>(xcat, 512, 0, 64, 64, W2a, b2a, u, v);
  edge_mlp_kernel<64, 64, 64><<<EB, 960, 0, stream>>>(u, v, idx, wbt2, b2b, xcat, 64);
  // layer 3: in xcat[:,64:128] -> xcat[:,128:256]
  pairdist_kernel<<<pd_grid, 256, 0, stream>>>(xcat, 512, 64, 64, Dk);
  topk_kernel<<<NP / 4, 256, 0, stream>>>(Dk, idx);
  transform_kernel<<<dim3(NP / 16, 2), 256, 0, stream>>>(xcat, 512, 64, 64, 128, W3a, b3a, u, v);
  edge_mlp_kernel<128, 128, 64><<<EB, 960, 0, stream>>>(u, v, idx, wbt3, b3b, xcat, 128);
  // layer 4: in xcat[:,128:256] -> xcat[:,256:512]
  pairdist_kernel<<<pd_grid, 256, 0, stream>>>(xcat, 512, 128, 128, Dk);
  topk_kernel<<<NP / 4, 256, 0, stream>>>(Dk, idx);
  transform_kernel<<<dim3(NP / 16, 4), 256, 0, stream>>>(xcat, 512, 128, 128, 256, W4a, b4a, u, v);
  edge_mlp_kernel<256, 256, 32><<<EB, 960, 0, stream>>>(u, v, idx, wbt4, b4b, xcat, 256);
  // head
  pool1_kernel<<<dim3(16, 8), 256, 0, stream>>>(xcat, part);
  pool2_kernel<<<16, 256, 0, stream>>>(part, pooled);
  lin1_kernel<<<64, 256, 0, stream>>>(pooled, lin1_w, lin1_b, h);
  bn_kernel<<<4, 256, 0, stream>>>(h, gamma, beta, h2);
  lin2_kernel<<<16, 64, 0, stream>>>(h2, lin2_w, lin2_b, out);
}

// Round 15
// 669.091 us; speedup vs baseline: 1.3514x; 1.0759x over previous
//
#include <hip/hip_runtime.h>
#include <hip/hip_bf16.h>

#define B_   16
#define N_   1024
#define KNN  20
#define NP   (B_ * N_)   // 16384

typedef short bf16x8 __attribute__((ext_vector_type(8)));
typedef float f32x4  __attribute__((ext_vector_type(4)));
typedef float f32x16 __attribute__((ext_vector_type(16)));

__device__ __forceinline__ unsigned short f2bf(float f) {
  unsigned u = __float_as_uint(f);
  u += 0x7fffu + ((u >> 16) & 1u);   // RNE
  return (unsigned short)(u >> 16);
}

// ---------------------------------------------------------------------------
// Pairwise squared distances, Gram form, emitted as PACKED u32 SORT KEYS:
//   key[i][j] = (float_bits(max(d,0)) & 0xFFFFFC00) | j
// Squared norms fused (waves 0/1, ascending-c, bit-identical to a separate
// sqnorm pass).
// ---------------------------------------------------------------------------
__global__ __launch_bounds__(256) void pairdist_kernel(
    const float* __restrict__ X, int LD, int coff, int C,
    unsigned* __restrict__ Dk) {
  __shared__ float Xi[16][68];
  __shared__ float Xj[16][68];
  __shared__ float sqi_s[64], sqj_s[64];
  int b  = blockIdx.z;
  int i0 = blockIdx.y * 64, j0 = blockIdx.x * 64;
  int t  = threadIdx.x;
  int tx = t & 15, ty = t >> 4;
  float acc[4][4] = {};
  float sqacc = 0.f;     // t<64: ||x_i||^2 row t ; t in [64,128): ||x_j||^2
  for (int c0 = 0; c0 < C; c0 += 16) {
    int cc = min(16, C - c0);
    if (tx < cc) {
      for (int r = ty; r < 64; r += 16) {
        Xi[tx][r] = X[(size_t)(b * N_ + i0 + r) * LD + coff + c0 + tx];
        Xj[tx][r] = X[(size_t)(b * N_ + j0 + r) * LD + coff + c0 + tx];
      }
    }
    __syncthreads();
    if (t < 64) {
      for (int c = 0; c < cc; ++c) sqacc = fmaf(Xi[c][t], Xi[c][t], sqacc);
    } else if (t < 128) {
      int r = t - 64;
      for (int c = 0; c < cc; ++c) sqacc = fmaf(Xj[c][r], Xj[c][r], sqacc);
    }
    for (int c = 0; c < cc; ++c) {
      float4 a4 = *(const float4*)&Xi[c][ty * 4];
      float4 b4 = *(const float4*)&Xj[c][tx * 4];
      float a[4] = {a4.x, a4.y, a4.z, a4.w};
      float bb[4] = {b4.x, b4.y, b4.z, b4.w};
#pragma unroll
      for (int p = 0; p < 4; ++p)
#pragma unroll
        for (int q = 0; q < 4; ++q)
          acc[p][q] = fmaf(a[p], bb[q], acc[p][q]);
    }
    __syncthreads();
  }
  if (t < 64) sqi_s[t] = sqacc;
  else if (t < 128) sqj_s[t - 64] = sqacc;
  __syncthreads();
  float sqi[4], sqj[4];
#pragma unroll
  for (int p = 0; p < 4; ++p) sqi[p] = sqi_s[ty * 4 + p];
#pragma unroll
  for (int q = 0; q < 4; ++q) sqj[q] = sqj_s[tx * 4 + q];
#pragma unroll
  for (int p = 0; p < 4; ++p) {
    uint4 st;
    unsigned* kk = (unsigned*)&st;
#pragma unroll
    for (int q = 0; q < 4; ++q) {
      float d = fmaxf((sqi[p] - 2.f * acc[p][q]) + sqj[q], 0.f);
      kk[q] = (__float_as_uint(d) & 0xFFFFFC00u) | (unsigned)(j0 + tx * 4 + q);
    }
    *(uint4*)&Dk[(size_t)(b * N_ + i0 + ty * 4 + p) * N_ + j0 + tx * 4] = st;
  }
}

// ---------------------------------------------------------------------------
// Top-K=20 smallest keys per point. One wave per point, u32 keys.
// ---------------------------------------------------------------------------
__global__ __launch_bounds__(256) void topk_kernel(
    const unsigned* __restrict__ Dk, int* __restrict__ idx) {
  int w = threadIdx.x >> 6, lane = threadIdx.x & 63;
  int p = blockIdx.x * 4 + w;
  const unsigned* row = Dk + (size_t)p * N_;
  unsigned key[16];
#pragma unroll
  for (int s = 0; s < 16; ++s) key[s] = row[lane + 64 * s];
  int base = p & ~(N_ - 1);
  for (int k = 0; k < KNN; ++k) {
    unsigned m = key[0];
#pragma unroll
    for (int s = 1; s < 16; ++s) m = min(m, key[s]);
#pragma unroll
    for (int off = 32; off >= 1; off >>= 1)
      m = min(m, (unsigned)__shfl_xor((int)m, off));
    int j = (int)(m & 1023u);
    if (lane == 0) idx[p * KNN + k] = base + j;
    if ((j & 63) == lane) key[j >> 6] = 0xFFFFFFFFu;
  }
}

// ---------------------------------------------------------------------------
// Scalar per-point transform (layer 1 only, Cin=3):
//   u = x@(Wa_top - Wa_bot) + ba ; v = x@Wa_bot  (fp32 acc, bf16 out)
// ---------------------------------------------------------------------------
__global__ __launch_bounds__(256) void transform_kernel(
    const float* __restrict__ X, int LD, int coff, int Cin, int Cmid,
    const float* __restrict__ Wa, const float* __restrict__ ba,
    unsigned short* __restrict__ u, unsigned short* __restrict__ v) {
  __shared__ float xs[16 * 128];
  int w = threadIdx.x >> 6, lane = threadIdx.x & 63;
  int m  = blockIdx.y * 64 + lane;
  int p0 = blockIdx.x * 16;
  for (int i = threadIdx.x; i < 16 * Cin; i += 256) {
    int pt = i / Cin, c = i - pt * Cin;
    xs[pt * Cin + c] = X[(size_t)(p0 + pt) * LD + coff + c];
  }
  __syncthreads();
  const float* xw = xs + (w * 4) * Cin;
  float ua[4] = {0.f, 0.f, 0.f, 0.f}, va[4] = {0.f, 0.f, 0.f, 0.f};
  for (int c = 0; c < Cin; ++c) {
    float wt = Wa[(size_t)c * Cmid + m];
    float wb = Wa[(size_t)(Cin + c) * Cmid + m];
    float wd = wt - wb;
#pragma unroll
    for (int i = 0; i < 4; ++i) {
      float xv = xw[i * Cin + c];
      ua[i] = fmaf(xv, wd, ua[i]);
      va[i] = fmaf(xv, wb, va[i]);
    }
  }
  float bias = ba[m];
#pragma unroll
  for (int i = 0; i < 4; ++i) {
    u[(size_t)(p0 + w * 4 + i) * Cmid + m] = f2bf(ua[i] + bias);
    v[(size_t)(p0 + w * 4 + i) * Cmid + m] = f2bf(va[i]);
  }
}

// ---------------------------------------------------------------------------
// Weight prep for MFMA transforms (layers 2-4): split Wa into
// Wd = Wa_top - Wa_bot and Wb = Wa_bot, both in FRAGMENT-MAJOR bf16:
//   out[((nt*KC + c)*64 + lane)*8 + j] = W[k][n],
//   n = nt*32 + (lane&31), k = c*16 + (lane>>5)*8 + j, KC = Cin/16.
// (same layout as r10's cvtw_swz — correctness-proven)
// ---------------------------------------------------------------------------
__global__ __launch_bounds__(256) void cvtwa_swz_kernel(
    const float* __restrict__ A2, const float* __restrict__ A3,
    const float* __restrict__ A4,
    unsigned short* __restrict__ d2, unsigned short* __restrict__ b2,
    unsigned short* __restrict__ d3, unsigned short* __restrict__ b3,
    unsigned short* __restrict__ d4, unsigned short* __restrict__ b4) {
  int z = blockIdx.z;
  const float* Wa; unsigned short *wd, *wb; int Cin, Cmid;
  if (z == 0)      { Wa = A2; wd = d2; wb = b2; Cin = 64;  Cmid = 64;  }
  else if (z == 1) { Wa = A3; wd = d3; wb = b3; Cin = 64;  Cmid = 128; }
  else             { Wa = A4; wd = d4; wb = b4; Cin = 128; Cmid = 256; }
  int KC = Cin / 16;
  int NC = (Cmid / 32) * KC * 64;
  int ci = blockIdx.x * 256 + threadIdx.x;
  if (ci >= NC) return;
  int ntc = ci >> 6, lane = ci & 63;
  int nt = ntc / KC, c = ntc - nt * KC;
  int n  = nt * 32 + (lane & 31);
  int kb = c * 16 + (lane >> 5) * 8;
#pragma unroll
  for (int j = 0; j < 8; ++j) {
    float top = Wa[(size_t)(kb + j) * Cmid + n];
    float bot = Wa[(size_t)(Cin + kb + j) * Cmid + n];
    wd[(size_t)ci * 8 + j] = f2bf(top - bot);
    wb[(size_t)ci * 8 + j] = f2bf(bot);
  }
}

// ---------------------------------------------------------------------------
// MFMA transform (layers 2-4): u = X@Wd + ba, v = X@Wb via 32x32x16 bf16.
// A-frag: row=lane&31, k=(lane>>5)*8+j (edge-verified layout), X fp32->bf16.
// B-frag: fragment-major global (1KB coalesced per load, L2-hot weights).
// C-store: row=(reg&3)+8*(reg>>2)+4*(lane>>5) (edge-verified).
// Grid: (NP/128, Cmid/32); block 256 = 4 waves x 32 points.
// ---------------------------------------------------------------------------
template<int Cin, int Cmid>
__global__ __launch_bounds__(256) void transform_mfma_kernel(
    const float* __restrict__ X, int LD, int coff,
    const unsigned short* __restrict__ wdf, const unsigned short* __restrict__ wbf,
    const float* __restrict__ ba,
    unsigned short* __restrict__ u, unsigned short* __restrict__ v) {
  constexpr int KC = Cin / 16;
  int wv = threadIdx.x >> 6, lane = threadIdx.x & 63;
  int row = lane & 31, half = lane >> 5;
  int p0 = blockIdx.x * 128 + wv * 32;
  int nt = blockIdx.y;

  // A-fragments: X[p0+row][k], k = c*16 + half*8 + j, fp32 -> bf16
  bf16x8 afr[KC];
  const float* xr = X + (size_t)(p0 + row) * LD + coff + half * 8;
#pragma unroll
  for (int c = 0; c < KC; ++c) {
    float4 x0 = *(const float4*)(xr + c * 16);
    float4 x1 = *(const float4*)(xr + c * 16 + 4);
    union { bf16x8 vec; __hip_bfloat162 h[4]; } pk;
    pk.h[0] = __float22bfloat162_rn({x0.x, x0.y});
    pk.h[1] = __float22bfloat162_rn({x0.z, x0.w});
    pk.h[2] = __float22bfloat162_rn({x1.x, x1.y});
    pk.h[3] = __float22bfloat162_rn({x1.z, x1.w});
    afr[c] = pk.vec;
  }

  const unsigned short* wdl = wdf + ((size_t)nt * KC * 64 + lane) * 8;
  const unsigned short* wbl = wbf + ((size_t)nt * KC * 64 + lane) * 8;
  f32x16 au = {}, av = {};
#pragma unroll
  for (int c = 0; c < KC; ++c) {
    bf16x8 bd = *(const bf16x8*)(wdl + (size_t)c * 512);
    au = __builtin_amdgcn_mfma_f32_32x32x16_bf16(afr[c], bd, au, 0, 0, 0);
  }
#pragma unroll
  for (int c = 0; c < KC; ++c) {
    bf16x8 bv = *(const bf16x8*)(wbl + (size_t)c * 512);
    av = __builtin_amdgcn_mfma_f32_32x32x16_bf16(afr[c], bv, av, 0, 0, 0);
  }

  int m = nt * 32 + row;            // output col (per lane)
  float bias = ba[m];
#pragma unroll
  for (int e = 0; e < 16; ++e) {
    int orow = (e & 3) + 8 * (e >> 2) + 4 * half;
    u[(size_t)(p0 + orow) * Cmid + m] = f2bf(au[e] + bias);
    v[(size_t)(p0 + orow) * Cmid + m] = f2bf(av[e]);
  }
}

// ---------------------------------------------------------------------------
// Batched transpose+convert of all four Wb (Cmid x Cout, fp32) -> bf16 WbT
// (row-major Cout x Cmid). grid.z selects layer.
// ---------------------------------------------------------------------------
__global__ __launch_bounds__(256) void cvtw4_kernel(
    const float* __restrict__ W0, const float* __restrict__ W1,
    const float* __restrict__ W2, const float* __restrict__ W3,
    unsigned short* __restrict__ o0, unsigned short* __restrict__ o1,
    unsigned short* __restrict__ o2, unsigned short* __restrict__ o3) {
  __shared__ unsigned short tile[32][33];
  int z = blockIdx.z;
  const float* W; unsigned short* out; int Cmid, Cout;
  if (z == 0)      { W = W0; out = o0; Cmid = 64;  Cout = 64;  }
  else if (z == 1) { W = W1; out = o1; Cmid = 64;  Cout = 64;  }
  else if (z == 2) { W = W2; out = o2; Cmid = 128; Cout = 128; }
  else             { W = W3; out = o3; Cmid = 256; Cout = 256; }
  int c0 = blockIdx.x * 32, co0 = blockIdx.y * 32;
  if (c0 >= Cmid || co0 >= Cout) return;
  int tx = threadIdx.x & 31, ty = threadIdx.x >> 5;   // 32 x 8
  for (int r = ty; r < 32; r += 8)
    tile[r][tx] = f2bf(W[(size_t)(c0 + r) * Cout + co0 + tx]);
  __syncthreads();
  for (int r = ty; r < 32; r += 8)
    out[(size_t)(co0 + r) * Cmid + c0 + tx] = tile[tx][r];
}

// ---------------------------------------------------------------------------
// Edge MLP second GEMM + max-aggregate. 960-thread two-barrier structure
// (r13/r14); L4 now CG=64 (G=4 stage rounds, LDS 63KB, T=2 acc).
// ---------------------------------------------------------------------------
template<int Cmid, int Cout, int CG>
__global__ __launch_bounds__(960, 3) void edge_mlp_kernel(
    const unsigned short* __restrict__ u, const unsigned short* __restrict__ v,
    const int* __restrict__ idx,
    const unsigned short* __restrict__ wbt, const float* __restrict__ bb,
    float* __restrict__ xcat, int coff) {
  constexpr int AP = Cmid + 8;
  constexpr int T  = CG / 32;      // 32-col tiles per group
  constexpr int KC = Cmid / 16;    // k chunks of 16
  constexpr int G  = Cout / CG;    // col groups
  __shared__ __align__(16) unsigned short W_lds[CG * AP];
  __shared__ float qmax[120 * CG];
  int tid = threadIdx.x, w = tid >> 6, lane = tid & 63;
  int col = lane & 31, half = lane >> 5;

  int rg = blockIdx.x * 480 + w * 32 + col;
  int rgc = min(rg, NP * KNN - 1);           // tail-block clamp (stores guarded)
  int p  = rgc / 20;
  int j  = idx[rgc];
  const unsigned short* up = u + (size_t)p * Cmid + half * 8;
  const unsigned short* vp = v + (size_t)j * Cmid + half * 8;

  bf16x8 afr[KC];
#pragma unroll
  for (int c = 0; c < KC; ++c) {
    union { int4 i; __hip_bfloat162 h[4]; bf16x8 vec; } U, V, R;
    U.i = *(const int4*)(up + c * 16);
    V.i = *(const int4*)(vp + c * 16);
#pragma unroll
    for (int q = 0; q < 4; ++q) {
      float2 a = __bfloat1622float2(U.h[q]);
      float2 b = __bfloat1622float2(V.h[q]);
      R.h[q] = __float22bfloat162_rn({fmaxf(a.x + b.x, 0.f), fmaxf(a.y + b.y, 0.f)});
    }
    afr[c] = R.vec;
  }

  int brow = col * AP + half * 8;

  for (int g = 0; g < G; ++g) {
    __syncthreads();
    for (int i = tid; i < CG * (Cmid / 8); i += 960) {
      int rr = i / (Cmid / 8), q = i - rr * (Cmid / 8);
      *(int4*)&W_lds[rr * AP + q * 8] =
          *(const int4*)&wbt[(size_t)(g * CG + rr) * Cmid + q * 8];
    }
    __syncthreads();
    f32x16 acc[T] = {};
#pragma unroll
    for (int c = 0; c < KC; ++c) {
#pragma unroll
      for (int t = 0; t < T; ++t) {
        bf16x8 bf = *(const bf16x8*)&W_lds[brow + t * 32 * AP + c * 16];
        acc[t] = __builtin_amdgcn_mfma_f32_32x32x16_bf16(afr[c], bf, acc[t], 0, 0, 0);
      }
    }
#pragma unroll
    for (int t = 0; t < T; ++t) {
#pragma unroll
      for (int Q = 0; Q < 4; ++Q) {
        float m0 = fmaxf(fmaxf(acc[t][4 * Q], acc[t][4 * Q + 1]),
                         fmaxf(acc[t][4 * Q + 2], acc[t][4 * Q + 3]));
        qmax[(w * 8 + 2 * Q + half) * CG + t * 32 + col] = m0;
      }
    }
    __syncthreads();
    for (int i = tid; i < 24 * CG; i += 960) {
      int pl = i / CG, c2 = i - pl * CG;
      int pg = blockIdx.x * 24 + pl;
      if (pg < NP) {
        float mm = qmax[(pl * 5 + 0) * CG + c2];
#pragma unroll
        for (int qq = 1; qq < 5; ++qq) mm = fmaxf(mm, qmax[(pl * 5 + qq) * CG + c2]);
        xcat[(size_t)pg * 512 + coff + g * CG + c2] = mm + bb[g * CG + c2];
      }
    }
  }
}

// ---------------------------------------------------------------------------
// Global max pool, two-stage coalesced.
// ---------------------------------------------------------------------------
__global__ __launch_bounds__(256) void pool1_kernel(const float* __restrict__ xcat,
                                                    float* __restrict__ part) {
  int b = blockIdx.x, g = blockIdx.y, t = threadIdx.x;
  const float* base = xcat + ((size_t)b * N_ + g * 128) * 512 + t * 2;
  float mx = -__builtin_inff(), my = -__builtin_inff();
#pragma unroll 4
  for (int r = 0; r < 128; ++r) {
    float2 vv = *(const float2*)(base + (size_t)r * 512);
    mx = fmaxf(mx, vv.x);
    my = fmaxf(my, vv.y);
  }
  *(float2*)&part[((size_t)b * 8 + g) * 512 + t * 2] = make_float2(mx, my);
}

__global__ __launch_bounds__(256) void pool2_kernel(const float* __restrict__ part,
                                                    float* __restrict__ pooled) {
  int b = blockIdx.x, t = threadIdx.x;
  float2 m = *(const float2*)&part[(size_t)b * 8 * 512 + t * 2];
#pragma unroll
  for (int g = 1; g < 8; ++g) {
    float2 vv = *(const float2*)&part[((size_t)b * 8 + g) * 512 + t * 2];
    m.x = fmaxf(m.x, vv.x);
    m.y = fmaxf(m.y, vv.y);
  }
  *(float2*)&pooled[b * 512 + t * 2] = m;
}

__global__ __launch_bounds__(256) void lin1_kernel(const float* __restrict__ pooled,
                                                   const float* __restrict__ W,
                                                   const float* __restrict__ bias,
                                                   float* __restrict__ h) {
  int flat = blockIdx.x * 256 + threadIdx.x;
  int b = flat >> 10, m = flat & 1023;
  float s = 0.f;
  for (int c = 0; c < 512; ++c) s = fmaf(pooled[b * 512 + c], W[(size_t)c * 1024 + m], s);
  h[flat] = s + bias[m];
}

__global__ __launch_bounds__(256) void bn_kernel(const float* __restrict__ h,
                                                 const float* __restrict__ gamma,
                                                 const float* __restrict__ beta,
                                                 float* __restrict__ h2) {
  int m = blockIdx.x * 256 + threadIdx.x;
  float s = 0.f;
  for (int b = 0; b < 16; ++b) s += h[b * 1024 + m];
  float mu = s * (1.f / 16.f);
  float vv = 0.f;
  for (int b = 0; b < 16; ++b) { float d = h[b * 1024 + m] - mu; vv = fmaf(d, d, vv); }
  vv *= (1.f / 16.f);
  float rstd = rsqrtf(vv + 1e-5f);
  float g = gamma[m] * rstd, be = beta[m];
  for (int b = 0; b < 16; ++b) {
    float val = (h[b * 1024 + m] - mu) * g + be;
    h2[b * 1024 + m] = fmaxf(val, 0.f);
  }
}

__global__ __launch_bounds__(64) void lin2_kernel(const float* __restrict__ h2,
                                                  const float* __restrict__ W,
                                                  const float* __restrict__ bias,
                                                  float* __restrict__ out) {
  int b = blockIdx.x, lane = threadIdx.x;
  float logit = 0.f;
  if (lane < 40) {
    logit = bias[lane];
    for (int c = 0; c < 1024; ++c)
      logit = fmaf(h2[b * 1024 + c], W[(size_t)c * 40 + lane], logit);
  }
  float mv = (lane < 40) ? logit : -__builtin_inff();
#pragma unroll
  for (int off = 32; off >= 1; off >>= 1) mv = fmaxf(mv, __shfl_xor(mv, off));
  float e = (lane < 40) ? expf(logit - mv) : 0.f;
#pragma unroll
  for (int off = 32; off >= 1; off >>= 1) e += __shfl_xor(e, off);
  float lse = mv + logf(e);
  if (lane < 40) out[b * 40 + lane] = logit - lse;
}

// ---------------------------------------------------------------------------
extern "C" void kernel_launch(void* const* d_in, const int* in_sizes, int n_in,
                              void* d_out, int out_size, void* d_ws, size_t ws_size,
                              hipStream_t stream) {
  const float* pos    = (const float*)d_in[0];
  const float* W1a = (const float*)d_in[2];  const float* b1a = (const float*)d_in[3];
  const float* W1b = (const float*)d_in[4];  const float* b1b = (const float*)d_in[5];
  const float* W2a = (const float*)d_in[6];  const float* b2a = (const float*)d_in[7];
  const float* W2b = (const float*)d_in[8];  const float* b2b = (const float*)d_in[9];
  const float* W3a = (const float*)d_in[10]; const float* b3a = (const float*)d_in[11];
  const float* W3b = (const float*)d_in[12]; const float* b3b = (const float*)d_in[13];
  const float* W4a = (const float*)d_in[14]; const float* b4a = (const float*)d_in[15];
  const float* W4b = (const float*)d_in[16]; const float* b4b = (const float*)d_in[17];
  const float* lin1_w = (const float*)d_in[18]; const float* lin1_b = (const float*)d_in[19];
  const float* gamma  = (const float*)d_in[20]; const float* beta   = (const float*)d_in[21];
  const float* lin2_w = (const float*)d_in[22]; const float* lin2_b = (const float*)d_in[23];
  float* out = (float*)d_out;

  char* ws = (char*)d_ws;
  size_t off = 0;
  auto alloc = [&](size_t bytes) {
    void* p = ws + off; off += (bytes + 255) & ~(size_t)255; return p;
  };
  float*    xcat = (float*)alloc((size_t)NP * 512 * 4);   // 32 MB
  unsigned* Dk   = (unsigned*)alloc((size_t)NP * N_ * 4); // 64 MB (u/v alias inside)
  int*      idx  = (int*)alloc((size_t)NP * KNN * 4);
  unsigned short* wbt1 = (unsigned short*)alloc(64 * 64 * 2);
  unsigned short* wbt2 = (unsigned short*)alloc(64 * 64 * 2);
  unsigned short* wbt3 = (unsigned short*)alloc(128 * 128 * 2);
  unsigned short* wbt4 = (unsigned short*)alloc(256 * 256 * 2);
  unsigned short* wd2 = (unsigned short*)alloc(64 * 64 * 2);
  unsigned short* wb2 = (unsigned short*)alloc(64 * 64 * 2);
  unsigned short* wd3 = (unsigned short*)alloc(64 * 128 * 2);
  unsigned short* wb3 = (unsigned short*)alloc(64 * 128 * 2);
  unsigned short* wd4 = (unsigned short*)alloc(128 * 256 * 2);
  unsigned short* wb4 = (unsigned short*)alloc(128 * 256 * 2);
  float* h      = (float*)alloc(16 * 1024 * 4);
  float* h2     = (float*)alloc(16 * 1024 * 4);
  float* pooled = (float*)alloc(16 * 512 * 4);
  float* part   = (float*)alloc(16 * 8 * 512 * 4);
  unsigned short* u = (unsigned short*)Dk;             // bf16, aliases Dk
  unsigned short* v = (unsigned short*)Dk + (size_t)NP * 256;

  cvtw4_kernel<<<dim3(8, 8, 4), 256, 0, stream>>>(W1b, W2b, W3b, W4b,
                                                  wbt1, wbt2, wbt3, wbt4);
  cvtwa_swz_kernel<<<dim3(16, 1, 3), 256, 0, stream>>>(W2a, W3a, W4a,
                                                       wd2, wb2, wd3, wb3, wd4, wb4);

  dim3 pd_grid(16, 16, 16);
  const int EB = (NP * KNN + 479) / 480;   // 683 edge blocks
  // layer 1: in pos (C=3) -> xcat[:,0:64]
  pairdist_kernel<<<pd_grid, 256, 0, stream>>>(pos, 3, 0, 3, Dk);
  topk_kernel<<<NP / 4, 256, 0, stream>>>(Dk, idx);
  transform_kernel<<<dim3(NP / 16, 1), 256, 0, stream>>>(pos, 3, 0, 3, 64, W1a, b1a, u, v);
  edge_mlp_kernel<64, 64, 64><<<EB, 960, 0, stream>>>(u, v, idx, wbt1, b1b, xcat, 0);
  // layer 2: in xcat[:,0:64] -> xcat[:,64:128]
  pairdist_kernel<<<pd_grid, 256, 0, stream>>>(xcat, 512, 0, 64, Dk);
  topk_kernel<<<NP / 4, 256, 0, stream>>>(Dk, idx);
  transform_mfma_kernel<64, 64><<<dim3(NP / 128, 2), 256, 0, stream>>>(
      xcat, 512, 0, wd2, wb2, b2a, u, v);
  edge_mlp_kernel<64, 64, 64><<<EB, 960, 0, stream>>>(u, v, idx, wbt2, b2b, xcat, 64);
  // layer 3: in xcat[:,64:128] -> xcat[:,128:256]
  pairdist_kernel<<<pd_grid, 256, 0, stream>>>(xcat, 512, 64, 64, Dk);
  topk_kernel<<<NP / 4, 256, 0, stream>>>(Dk, idx);
  transform_mfma_kernel<64, 128><<<dim3(NP / 128, 4), 256, 0, stream>>>(
      xcat, 512, 64, wd3, wb3, b3a, u, v);
  edge_mlp_kernel<128, 128, 64><<<EB, 960, 0, stream>>>(u, v, idx, wbt3, b3b, xcat, 128);
  // layer 4: in xcat[:,128:256] -> xcat[:,256:512]
  pairdist_kernel<<<pd_grid, 256, 0, stream>>>(xcat, 512, 128, 128, Dk);
  topk_kernel<<<NP / 4, 256, 0, stream>>>(Dk, idx);
  transform_mfma_kernel<128, 256><<<dim3(NP / 128, 8), 256, 0, stream>>>(
      xcat, 512, 128, wd4, wb4, b4a, u, v);
  edge_mlp_kernel<256, 256, 64><<<EB, 960, 0, stream>>>(u, v, idx, wbt4, b4b, xcat, 256);
  // head
  pool1_kernel<<<dim3(16, 8), 256, 0, stream>>>(xcat, part);
  pool2_kernel<<<16, 256, 0, stream>>>(part, pooled);
  lin1_kernel<<<64, 256, 0, stream>>>(pooled, lin1_w, lin1_b, h);
  bn_kernel<<<4, 256, 0, stream>>>(h, gamma, beta, h2);
  lin2_kernel<<<16, 64, 0, stream>>>(h2, lin2_w, lin2_b, out);
}

// Round 16
// 663.279 us; speedup vs baseline: 1.3632x; 1.0088x over previous
//
#include <hip/hip_runtime.h>
#include <hip/hip_bf16.h>

#define B_   16
#define N_   1024
#define KNN  20
#define NP   (B_ * N_)   // 16384

typedef short bf16x8 __attribute__((ext_vector_type(8)));
typedef float f32x4  __attribute__((ext_vector_type(4)));
typedef float f32x16 __attribute__((ext_vector_type(16)));

__device__ __forceinline__ unsigned short f2bf(float f) {
  unsigned u = __float_as_uint(f);
  u += 0x7fffu + ((u >> 16) & 1u);   // RNE
  return (unsigned short)(u >> 16);
}

// ---------------------------------------------------------------------------
// Pairwise squared distances, Gram form, PACKED u32 SORT KEYS:
//   key[i][j] = (float_bits(max(d,0)) & 0xFFFFFC00) | j
// v3: SYMMETRIC — only blocks with bx >= by compute (47% less FMA); the
// off-diagonal tile is also emitted TRANSPOSED (key repacked with i-index)
// via an LDS transpose overlaying the dead Xi/Xj buffers. fma(a,b)=fma(b,a)
// with identical c-order => both triangles are bit-identical to the full
// computation. Squared norms fused as before (bit-identical).
// ---------------------------------------------------------------------------
__global__ __launch_bounds__(256) void pairdist_kernel(
    const float* __restrict__ X, int LD, int coff, int C,
    unsigned* __restrict__ Dk) {
  if (blockIdx.x < blockIdx.y) return;          // lower-left blocks: covered by transpose
  __shared__ __align__(16) char pd_smem[64 * 68 * 4];   // Xi+Xj (8.5KB) / Tt (17.4KB)
  __shared__ float sqi_s[64], sqj_s[64];
  float (*Xi)[68] = (float(*)[68])pd_smem;
  float (*Xj)[68] = (float(*)[68])(pd_smem + 16 * 68 * 4);
  unsigned (*Tt)[68] = (unsigned(*)[68])pd_smem;
  int b  = blockIdx.z;
  int i0 = blockIdx.y * 64, j0 = blockIdx.x * 64;
  int t  = threadIdx.x;
  int tx = t & 15, ty = t >> 4;
  float acc[4][4] = {};
  float sqacc = 0.f;     // t<64: ||x_i||^2 row t ; t in [64,128): ||x_j||^2
  for (int c0 = 0; c0 < C; c0 += 16) {
    int cc = min(16, C - c0);
    if (tx < cc) {
      for (int r = ty; r < 64; r += 16) {
        Xi[tx][r] = X[(size_t)(b * N_ + i0 + r) * LD + coff + c0 + tx];
        Xj[tx][r] = X[(size_t)(b * N_ + j0 + r) * LD + coff + c0 + tx];
      }
    }
    __syncthreads();
    if (t < 64) {
      for (int c = 0; c < cc; ++c) sqacc = fmaf(Xi[c][t], Xi[c][t], sqacc);
    } else if (t < 128) {
      int r = t - 64;
      for (int c = 0; c < cc; ++c) sqacc = fmaf(Xj[c][r], Xj[c][r], sqacc);
    }
    for (int c = 0; c < cc; ++c) {
      float4 a4 = *(const float4*)&Xi[c][ty * 4];
      float4 b4 = *(const float4*)&Xj[c][tx * 4];
      float a[4] = {a4.x, a4.y, a4.z, a4.w};
      float bb[4] = {b4.x, b4.y, b4.z, b4.w};
#pragma unroll
      for (int p = 0; p < 4; ++p)
#pragma unroll
        for (int q = 0; q < 4; ++q)
          acc[p][q] = fmaf(a[p], bb[q], acc[p][q]);
    }
    __syncthreads();
  }
  if (t < 64) sqi_s[t] = sqacc;
  else if (t < 128) sqj_s[t - 64] = sqacc;
  __syncthreads();                    // also: all Xi/Xj reads done -> Tt may overlay
  float sqi[4], sqj[4];
#pragma unroll
  for (int p = 0; p < 4; ++p) sqi[p] = sqi_s[ty * 4 + p];
#pragma unroll
  for (int q = 0; q < 4; ++q) sqj[q] = sqj_s[tx * 4 + q];
  bool offdiag = (blockIdx.x > blockIdx.y);
#pragma unroll
  for (int p = 0; p < 4; ++p) {
    uint4 st;
    unsigned* kk = (unsigned*)&st;
#pragma unroll
    for (int q = 0; q < 4; ++q) {
      float d = fmaxf((sqi[p] - 2.f * acc[p][q]) + sqj[q], 0.f);
      unsigned db = __float_as_uint(d) & 0xFFFFFC00u;
      kk[q] = db | (unsigned)(j0 + tx * 4 + q);
      if (offdiag)
        Tt[tx * 4 + q][ty * 4 + p] = db | (unsigned)(i0 + ty * 4 + p);
    }
    *(uint4*)&Dk[(size_t)(b * N_ + i0 + ty * 4 + p) * N_ + j0 + tx * 4] = st;
  }
  if (offdiag) {
    __syncthreads();
#pragma unroll
    for (int p = 0; p < 4; ++p) {
      *(uint4*)&Dk[(size_t)(b * N_ + j0 + ty * 4 + p) * N_ + i0 + tx * 4] =
          *(uint4*)&Tt[ty * 4 + p][tx * 4];
    }
  }
}

// ---------------------------------------------------------------------------
// Top-K=20 smallest keys per point. One wave per point, u32 keys.
// ---------------------------------------------------------------------------
__global__ __launch_bounds__(256) void topk_kernel(
    const unsigned* __restrict__ Dk, int* __restrict__ idx) {
  int w = threadIdx.x >> 6, lane = threadIdx.x & 63;
  int p = blockIdx.x * 4 + w;
  const unsigned* row = Dk + (size_t)p * N_;
  unsigned key[16];
#pragma unroll
  for (int s = 0; s < 16; ++s) key[s] = row[lane + 64 * s];
  int base = p & ~(N_ - 1);
  for (int k = 0; k < KNN; ++k) {
    unsigned m = key[0];
#pragma unroll
    for (int s = 1; s < 16; ++s) m = min(m, key[s]);
#pragma unroll
    for (int off = 32; off >= 1; off >>= 1)
      m = min(m, (unsigned)__shfl_xor((int)m, off));
    int j = (int)(m & 1023u);
    if (lane == 0) idx[p * KNN + k] = base + j;
    if ((j & 63) == lane) key[j >> 6] = 0xFFFFFFFFu;
  }
}

// ---------------------------------------------------------------------------
// Scalar per-point transform (layer 1 only, Cin=3):
//   u = x@(Wa_top - Wa_bot) + ba ; v = x@Wa_bot  (fp32 acc, bf16 out)
// ---------------------------------------------------------------------------
__global__ __launch_bounds__(256) void transform_kernel(
    const float* __restrict__ X, int LD, int coff, int Cin, int Cmid,
    const float* __restrict__ Wa, const float* __restrict__ ba,
    unsigned short* __restrict__ u, unsigned short* __restrict__ v) {
  __shared__ float xs[16 * 128];
  int w = threadIdx.x >> 6, lane = threadIdx.x & 63;
  int m  = blockIdx.y * 64 + lane;
  int p0 = blockIdx.x * 16;
  for (int i = threadIdx.x; i < 16 * Cin; i += 256) {
    int pt = i / Cin, c = i - pt * Cin;
    xs[pt * Cin + c] = X[(size_t)(p0 + pt) * LD + coff + c];
  }
  __syncthreads();
  const float* xw = xs + (w * 4) * Cin;
  float ua[4] = {0.f, 0.f, 0.f, 0.f}, va[4] = {0.f, 0.f, 0.f, 0.f};
  for (int c = 0; c < Cin; ++c) {
    float wt = Wa[(size_t)c * Cmid + m];
    float wb = Wa[(size_t)(Cin + c) * Cmid + m];
    float wd = wt - wb;
#pragma unroll
    for (int i = 0; i < 4; ++i) {
      float xv = xw[i * Cin + c];
      ua[i] = fmaf(xv, wd, ua[i]);
      va[i] = fmaf(xv, wb, va[i]);
    }
  }
  float bias = ba[m];
#pragma unroll
  for (int i = 0; i < 4; ++i) {
    u[(size_t)(p0 + w * 4 + i) * Cmid + m] = f2bf(ua[i] + bias);
    v[(size_t)(p0 + w * 4 + i) * Cmid + m] = f2bf(va[i]);
  }
}

// ---------------------------------------------------------------------------
// Weight prep for MFMA transforms (layers 2-4): split Wa into
// Wd = Wa_top - Wa_bot and Wb = Wa_bot, both in FRAGMENT-MAJOR bf16:
//   out[((nt*KC + c)*64 + lane)*8 + j] = W[k][n],
//   n = nt*32 + (lane&31), k = c*16 + (lane>>5)*8 + j, KC = Cin/16.
// ---------------------------------------------------------------------------
__global__ __launch_bounds__(256) void cvtwa_swz_kernel(
    const float* __restrict__ A2, const float* __restrict__ A3,
    const float* __restrict__ A4,
    unsigned short* __restrict__ d2, unsigned short* __restrict__ b2,
    unsigned short* __restrict__ d3, unsigned short* __restrict__ b3,
    unsigned short* __restrict__ d4, unsigned short* __restrict__ b4) {
  int z = blockIdx.z;
  const float* Wa; unsigned short *wd, *wb; int Cin, Cmid;
  if (z == 0)      { Wa = A2; wd = d2; wb = b2; Cin = 64;  Cmid = 64;  }
  else if (z == 1) { Wa = A3; wd = d3; wb = b3; Cin = 64;  Cmid = 128; }
  else             { Wa = A4; wd = d4; wb = b4; Cin = 128; Cmid = 256; }
  int KC = Cin / 16;
  int NC = (Cmid / 32) * KC * 64;
  int ci = blockIdx.x * 256 + threadIdx.x;
  if (ci >= NC) return;
  int ntc = ci >> 6, lane = ci & 63;
  int nt = ntc / KC, c = ntc - nt * KC;
  int n  = nt * 32 + (lane & 31);
  int kb = c * 16 + (lane >> 5) * 8;
#pragma unroll
  for (int j = 0; j < 8; ++j) {
    float top = Wa[(size_t)(kb + j) * Cmid + n];
    float bot = Wa[(size_t)(Cin + kb + j) * Cmid + n];
    wd[(size_t)ci * 8 + j] = f2bf(top - bot);
    wb[(size_t)ci * 8 + j] = f2bf(bot);
  }
}

// ---------------------------------------------------------------------------
// MFMA transform (layers 2-4): u = X@Wd + ba, v = X@Wb via 32x32x16 bf16.
// ---------------------------------------------------------------------------
template<int Cin, int Cmid>
__global__ __launch_bounds__(256) void transform_mfma_kernel(
    const float* __restrict__ X, int LD, int coff,
    const unsigned short* __restrict__ wdf, const unsigned short* __restrict__ wbf,
    const float* __restrict__ ba,
    unsigned short* __restrict__ u, unsigned short* __restrict__ v) {
  constexpr int KC = Cin / 16;
  int wv = threadIdx.x >> 6, lane = threadIdx.x & 63;
  int row = lane & 31, half = lane >> 5;
  int p0 = blockIdx.x * 128 + wv * 32;
  int nt = blockIdx.y;

  bf16x8 afr[KC];
  const float* xr = X + (size_t)(p0 + row) * LD + coff + half * 8;
#pragma unroll
  for (int c = 0; c < KC; ++c) {
    float4 x0 = *(const float4*)(xr + c * 16);
    float4 x1 = *(const float4*)(xr + c * 16 + 4);
    union { bf16x8 vec; __hip_bfloat162 h[4]; } pk;
    pk.h[0] = __float22bfloat162_rn({x0.x, x0.y});
    pk.h[1] = __float22bfloat162_rn({x0.z, x0.w});
    pk.h[2] = __float22bfloat162_rn({x1.x, x1.y});
    pk.h[3] = __float22bfloat162_rn({x1.z, x1.w});
    afr[c] = pk.vec;
  }

  const unsigned short* wdl = wdf + ((size_t)nt * KC * 64 + lane) * 8;
  const unsigned short* wbl = wbf + ((size_t)nt * KC * 64 + lane) * 8;
  f32x16 au = {}, av = {};
#pragma unroll
  for (int c = 0; c < KC; ++c) {
    bf16x8 bd = *(const bf16x8*)(wdl + (size_t)c * 512);
    au = __builtin_amdgcn_mfma_f32_32x32x16_bf16(afr[c], bd, au, 0, 0, 0);
  }
#pragma unroll
  for (int c = 0; c < KC; ++c) {
    bf16x8 bv = *(const bf16x8*)(wbl + (size_t)c * 512);
    av = __builtin_amdgcn_mfma_f32_32x32x16_bf16(afr[c], bv, av, 0, 0, 0);
  }

  int m = nt * 32 + row;
  float bias = ba[m];
#pragma unroll
  for (int e = 0; e < 16; ++e) {
    int orow = (e & 3) + 8 * (e >> 2) + 4 * half;
    u[(size_t)(p0 + orow) * Cmid + m] = f2bf(au[e] + bias);
    v[(size_t)(p0 + orow) * Cmid + m] = f2bf(av[e]);
  }
}

// ---------------------------------------------------------------------------
// Batched transpose+convert of all four Wb (Cmid x Cout, fp32) -> bf16 WbT
// (row-major Cout x Cmid). grid.z selects layer.
// ---------------------------------------------------------------------------
__global__ __launch_bounds__(256) void cvtw4_kernel(
    const float* __restrict__ W0, const float* __restrict__ W1,
    const float* __restrict__ W2, const float* __restrict__ W3,
    unsigned short* __restrict__ o0, unsigned short* __restrict__ o1,
    unsigned short* __restrict__ o2, unsigned short* __restrict__ o3) {
  __shared__ unsigned short tile[32][33];
  int z = blockIdx.z;
  const float* W; unsigned short* out; int Cmid, Cout;
  if (z == 0)      { W = W0; out = o0; Cmid = 64;  Cout = 64;  }
  else if (z == 1) { W = W1; out = o1; Cmid = 64;  Cout = 64;  }
  else if (z == 2) { W = W2; out = o2; Cmid = 128; Cout = 128; }
  else             { W = W3; out = o3; Cmid = 256; Cout = 256; }
  int c0 = blockIdx.x * 32, co0 = blockIdx.y * 32;
  if (c0 >= Cmid || co0 >= Cout) return;
  int tx = threadIdx.x & 31, ty = threadIdx.x >> 5;   // 32 x 8
  for (int r = ty; r < 32; r += 8)
    tile[r][tx] = f2bf(W[(size_t)(c0 + r) * Cout + co0 + tx]);
  __syncthreads();
  for (int r = ty; r < 32; r += 8)
    out[(size_t)(co0 + r) * Cmid + c0 + tx] = tile[tx][r];
}

// ---------------------------------------------------------------------------
// Edge MLP second GEMM + max-aggregate. 960-thread two-barrier structure.
// ---------------------------------------------------------------------------
template<int Cmid, int Cout, int CG>
__global__ __launch_bounds__(960, 3) void edge_mlp_kernel(
    const unsigned short* __restrict__ u, const unsigned short* __restrict__ v,
    const int* __restrict__ idx,
    const unsigned short* __restrict__ wbt, const float* __restrict__ bb,
    float* __restrict__ xcat, int coff) {
  constexpr int AP = Cmid + 8;
  constexpr int T  = CG / 32;      // 32-col tiles per group
  constexpr int KC = Cmid / 16;    // k chunks of 16
  constexpr int G  = Cout / CG;    // col groups
  __shared__ __align__(16) unsigned short W_lds[CG * AP];
  __shared__ float qmax[120 * CG];
  int tid = threadIdx.x, w = tid >> 6, lane = tid & 63;
  int col = lane & 31, half = lane >> 5;

  int rg = blockIdx.x * 480 + w * 32 + col;
  int rgc = min(rg, NP * KNN - 1);           // tail-block clamp (stores guarded)
  int p  = rgc / 20;
  int j  = idx[rgc];
  const unsigned short* up = u + (size_t)p * Cmid + half * 8;
  const unsigned short* vp = v + (size_t)j * Cmid + half * 8;

  bf16x8 afr[KC];
#pragma unroll
  for (int c = 0; c < KC; ++c) {
    union { int4 i; __hip_bfloat162 h[4]; bf16x8 vec; } U, V, R;
    U.i = *(const int4*)(up + c * 16);
    V.i = *(const int4*)(vp + c * 16);
#pragma unroll
    for (int q = 0; q < 4; ++q) {
      float2 a = __bfloat1622float2(U.h[q]);
      float2 b = __bfloat1622float2(V.h[q]);
      R.h[q] = __float22bfloat162_rn({fmaxf(a.x + b.x, 0.f), fmaxf(a.y + b.y, 0.f)});
    }
    afr[c] = R.vec;
  }

  int brow = col * AP + half * 8;

  for (int g = 0; g < G; ++g) {
    __syncthreads();
    for (int i = tid; i < CG * (Cmid / 8); i += 960) {
      int rr = i / (Cmid / 8), q = i - rr * (Cmid / 8);
      *(int4*)&W_lds[rr * AP + q * 8] =
          *(const int4*)&wbt[(size_t)(g * CG + rr) * Cmid + q * 8];
    }
    __syncthreads();
    f32x16 acc[T] = {};
#pragma unroll
    for (int c = 0; c < KC; ++c) {
#pragma unroll
      for (int t = 0; t < T; ++t) {
        bf16x8 bf = *(const bf16x8*)&W_lds[brow + t * 32 * AP + c * 16];
        acc[t] = __builtin_amdgcn_mfma_f32_32x32x16_bf16(afr[c], bf, acc[t], 0, 0, 0);
      }
    }
#pragma unroll
    for (int t = 0; t < T; ++t) {
#pragma unroll
      for (int Q = 0; Q < 4; ++Q) {
        float m0 = fmaxf(fmaxf(acc[t][4 * Q], acc[t][4 * Q + 1]),
                         fmaxf(acc[t][4 * Q + 2], acc[t][4 * Q + 3]));
        qmax[(w * 8 + 2 * Q + half) * CG + t * 32 + col] = m0;
      }
    }
    __syncthreads();
    for (int i = tid; i < 24 * CG; i += 960) {
      int pl = i / CG, c2 = i - pl * CG;
      int pg = blockIdx.x * 24 + pl;
      if (pg < NP) {
        float mm = qmax[(pl * 5 + 0) * CG + c2];
#pragma unroll
        for (int qq = 1; qq < 5; ++qq) mm = fmaxf(mm, qmax[(pl * 5 + qq) * CG + c2]);
        xcat[(size_t)pg * 512 + coff + g * CG + c2] = mm + bb[g * CG + c2];
      }
    }
  }
}

// ---------------------------------------------------------------------------
// Global max pool, two-stage coalesced.
// ---------------------------------------------------------------------------
__global__ __launch_bounds__(256) void pool1_kernel(const float* __restrict__ xcat,
                                                    float* __restrict__ part) {
  int b = blockIdx.x, g = blockIdx.y, t = threadIdx.x;
  const float* base = xcat + ((size_t)b * N_ + g * 128) * 512 + t * 2;
  float mx = -__builtin_inff(), my = -__builtin_inff();
#pragma unroll 4
  for (int r = 0; r < 128; ++r) {
    float2 vv = *(const float2*)(base + (size_t)r * 512);
    mx = fmaxf(mx, vv.x);
    my = fmaxf(my, vv.y);
  }
  *(float2*)&part[((size_t)b * 8 + g) * 512 + t * 2] = make_float2(mx, my);
}

__global__ __launch_bounds__(256) void pool2_kernel(const float* __restrict__ part,
                                                    float* __restrict__ pooled) {
  int b = blockIdx.x, t = threadIdx.x;
  float2 m = *(const float2*)&part[(size_t)b * 8 * 512 + t * 2];
#pragma unroll
  for (int g = 1; g < 8; ++g) {
    float2 vv = *(const float2*)&part[((size_t)b * 8 + g) * 512 + t * 2];
    m.x = fmaxf(m.x, vv.x);
    m.y = fmaxf(m.y, vv.y);
  }
  *(float2*)&pooled[b * 512 + t * 2] = m;
}

__global__ __launch_bounds__(256) void lin1_kernel(const float* __restrict__ pooled,
                                                   const float* __restrict__ W,
                                                   const float* __restrict__ bias,
                                                   float* __restrict__ h) {
  int flat = blockIdx.x * 256 + threadIdx.x;
  int b = flat >> 10, m = flat & 1023;
  float s = 0.f;
  for (int c = 0; c < 512; ++c) s = fmaf(pooled[b * 512 + c], W[(size_t)c * 1024 + m], s);
  h[flat] = s + bias[m];
}

__global__ __launch_bounds__(256) void bn_kernel(const float* __restrict__ h,
                                                 const float* __restrict__ gamma,
                                                 const float* __restrict__ beta,
                                                 float* __restrict__ h2) {
  int m = blockIdx.x * 256 + threadIdx.x;
  float s = 0.f;
  for (int b = 0; b < 16; ++b) s += h[b * 1024 + m];
  float mu = s * (1.f / 16.f);
  float vv = 0.f;
  for (int b = 0; b < 16; ++b) { float d = h[b * 1024 + m] - mu; vv = fmaf(d, d, vv); }
  vv *= (1.f / 16.f);
  float rstd = rsqrtf(vv + 1e-5f);
  float g = gamma[m] * rstd, be = beta[m];
  for (int b = 0; b < 16; ++b) {
    float val = (h[b * 1024 + m] - mu) * g + be;
    h2[b * 1024 + m] = fmaxf(val, 0.f);
  }
}

__global__ __launch_bounds__(64) void lin2_kernel(const float* __restrict__ h2,
                                                  const float* __restrict__ W,
                                                  const float* __restrict__ bias,
                                                  float* __restrict__ out) {
  int b = blockIdx.x, lane = threadIdx.x;
  float logit = 0.f;
  if (lane < 40) {
    logit = bias[lane];
    for (int c = 0; c < 1024; ++c)
      logit = fmaf(h2[b * 1024 + c], W[(size_t)c * 40 + lane], logit);
  }
  float mv = (lane < 40) ? logit : -__builtin_inff();
#pragma unroll
  for (int off = 32; off >= 1; off >>= 1) mv = fmaxf(mv, __shfl_xor(mv, off));
  float e = (lane < 40) ? expf(logit - mv) : 0.f;
#pragma unroll
  for (int off = 32; off >= 1; off >>= 1) e += __shfl_xor(e, off);
  float lse = mv + logf(e);
  if (lane < 40) out[b * 40 + lane] = logit - lse;
}

// ---------------------------------------------------------------------------
extern "C" void kernel_launch(void* const* d_in, const int* in_sizes, int n_in,
                              void* d_out, int out_size, void* d_ws, size_t ws_size,
                              hipStream_t stream) {
  const float* pos    = (const float*)d_in[0];
  const float* W1a = (const float*)d_in[2];  const float* b1a = (const float*)d_in[3];
  const float* W1b = (const float*)d_in[4];  const float* b1b = (const float*)d_in[5];
  const float* W2a = (const float*)d_in[6];  const float* b2a = (const float*)d_in[7];
  const float* W2b = (const float*)d_in[8];  const float* b2b = (const float*)d_in[9];
  const float* W3a = (const float*)d_in[10]; const float* b3a = (const float*)d_in[11];
  const float* W3b = (const float*)d_in[12]; const float* b3b = (const float*)d_in[13];
  const float* W4a = (const float*)d_in[14]; const float* b4a = (const float*)d_in[15];
  const float* W4b = (const float*)d_in[16]; const float* b4b = (const float*)d_in[17];
  const float* lin1_w = (const float*)d_in[18]; const float* lin1_b = (const float*)d_in[19];
  const float* gamma  = (const float*)d_in[20]; const float* beta   = (const float*)d_in[21];
  const float* lin2_w = (const float*)d_in[22]; const float* lin2_b = (const float*)d_in[23];
  float* out = (float*)d_out;

  char* ws = (char*)d_ws;
  size_t off = 0;
  auto alloc = [&](size_t bytes) {
    void* p = ws + off; off += (bytes + 255) & ~(size_t)255; return p;
  };
  float*    xcat = (float*)alloc((size_t)NP * 512 * 4);   // 32 MB
  unsigned* Dk   = (unsigned*)alloc((size_t)NP * N_ * 4); // 64 MB (u/v alias inside)
  int*      idx  = (int*)alloc((size_t)NP * KNN * 4);
  unsigned short* wbt1 = (unsigned short*)alloc(64 * 64 * 2);
  unsigned short* wbt2 = (unsigned short*)alloc(64 * 64 * 2);
  unsigned short* wbt3 = (unsigned short*)alloc(128 * 128 * 2);
  unsigned short* wbt4 = (unsigned short*)alloc(256 * 256 * 2);
  unsigned short* wd2 = (unsigned short*)alloc(64 * 64 * 2);
  unsigned short* wb2 = (unsigned short*)alloc(64 * 64 * 2);
  unsigned short* wd3 = (unsigned short*)alloc(64 * 128 * 2);
  unsigned short* wb3 = (unsigned short*)alloc(64 * 128 * 2);
  unsigned short* wd4 = (unsigned short*)alloc(128 * 256 * 2);
  unsigned short* wb4 = (unsigned short*)alloc(128 * 256 * 2);
  float* h      = (float*)alloc(16 * 1024 * 4);
  float* h2     = (float*)alloc(16 * 1024 * 4);
  float* pooled = (float*)alloc(16 * 512 * 4);
  float* part   = (float*)alloc(16 * 8 * 512 * 4);
  unsigned short* u = (unsigned short*)Dk;             // bf16, aliases Dk
  unsigned short* v = (unsigned short*)Dk + (size_t)NP * 256;

  cvtw4_kernel<<<dim3(8, 8, 4), 256, 0, stream>>>(W1b, W2b, W3b, W4b,
                                                  wbt1, wbt2, wbt3, wbt4);
  cvtwa_swz_kernel<<<dim3(16, 1, 3), 256, 0, stream>>>(W2a, W3a, W4a,
                                                       wd2, wb2, wd3, wb3, wd4, wb4);

  dim3 pd_grid(16, 16, 16);
  const int EB = (NP * KNN + 479) / 480;   // 683 edge blocks
  // layer 1: in pos (C=3) -> xcat[:,0:64]
  pairdist_kernel<<<pd_grid, 256, 0, stream>>>(pos, 3, 0, 3, Dk);
  topk_kernel<<<NP / 4, 256, 0, stream>>>(Dk, idx);
  transform_kernel<<<dim3(NP / 16, 1), 256, 0, stream>>>(pos, 3, 0, 3, 64, W1a, b1a, u, v);
  edge_mlp_kernel<64, 64, 64><<<EB, 960, 0, stream>>>(u, v, idx, wbt1, b1b, xcat, 0);
  // layer 2: in xcat[:,0:64] -> xcat[:,64:128]
  pairdist_kernel<<<pd_grid, 256, 0, stream>>>(xcat, 512, 0, 64, Dk);
  topk_kernel<<<NP / 4, 256, 0, stream>>>(Dk, idx);
  transform_mfma_kernel<64, 64><<<dim3(NP / 128, 2), 256, 0, stream>>>(
      xcat, 512, 0, wd2, wb2, b2a, u, v);
  edge_mlp_kernel<64, 64, 64><<<EB, 960, 0, stream>>>(u, v, idx, wbt2, b2b, xcat, 64);
  // layer 3: in xcat[:,64:128] -> xcat[:,128:256]
  pairdist_kernel<<<pd_grid, 256, 0, stream>>>(xcat, 512, 64, 64, Dk);
  topk_kernel<<<NP / 4, 256, 0, stream>>>(Dk, idx);
  transform_mfma_kernel<64, 128><<<dim3(NP / 128, 4), 256, 0, stream>>>(
      xcat, 512, 64, wd3, wb3, b3a, u, v);
  edge_mlp_kernel<128, 128, 64><<<EB, 960, 0, stream>>>(u, v, idx, wbt3, b3b, xcat, 128);
  // layer 4: in xcat[:,128:256] -> xcat[:,256:512]
  pairdist_kernel<<<pd_grid, 256, 0, stream>>>(xcat, 512, 128, 128, Dk);
  topk_kernel<<<NP / 4, 256, 0, stream>>>(Dk, idx);
  transform_mfma_kernel<128, 256><<<dim3(NP / 128, 8), 256, 0, stream>>>(
      xcat, 512, 128, wd4, wb4, b4a, u, v);
  edge_mlp_kernel<256, 256, 64><<<EB, 960, 0, stream>>>(u, v, idx, wbt4, b4b, xcat, 256);
  // head
  pool1_kernel<<<dim3(16, 8), 256, 0, stream>>>(xcat, part);
  pool2_kernel<<<16, 256, 0, stream>>>(part, pooled);
  lin1_kernel<<<64, 256, 0, stream>>>(pooled, lin1_w, lin1_b, h);
  bn_kernel<<<4, 256, 0, stream>>>(h, gamma, beta, h2);
  lin2_kernel<<<16, 64, 0, stream>>>(h2, lin2_w, lin2_b, out);
}

// Round 17
// 622.846 us; speedup vs baseline: 1.4517x; 1.0649x over previous
//
#include <hip/hip_runtime.h>
#include <hip/hip_bf16.h>

#define B_   16
#define N_   1024
#define KNN  20
#define NP   (B_ * N_)   // 16384

typedef short bf16x8 __attribute__((ext_vector_type(8)));
typedef float f32x4  __attribute__((ext_vector_type(4)));
typedef float f32x16 __attribute__((ext_vector_type(16)));

__device__ __forceinline__ unsigned short f2bf(float f) {
  unsigned u = __float_as_uint(f);
  u += 0x7fffu + ((u >> 16) & 1u);   // RNE
  return (unsigned short)(u >> 16);
}

// ---------------------------------------------------------------------------
// Pairwise squared distances, Gram form, PACKED u32 SORT KEYS:
//   key[i][j] = (float_bits(max(d,0)) & 0xFFFFFC00) | j
// v4: symmetric (bx>=by only) with PACKED TRIANGULAR GRID (136 blocks/cloud,
// no dead blocks) and 32-WIDE c-tiles (half the barrier rounds; ascending-c
// order preserved -> bit-identical to v3/v2). Off-diagonal tiles also emitted
// transposed via LDS (overlays the dead Xi/Xj buffers).
// ---------------------------------------------------------------------------
__global__ __launch_bounds__(256) void pairdist_kernel(
    const float* __restrict__ X, int LD, int coff, int C,
    unsigned* __restrict__ Dk) {
  __shared__ __align__(16) char pd_smem[64 * 68 * 4];   // Xi+Xj (2x8.7KB) / Tt (17.4KB)
  __shared__ float sqi_s[64], sqj_s[64];
  float (*Xi)[68] = (float(*)[68])pd_smem;               // [32][68]
  float (*Xj)[68] = (float(*)[68])(pd_smem + 32 * 68 * 4);
  unsigned (*Tt)[68] = (unsigned(*)[68])pd_smem;         // [64][68]
  // triangular decode: blockIdx.x in [0,136) -> (by, bx) with bx >= by
  int lin = blockIdx.x, by = 0;
  while (lin >= 16 - by) { lin -= 16 - by; ++by; }
  int bx = by + lin;
  int b  = blockIdx.z;
  int i0 = by * 64, j0 = bx * 64;
  int t  = threadIdx.x;
  int tx = t & 15, ty = t >> 4;
  int cx = t & 31, ry = t >> 5;      // staging map: 32 c x 8 rows
  float acc[4][4] = {};
  float sqacc = 0.f;     // t<64: ||x_i||^2 row t ; t in [64,128): ||x_j||^2
  for (int c0 = 0; c0 < C; c0 += 32) {
    int cc = min(32, C - c0);
    if (cx < cc) {
      for (int r = ry; r < 64; r += 8) {
        Xi[cx][r] = X[(size_t)(b * N_ + i0 + r) * LD + coff + c0 + cx];
        Xj[cx][r] = X[(size_t)(b * N_ + j0 + r) * LD + coff + c0 + cx];
      }
    }
    __syncthreads();
    if (t < 64) {
      for (int c = 0; c < cc; ++c) sqacc = fmaf(Xi[c][t], Xi[c][t], sqacc);
    } else if (t < 128) {
      int r = t - 64;
      for (int c = 0; c < cc; ++c) sqacc = fmaf(Xj[c][r], Xj[c][r], sqacc);
    }
    for (int c = 0; c < cc; ++c) {
      float4 a4 = *(const float4*)&Xi[c][ty * 4];
      float4 b4 = *(const float4*)&Xj[c][tx * 4];
      float a[4] = {a4.x, a4.y, a4.z, a4.w};
      float bb[4] = {b4.x, b4.y, b4.z, b4.w};
#pragma unroll
      for (int p = 0; p < 4; ++p)
#pragma unroll
        for (int q = 0; q < 4; ++q)
          acc[p][q] = fmaf(a[p], bb[q], acc[p][q]);
    }
    __syncthreads();
  }
  if (t < 64) sqi_s[t] = sqacc;
  else if (t < 128) sqj_s[t - 64] = sqacc;
  __syncthreads();                    // all Xi/Xj reads done -> Tt may overlay
  float sqi[4], sqj[4];
#pragma unroll
  for (int p = 0; p < 4; ++p) sqi[p] = sqi_s[ty * 4 + p];
#pragma unroll
  for (int q = 0; q < 4; ++q) sqj[q] = sqj_s[tx * 4 + q];
  bool offdiag = (bx > by);
#pragma unroll
  for (int p = 0; p < 4; ++p) {
    uint4 st;
    unsigned* kk = (unsigned*)&st;
#pragma unroll
    for (int q = 0; q < 4; ++q) {
      float d = fmaxf((sqi[p] - 2.f * acc[p][q]) + sqj[q], 0.f);
      unsigned db = __float_as_uint(d) & 0xFFFFFC00u;
      kk[q] = db | (unsigned)(j0 + tx * 4 + q);
      if (offdiag)
        Tt[tx * 4 + q][ty * 4 + p] = db | (unsigned)(i0 + ty * 4 + p);
    }
    *(uint4*)&Dk[(size_t)(b * N_ + i0 + ty * 4 + p) * N_ + j0 + tx * 4] = st;
  }
  if (offdiag) {
    __syncthreads();
#pragma unroll
    for (int p = 0; p < 4; ++p) {
      *(uint4*)&Dk[(size_t)(b * N_ + j0 + ty * 4 + p) * N_ + i0 + tx * 4] =
          *(uint4*)&Tt[ty * 4 + p][tx * 4];
    }
  }
}

// ---------------------------------------------------------------------------
// Top-K=20 smallest keys per point. One wave per point, u32 keys.
// ---------------------------------------------------------------------------
__global__ __launch_bounds__(256) void topk_kernel(
    const unsigned* __restrict__ Dk, int* __restrict__ idx) {
  int w = threadIdx.x >> 6, lane = threadIdx.x & 63;
  int p = blockIdx.x * 4 + w;
  const unsigned* row = Dk + (size_t)p * N_;
  unsigned key[16];
#pragma unroll
  for (int s = 0; s < 16; ++s) key[s] = row[lane + 64 * s];
  int base = p & ~(N_ - 1);
  for (int k = 0; k < KNN; ++k) {
    unsigned m = key[0];
#pragma unroll
    for (int s = 1; s < 16; ++s) m = min(m, key[s]);
#pragma unroll
    for (int off = 32; off >= 1; off >>= 1)
      m = min(m, (unsigned)__shfl_xor((int)m, off));
    int j = (int)(m & 1023u);
    if (lane == 0) idx[p * KNN + k] = base + j;
    if ((j & 63) == lane) key[j >> 6] = 0xFFFFFFFFu;
  }
}

// ---------------------------------------------------------------------------
// Scalar per-point transform (layer 1 only, Cin=3):
//   u = x@(Wa_top - Wa_bot) + ba ; v = x@Wa_bot  (fp32 acc, bf16 out)
// ---------------------------------------------------------------------------
__global__ __launch_bounds__(256) void transform_kernel(
    const float* __restrict__ X, int LD, int coff, int Cin, int Cmid,
    const float* __restrict__ Wa, const float* __restrict__ ba,
    unsigned short* __restrict__ u, unsigned short* __restrict__ v) {
  __shared__ float xs[16 * 128];
  int w = threadIdx.x >> 6, lane = threadIdx.x & 63;
  int m  = blockIdx.y * 64 + lane;
  int p0 = blockIdx.x * 16;
  for (int i = threadIdx.x; i < 16 * Cin; i += 256) {
    int pt = i / Cin, c = i - pt * Cin;
    xs[pt * Cin + c] = X[(size_t)(p0 + pt) * LD + coff + c];
  }
  __syncthreads();
  const float* xw = xs + (w * 4) * Cin;
  float ua[4] = {0.f, 0.f, 0.f, 0.f}, va[4] = {0.f, 0.f, 0.f, 0.f};
  for (int c = 0; c < Cin; ++c) {
    float wt = Wa[(size_t)c * Cmid + m];
    float wb = Wa[(size_t)(Cin + c) * Cmid + m];
    float wd = wt - wb;
#pragma unroll
    for (int i = 0; i < 4; ++i) {
      float xv = xw[i * Cin + c];
      ua[i] = fmaf(xv, wd, ua[i]);
      va[i] = fmaf(xv, wb, va[i]);
    }
  }
  float bias = ba[m];
#pragma unroll
  for (int i = 0; i < 4; ++i) {
    u[(size_t)(p0 + w * 4 + i) * Cmid + m] = f2bf(ua[i] + bias);
    v[(size_t)(p0 + w * 4 + i) * Cmid + m] = f2bf(va[i]);
  }
}

// ---------------------------------------------------------------------------
// Weight prep for MFMA transforms (layers 2-4): split Wa into
// Wd = Wa_top - Wa_bot and Wb = Wa_bot, both in FRAGMENT-MAJOR bf16.
// ---------------------------------------------------------------------------
__global__ __launch_bounds__(256) void cvtwa_swz_kernel(
    const float* __restrict__ A2, const float* __restrict__ A3,
    const float* __restrict__ A4,
    unsigned short* __restrict__ d2, unsigned short* __restrict__ b2,
    unsigned short* __restrict__ d3, unsigned short* __restrict__ b3,
    unsigned short* __restrict__ d4, unsigned short* __restrict__ b4) {
  int z = blockIdx.z;
  const float* Wa; unsigned short *wd, *wb; int Cin, Cmid;
  if (z == 0)      { Wa = A2; wd = d2; wb = b2; Cin = 64;  Cmid = 64;  }
  else if (z == 1) { Wa = A3; wd = d3; wb = b3; Cin = 64;  Cmid = 128; }
  else             { Wa = A4; wd = d4; wb = b4; Cin = 128; Cmid = 256; }
  int KC = Cin / 16;
  int NC = (Cmid / 32) * KC * 64;
  int ci = blockIdx.x * 256 + threadIdx.x;
  if (ci >= NC) return;
  int ntc = ci >> 6, lane = ci & 63;
  int nt = ntc / KC, c = ntc - nt * KC;
  int n  = nt * 32 + (lane & 31);
  int kb = c * 16 + (lane >> 5) * 8;
#pragma unroll
  for (int j = 0; j < 8; ++j) {
    float top = Wa[(size_t)(kb + j) * Cmid + n];
    float bot = Wa[(size_t)(Cin + kb + j) * Cmid + n];
    wd[(size_t)ci * 8 + j] = f2bf(top - bot);
    wb[(size_t)ci * 8 + j] = f2bf(bot);
  }
}

// ---------------------------------------------------------------------------
// MFMA transform (layers 2-4): u = X@Wd + ba, v = X@Wb via 32x32x16 bf16.
// ---------------------------------------------------------------------------
template<int Cin, int Cmid>
__global__ __launch_bounds__(256) void transform_mfma_kernel(
    const float* __restrict__ X, int LD, int coff,
    const unsigned short* __restrict__ wdf, const unsigned short* __restrict__ wbf,
    const float* __restrict__ ba,
    unsigned short* __restrict__ u, unsigned short* __restrict__ v) {
  constexpr int KC = Cin / 16;
  int wv = threadIdx.x >> 6, lane = threadIdx.x & 63;
  int row = lane & 31, half = lane >> 5;
  int p0 = blockIdx.x * 128 + wv * 32;
  int nt = blockIdx.y;

  bf16x8 afr[KC];
  const float* xr = X + (size_t)(p0 + row) * LD + coff + half * 8;
#pragma unroll
  for (int c = 0; c < KC; ++c) {
    float4 x0 = *(const float4*)(xr + c * 16);
    float4 x1 = *(const float4*)(xr + c * 16 + 4);
    union { bf16x8 vec; __hip_bfloat162 h[4]; } pk;
    pk.h[0] = __float22bfloat162_rn({x0.x, x0.y});
    pk.h[1] = __float22bfloat162_rn({x0.z, x0.w});
    pk.h[2] = __float22bfloat162_rn({x1.x, x1.y});
    pk.h[3] = __float22bfloat162_rn({x1.z, x1.w});
    afr[c] = pk.vec;
  }

  const unsigned short* wdl = wdf + ((size_t)nt * KC * 64 + lane) * 8;
  const unsigned short* wbl = wbf + ((size_t)nt * KC * 64 + lane) * 8;
  f32x16 au = {}, av = {};
#pragma unroll
  for (int c = 0; c < KC; ++c) {
    bf16x8 bd = *(const bf16x8*)(wdl + (size_t)c * 512);
    au = __builtin_amdgcn_mfma_f32_32x32x16_bf16(afr[c], bd, au, 0, 0, 0);
  }
#pragma unroll
  for (int c = 0; c < KC; ++c) {
    bf16x8 bv = *(const bf16x8*)(wbl + (size_t)c * 512);
    av = __builtin_amdgcn_mfma_f32_32x32x16_bf16(afr[c], bv, av, 0, 0, 0);
  }

  int m = nt * 32 + row;
  float bias = ba[m];
#pragma unroll
  for (int e = 0; e < 16; ++e) {
    int orow = (e & 3) + 8 * (e >> 2) + 4 * half;
    u[(size_t)(p0 + orow) * Cmid + m] = f2bf(au[e] + bias);
    v[(size_t)(p0 + orow) * Cmid + m] = f2bf(av[e]);
  }
}

// ---------------------------------------------------------------------------
// Batched transpose+convert of all four Wb (Cmid x Cout, fp32) -> bf16 WbT
// (row-major Cout x Cmid). grid.z selects layer.
// ---------------------------------------------------------------------------
__global__ __launch_bounds__(256) void cvtw4_kernel(
    const float* __restrict__ W0, const float* __restrict__ W1,
    const float* __restrict__ W2, const float* __restrict__ W3,
    unsigned short* __restrict__ o0, unsigned short* __restrict__ o1,
    unsigned short* __restrict__ o2, unsigned short* __restrict__ o3) {
  __shared__ unsigned short tile[32][33];
  int z = blockIdx.z;
  const float* W; unsigned short* out; int Cmid, Cout;
  if (z == 0)      { W = W0; out = o0; Cmid = 64;  Cout = 64;  }
  else if (z == 1) { W = W1; out = o1; Cmid = 64;  Cout = 64;  }
  else if (z == 2) { W = W2; out = o2; Cmid = 128; Cout = 128; }
  else             { W = W3; out = o3; Cmid = 256; Cout = 256; }
  int c0 = blockIdx.x * 32, co0 = blockIdx.y * 32;
  if (c0 >= Cmid || co0 >= Cout) return;
  int tx = threadIdx.x & 31, ty = threadIdx.x >> 5;   // 32 x 8
  for (int r = ty; r < 32; r += 8)
    tile[r][tx] = f2bf(W[(size_t)(c0 + r) * Cout + co0 + tx]);
  __syncthreads();
  for (int r = ty; r < 32; r += 8)
    out[(size_t)(co0 + r) * Cmid + c0 + tx] = tile[tx][r];
}

// ---------------------------------------------------------------------------
// Edge MLP second GEMM + max-aggregate. 960-thread two-barrier structure.
// ---------------------------------------------------------------------------
template<int Cmid, int Cout, int CG>
__global__ __launch_bounds__(960, 3) void edge_mlp_kernel(
    const unsigned short* __restrict__ u, const unsigned short* __restrict__ v,
    const int* __restrict__ idx,
    const unsigned short* __restrict__ wbt, const float* __restrict__ bb,
    float* __restrict__ xcat, int coff) {
  constexpr int AP = Cmid + 8;
  constexpr int T  = CG / 32;      // 32-col tiles per group
  constexpr int KC = Cmid / 16;    // k chunks of 16
  constexpr int G  = Cout / CG;    // col groups
  __shared__ __align__(16) unsigned short W_lds[CG * AP];
  __shared__ float qmax[120 * CG];
  int tid = threadIdx.x, w = tid >> 6, lane = tid & 63;
  int col = lane & 31, half = lane >> 5;

  int rg = blockIdx.x * 480 + w * 32 + col;
  int rgc = min(rg, NP * KNN - 1);           // tail-block clamp (stores guarded)
  int p  = rgc / 20;
  int j  = idx[rgc];
  const unsigned short* up = u + (size_t)p * Cmid + half * 8;
  const unsigned short* vp = v + (size_t)j * Cmid + half * 8;

  bf16x8 afr[KC];
#pragma unroll
  for (int c = 0; c < KC; ++c) {
    union { int4 i; __hip_bfloat162 h[4]; bf16x8 vec; } U, V, R;
    U.i = *(const int4*)(up + c * 16);
    V.i = *(const int4*)(vp + c * 16);
#pragma unroll
    for (int q = 0; q < 4; ++q) {
      float2 a = __bfloat1622float2(U.h[q]);
      float2 b = __bfloat1622float2(V.h[q]);
      R.h[q] = __float22bfloat162_rn({fmaxf(a.x + b.x, 0.f), fmaxf(a.y + b.y, 0.f)});
    }
    afr[c] = R.vec;
  }

  int brow = col * AP + half * 8;

  for (int g = 0; g < G; ++g) {
    __syncthreads();
    for (int i = tid; i < CG * (Cmid / 8); i += 960) {
      int rr = i / (Cmid / 8), q = i - rr * (Cmid / 8);
      *(int4*)&W_lds[rr * AP + q * 8] =
          *(const int4*)&wbt[(size_t)(g * CG + rr) * Cmid + q * 8];
    }
    __syncthreads();
    f32x16 acc[T] = {};
#pragma unroll
    for (int c = 0; c < KC; ++c) {
#pragma unroll
      for (int t = 0; t < T; ++t) {
        bf16x8 bf = *(const bf16x8*)&W_lds[brow + t * 32 * AP + c * 16];
        acc[t] = __builtin_amdgcn_mfma_f32_32x32x16_bf16(afr[c], bf, acc[t], 0, 0, 0);
      }
    }
#pragma unroll
    for (int t = 0; t < T; ++t) {
#pragma unroll
      for (int Q = 0; Q < 4; ++Q) {
        float m0 = fmaxf(fmaxf(acc[t][4 * Q], acc[t][4 * Q + 1]),
                         fmaxf(acc[t][4 * Q + 2], acc[t][4 * Q + 3]));
        qmax[(w * 8 + 2 * Q + half) * CG + t * 32 + col] = m0;
      }
    }
    __syncthreads();
    for (int i = tid; i < 24 * CG; i += 960) {
      int pl = i / CG, c2 = i - pl * CG;
      int pg = blockIdx.x * 24 + pl;
      if (pg < NP) {
        float mm = qmax[(pl * 5 + 0) * CG + c2];
#pragma unroll
        for (int qq = 1; qq < 5; ++qq) mm = fmaxf(mm, qmax[(pl * 5 + qq) * CG + c2]);
        xcat[(size_t)pg * 512 + coff + g * CG + c2] = mm + bb[g * CG + c2];
      }
    }
  }
}

// ---------------------------------------------------------------------------
// Global max pool, two-stage coalesced.
// ---------------------------------------------------------------------------
__global__ __launch_bounds__(256) void pool1_kernel(const float* __restrict__ xcat,
                                                    float* __restrict__ part) {
  int b = blockIdx.x, g = blockIdx.y, t = threadIdx.x;
  const float* base = xcat + ((size_t)b * N_ + g * 128) * 512 + t * 2;
  float mx = -__builtin_inff(), my = -__builtin_inff();
#pragma unroll 4
  for (int r = 0; r < 128; ++r) {
    float2 vv = *(const float2*)(base + (size_t)r * 512);
    mx = fmaxf(mx, vv.x);
    my = fmaxf(my, vv.y);
  }
  *(float2*)&part[((size_t)b * 8 + g) * 512 + t * 2] = make_float2(mx, my);
}

__global__ __launch_bounds__(256) void pool2_kernel(const float* __restrict__ part,
                                                    float* __restrict__ pooled) {
  int b = blockIdx.x, t = threadIdx.x;
  float2 m = *(const float2*)&part[(size_t)b * 8 * 512 + t * 2];
#pragma unroll
  for (int g = 1; g < 8; ++g) {
    float2 vv = *(const float2*)&part[((size_t)b * 8 + g) * 512 + t * 2];
    m.x = fmaxf(m.x, vv.x);
    m.y = fmaxf(m.y, vv.y);
  }
  *(float2*)&pooled[b * 512 + t * 2] = m;
}

__global__ __launch_bounds__(256) void lin1_kernel(const float* __restrict__ pooled,
                                                   const float* __restrict__ W,
                                                   const float* __restrict__ bias,
                                                   float* __restrict__ h) {
  int flat = blockIdx.x * 256 + threadIdx.x;
  int b = flat >> 10, m = flat & 1023;
  float s = 0.f;
  for (int c = 0; c < 512; ++c) s = fmaf(pooled[b * 512 + c], W[(size_t)c * 1024 + m], s);
  h[flat] = s + bias[m];
}

__global__ __launch_bounds__(256) void bn_kernel(const float* __restrict__ h,
                                                 const float* __restrict__ gamma,
                                                 const float* __restrict__ beta,
                                                 float* __restrict__ h2) {
  int m = blockIdx.x * 256 + threadIdx.x;
  float s = 0.f;
  for (int b = 0; b < 16; ++b) s += h[b * 1024 + m];
  float mu = s * (1.f / 16.f);
  float vv = 0.f;
  for (int b = 0; b < 16; ++b) { float d = h[b * 1024 + m] - mu; vv = fmaf(d, d, vv); }
  vv *= (1.f / 16.f);
  float rstd = rsqrtf(vv + 1e-5f);
  float g = gamma[m] * rstd, be = beta[m];
  for (int b = 0; b < 16; ++b) {
    float val = (h[b * 1024 + m] - mu) * g + be;
    h2[b * 1024 + m] = fmaxf(val, 0.f);
  }
}

__global__ __launch_bounds__(64) void lin2_kernel(const float* __restrict__ h2,
                                                  const float* __restrict__ W,
                                                  const float* __restrict__ bias,
                                                  float* __restrict__ out) {
  int b = blockIdx.x, lane = threadIdx.x;
  float logit = 0.f;
  if (lane < 40) {
    logit = bias[lane];
    for (int c = 0; c < 1024; ++c)
      logit = fmaf(h2[b * 1024 + c], W[(size_t)c * 40 + lane], logit);
  }
  float mv = (lane < 40) ? logit : -__builtin_inff();
#pragma unroll
  for (int off = 32; off >= 1; off >>= 1) mv = fmaxf(mv, __shfl_xor(mv, off));
  float e = (lane < 40) ? expf(logit - mv) : 0.f;
#pragma unroll
  for (int off = 32; off >= 1; off >>= 1) e += __shfl_xor(e, off);
  float lse = mv + logf(e);
  if (lane < 40) out[b * 40 + lane] = logit - lse;
}

// ---------------------------------------------------------------------------
extern "C" void kernel_launch(void* const* d_in, const int* in_sizes, int n_in,
                              void* d_out, int out_size, void* d_ws, size_t ws_size,
                              hipStream_t stream) {
  const float* pos    = (const float*)d_in[0];
  const float* W1a = (const float*)d_in[2];  const float* b1a = (const float*)d_in[3];
  const float* W1b = (const float*)d_in[4];  const float* b1b = (const float*)d_in[5];
  const float* W2a = (const float*)d_in[6];  const float* b2a = (const float*)d_in[7];
  const float* W2b = (const float*)d_in[8];  const float* b2b = (const float*)d_in[9];
  const float* W3a = (const float*)d_in[10]; const float* b3a = (const float*)d_in[11];
  const float* W3b = (const float*)d_in[12]; const float* b3b = (const float*)d_in[13];
  const float* W4a = (const float*)d_in[14]; const float* b4a = (const float*)d_in[15];
  const float* W4b = (const float*)d_in[16]; const float* b4b = (const float*)d_in[17];
  const float* lin1_w = (const float*)d_in[18]; const float* lin1_b = (const float*)d_in[19];
  const float* gamma  = (const float*)d_in[20]; const float* beta   = (const float*)d_in[21];
  const float* lin2_w = (const float*)d_in[22]; const float* lin2_b = (const float*)d_in[23];
  float* out = (float*)d_out;

  char* ws = (char*)d_ws;
  size_t off = 0;
  auto alloc = [&](size_t bytes) {
    void* p = ws + off; off += (bytes + 255) & ~(size_t)255; return p;
  };
  float*    xcat = (float*)alloc((size_t)NP * 512 * 4);   // 32 MB
  unsigned* Dk   = (unsigned*)alloc((size_t)NP * N_ * 4); // 64 MB (u/v alias inside)
  int*      idx  = (int*)alloc((size_t)NP * KNN * 4);
  unsigned short* wbt1 = (unsigned short*)alloc(64 * 64 * 2);
  unsigned short* wbt2 = (unsigned short*)alloc(64 * 64 * 2);
  unsigned short* wbt3 = (unsigned short*)alloc(128 * 128 * 2);
  unsigned short* wbt4 = (unsigned short*)alloc(256 * 256 * 2);
  unsigned short* wd2 = (unsigned short*)alloc(64 * 64 * 2);
  unsigned short* wb2 = (unsigned short*)alloc(64 * 64 * 2);
  unsigned short* wd3 = (unsigned short*)alloc(64 * 128 * 2);
  unsigned short* wb3 = (unsigned short*)alloc(64 * 128 * 2);
  unsigned short* wd4 = (unsigned short*)alloc(128 * 256 * 2);
  unsigned short* wb4 = (unsigned short*)alloc(128 * 256 * 2);
  float* h      = (float*)alloc(16 * 1024 * 4);
  float* h2     = (float*)alloc(16 * 1024 * 4);
  float* pooled = (float*)alloc(16 * 512 * 4);
  float* part   = (float*)alloc(16 * 8 * 512 * 4);
  unsigned short* u = (unsigned short*)Dk;             // bf16, aliases Dk
  unsigned short* v = (unsigned short*)Dk + (size_t)NP * 256;

  cvtw4_kernel<<<dim3(8, 8, 4), 256, 0, stream>>>(W1b, W2b, W3b, W4b,
                                                  wbt1, wbt2, wbt3, wbt4);
  cvtwa_swz_kernel<<<dim3(16, 1, 3), 256, 0, stream>>>(W2a, W3a, W4a,
                                                       wd2, wb2, wd3, wb3, wd4, wb4);

  dim3 pd_grid(136, 1, 16);                // packed triangular (bx >= by)
  const int EB = (NP * KNN + 479) / 480;   // 683 edge blocks
  // layer 1: in pos (C=3) -> xcat[:,0:64]
  pairdist_kernel<<<pd_grid, 256, 0, stream>>>(pos, 3, 0, 3, Dk);
  topk_kernel<<<NP / 4, 256, 0, stream>>>(Dk, idx);
  transform_kernel<<<dim3(NP / 16, 1), 256, 0, stream>>>(pos, 3, 0, 3, 64, W1a, b1a, u, v);
  edge_mlp_kernel<64, 64, 64><<<EB, 960, 0, stream>>>(u, v, idx, wbt1, b1b, xcat, 0);
  // layer 2: in xcat[:,0:64] -> xcat[:,64:128]
  pairdist_kernel<<<pd_grid, 256, 0, stream>>>(xcat, 512, 0, 64, Dk);
  topk_kernel<<<NP / 4, 256, 0, stream>>>(Dk, idx);
  transform_mfma_kernel<64, 64><<<dim3(NP / 128, 2), 256, 0, stream>>>(
      xcat, 512, 0, wd2, wb2, b2a, u, v);
  edge_mlp_kernel<64, 64, 64><<<EB, 960, 0, stream>>>(u, v, idx, wbt2, b2b, xcat, 64);
  // layer 3: in xcat[:,64:128] -> xcat[:,128:256]
  pairdist_kernel<<<pd_grid, 256, 0, stream>>>(xcat, 512, 64, 64, Dk);
  topk_kernel<<<NP / 4, 256, 0, stream>>>(Dk, idx);
  transform_mfma_kernel<64, 128><<<dim3(NP / 128, 4), 256, 0, stream>>>(
      xcat, 512, 64, wd3, wb3, b3a, u, v);
  edge_mlp_kernel<128, 128, 64><<<EB, 960, 0, stream>>>(u, v, idx, wbt3, b3b, xcat, 128);
  // layer 4: in xcat[:,128:256] -> xcat[:,256:512]
  pairdist_kernel<<<pd_grid, 256, 0, stream>>>(xcat, 512, 128, 128, Dk);
  topk_kernel<<<NP / 4, 256, 0, stream>>>(Dk, idx);
  transform_mfma_kernel<128, 256><<<dim3(NP / 128, 8), 256, 0, stream>>>(
      xcat, 512, 128, wd4, wb4, b4a, u, v);
  edge_mlp_kernel<256, 256, 64><<<EB, 960, 0, stream>>>(u, v, idx, wbt4, b4b, xcat, 256);
  // head
  pool1_kernel<<<dim3(16, 8), 256, 0, stream>>>(xcat, part);
  pool2_kernel<<<16, 256, 0, stream>>>(part, pooled);
  lin1_kernel<<<64, 256, 0, stream>>>(pooled, lin1_w, lin1_b, h);
  bn_kernel<<<4, 256, 0, stream>>>(h, gamma, beta, h2);
  lin2_kernel<<<16, 64, 0, stream>>>(h2, lin2_w, lin2_b, out);
}